// Round 1
// baseline (1464.401 us; speedup 1.0000x reference)
//
#include <hip/hip_runtime.h>
#include <hip/hip_bf16.h>
#include <math.h>

#define D_STATE   64
#define HEADDIM   64
#define D_INNER   2048
#define NHEADS    32
#define GN        64
#define CONV_DIM  2304
#define D_IN_PROJ 4416
#define K_SP      7
#define K_TP      4
#define CHUNK     256
#define BATCHN    2
#define FRAMES    8
#define SPATIAL   256
#define SEQLEN    2048
#define NCH       8
#define RTOT      4
#define MTOT      4096

__device__ __forceinline__ float silu_f(float x) { return x / (1.f + __expf(-x)); }
__device__ __forceinline__ int flip_l(int l) { return (l & ~7) | (7 - (l & 7)); }

// ---------------- C = A * B^T  (A: MxK k-fast, B: NxK k-fast) ----------------
__global__ __launch_bounds__(256) void gemm_bt_f32(
    const float* __restrict__ A, int lda,
    const float* __restrict__ B, int ldb,
    float* __restrict__ C, int ldc,
    int N, int K) {
  __shared__ float As[16][64];
  __shared__ float Bs[16][64];
  const int tid = threadIdx.x;
  const int tx = tid & 15, ty = tid >> 4;
  const int m0 = blockIdx.y * 64;
  const int n0 = blockIdx.x * 64;
  const int lm = tid >> 2;
  const int lk = (tid & 3) << 2;
  const float* Ag = A + (size_t)(m0 + lm) * lda + lk;
  const float* Bg = B + (size_t)(n0 + lm) * ldb + lk;
  const bool bvalid = (n0 + lm) < N;
  float acc[4][4] = {{0.f,0.f,0.f,0.f},{0.f,0.f,0.f,0.f},{0.f,0.f,0.f,0.f},{0.f,0.f,0.f,0.f}};
  for (int k0 = 0; k0 < K; k0 += 16) {
    float4 av = *(const float4*)(Ag + k0);
    float4 bv = bvalid ? *(const float4*)(Bg + k0) : make_float4(0.f,0.f,0.f,0.f);
    __syncthreads();
    As[lk+0][lm] = av.x; As[lk+1][lm] = av.y; As[lk+2][lm] = av.z; As[lk+3][lm] = av.w;
    Bs[lk+0][lm] = bv.x; Bs[lk+1][lm] = bv.y; Bs[lk+2][lm] = bv.z; Bs[lk+3][lm] = bv.w;
    __syncthreads();
#pragma unroll
    for (int kk = 0; kk < 16; ++kk) {
      float4 a4 = *(const float4*)&As[kk][ty << 2];
      float4 b4 = *(const float4*)&Bs[kk][tx << 2];
      float ar[4] = {a4.x, a4.y, a4.z, a4.w};
      float br[4] = {b4.x, b4.y, b4.z, b4.w};
#pragma unroll
      for (int i = 0; i < 4; ++i)
#pragma unroll
        for (int j = 0; j < 4; ++j)
          acc[i][j] += ar[i] * br[j];
    }
  }
  const int n = n0 + (tx << 2);
  if (n < N) {
#pragma unroll
    for (int i = 0; i < 4; ++i) {
      float4 o = make_float4(acc[i][0], acc[i][1], acc[i][2], acc[i][3]);
      *(float4*)(C + (size_t)(m0 + (ty<<2) + i) * ldc + n) = o;
    }
  }
}

// ---------------- dt = softplus(dt_raw + bias), flip for reverse ----------------
__global__ __launch_bounds__(256) void dt_kernel(const float* __restrict__ Z,
                                                 const float* __restrict__ dt_bias,
                                                 float* __restrict__ DTt) {
  int idx = blockIdx.x * 256 + threadIdx.x;   // ((r*32+h)<<11) + l
  int l  = idx & 2047;
  int rh = idx >> 11;
  int h  = rh & 31;
  int r  = rh >> 5;
  int bi = r & 1;
  int ls = (r < 2) ? l : flip_l(l);
  int ch = D_INNER + CONV_DIM + ((r < 2) ? h : NHEADS + h);
  float raw = Z[((size_t)bi * SEQLEN + ls) * D_IN_PROJ + ch] + dt_bias[h];
  DTt[idx] = (raw > 20.f) ? raw : log1pf(__expf(raw));
}

// ---------------- spatial depthwise conv (same pad) + silu ----------------
__global__ __launch_bounds__(256) void conv_sp_kernel(const float* __restrict__ Z,
                                                      const float* __restrict__ w,
                                                      const float* __restrict__ b,
                                                      float* __restrict__ XS) {
  size_t idx = (size_t)blockIdx.x * 256 + threadIdx.x;
  int c = (int)(idx % CONV_DIM);
  size_t t = idx / CONV_DIM;
  int l = (int)(t & 2047);
  int bi = (int)(t >> 11);
  int s = l >> 3, fr = l & 7;
  float acc = b[c];
  const float* wc = w + c * K_SP;
#pragma unroll
  for (int j = 0; j < K_SP; ++j) {
    int ss = s + j - 3;
    if (0 <= ss && ss < SPATIAL)
      acc += wc[j] * Z[((size_t)bi * SEQLEN + (ss*8 + fr)) * D_IN_PROJ + D_INNER + c];
  }
  XS[idx] = silu_f(acc);
}

// ---------------- temporal depthwise conv (causal) + silu ----------------
__global__ __launch_bounds__(256) void conv_tp_kernel(const float* __restrict__ XS,
                                                      const float* __restrict__ w,
                                                      const float* __restrict__ b,
                                                      float* __restrict__ XT) {
  size_t idx = (size_t)blockIdx.x * 256 + threadIdx.x;
  int c = (int)(idx % CONV_DIM);
  size_t t = idx / CONV_DIM;
  int l = (int)(t & 2047);
  int bi = (int)(t >> 11);
  int s = l >> 3, fr = l & 7;
  float acc = b[c];
  const float* wc = w + c * K_TP;
#pragma unroll
  for (int j = 0; j < K_TP; ++j) {
    int ff = fr + j - (K_TP - 1);
    if (ff >= 0)
      acc += wc[j] * XS[((size_t)bi * SEQLEN + (s*8 + ff)) * CONV_DIM + c];
  }
  XT[idx] = silu_f(acc);
}

// ---------------- CB[s][t] = sum_n C[t][n] B[s][n], per (r,c) ----------------
__global__ __launch_bounds__(256) void cb_kernel(const float* __restrict__ XT,
                                                 float* __restrict__ CBs) {
  __shared__ float Ct[64][65];
  __shared__ float Bt[64][65];
  int tid = threadIdx.x;
  int t0 = (blockIdx.x & 3) * 64;
  int s0 = (blockIdx.x >> 2) * 64;
  if (s0 > t0) return;   // strictly-upper tiles never read (mask s<=t)
  int c = blockIdx.y;
  int r = blockIdx.z;
  int bi = r & 1;
  int bOff = D_INNER + ((r < 2) ? 0 : 2*GN);
  int cOff = bOff + GN;
  int lrow = tid >> 4;
  int n4 = (tid & 15) << 2;
#pragma unroll
  for (int rep = 0; rep < 4; ++rep) {
    int tl = rep * 16 + lrow;
    int Lc = c * CHUNK + t0 + tl;
    int Ls = c * CHUNK + s0 + tl;
    if (r >= 2) { Lc = flip_l(Lc); Ls = flip_l(Ls); }
    float4 cv = *(const float4*)(XT + ((size_t)bi*SEQLEN + Lc)*CONV_DIM + cOff + n4);
    float4 bv = *(const float4*)(XT + ((size_t)bi*SEQLEN + Ls)*CONV_DIM + bOff + n4);
    Ct[n4+0][tl] = cv.x; Ct[n4+1][tl] = cv.y; Ct[n4+2][tl] = cv.z; Ct[n4+3][tl] = cv.w;
    Bt[n4+0][tl] = bv.x; Bt[n4+1][tl] = bv.y; Bt[n4+2][tl] = bv.z; Bt[n4+3][tl] = bv.w;
  }
  __syncthreads();
  int txx = tid & 15;
  int tyy = tid >> 4;
  float acc[4][4] = {{0.f,0.f,0.f,0.f},{0.f,0.f,0.f,0.f},{0.f,0.f,0.f,0.f},{0.f,0.f,0.f,0.f}};
#pragma unroll
  for (int n = 0; n < D_STATE; ++n) {
    float cr[4], br[4];
#pragma unroll
    for (int j = 0; j < 4; ++j) cr[j] = Ct[n][txx + 16*j];
#pragma unroll
    for (int i = 0; i < 4; ++i) br[i] = Bt[n][tyy + 16*i];
#pragma unroll
    for (int i = 0; i < 4; ++i)
#pragma unroll
      for (int j = 0; j < 4; ++j)
        acc[i][j] += br[i] * cr[j];
  }
  size_t base = (((size_t)r*NCH + c) * CHUNK) * CHUNK;
#pragma unroll
  for (int i = 0; i < 4; ++i)
#pragma unroll
    for (int j = 0; j < 4; ++j)
      CBs[base + (size_t)(s0 + tyy + 16*i)*CHUNK + (t0 + txx + 16*j)] = acc[i][j];
}

// ---------------- sequential chunk states (forward r=0,1 only) ----------------
__global__ __launch_bounds__(256) void state_kernel(const float* __restrict__ XT,
                                                    const float* __restrict__ DTt,
                                                    const float* __restrict__ A_log,
                                                    float* __restrict__ SPREV) {
  __shared__ float xs[64][64];
  __shared__ float bs[64][64];
  __shared__ float dts[CHUNK];
  __shared__ float cums[CHUNK];
  __shared__ float Gs[CHUNK];
  int tid = threadIdx.x;
  int h = blockIdx.x;
  int r = blockIdx.y;    // 0..1
  int bi = r;
  float A = -__expf(A_log[h]);
  int p  = tid & 63;
  int ng = tid >> 6;
  float S[16];
#pragma unroll
  for (int j = 0; j < 16; ++j) S[j] = 0.f;
  for (int c = 0; c < NCH; ++c) {
    size_t pb = ((((size_t)r*NCH + c)*NHEADS + h) * HEADDIM + p) * D_STATE + ng*16;
#pragma unroll
    for (int j = 0; j < 16; ++j) SPREV[pb + j] = S[j];
    __syncthreads();
    dts[tid] = DTt[((size_t)r*NHEADS + h)*SEQLEN + c*CHUNK + tid];
    __syncthreads();
    if (tid == 0) {
      float run = 0.f;
      for (int s2 = 0; s2 < CHUNK; ++s2) { run += dts[s2] * A; cums[s2] = run; }
    }
    __syncthreads();
    float cl = cums[CHUNK-1];
    Gs[tid] = __expf(cl - cums[tid]) * dts[tid];
    float dec = __expf(cl);
#pragma unroll
    for (int j = 0; j < 16; ++j) S[j] *= dec;
    for (int st = 0; st < 4; ++st) {
      int s0 = st * 64;
      __syncthreads();
      int lrow = tid >> 4;
      int p4 = (tid & 15) << 2;
#pragma unroll
      for (int rep = 0; rep < 4; ++rep) {
        int si = rep*16 + lrow;
        const float* row = XT + ((size_t)bi*SEQLEN + (c*CHUNK + s0 + si))*CONV_DIM;
        *(float4*)&xs[si][p4] = *(const float4*)(row + h*HEADDIM + p4);
        *(float4*)&bs[si][p4] = *(const float4*)(row + D_INNER + p4);
      }
      __syncthreads();
      for (int si = 0; si < 64; ++si) {
        float xv = Gs[s0+si] * xs[si][p];
        const float4* bp = (const float4*)&bs[si][ng*16];
#pragma unroll
        for (int q = 0; q < 4; ++q) {
          float4 b4 = bp[q];
          S[q*4+0] += xv * b4.x; S[q*4+1] += xv * b4.y;
          S[q*4+2] += xv * b4.z; S[q*4+3] += xv * b4.w;
        }
      }
    }
  }
}

// ---------------- Y = intra(triangular) + inter (fwd only) ----------------
__global__ __launch_bounds__(256) void yscan_kernel(const float* __restrict__ XT,
                                                    const float* __restrict__ DTt,
                                                    const float* __restrict__ CBs,
                                                    const float* __restrict__ SPREV,
                                                    const float* __restrict__ A_log,
                                                    float* __restrict__ Y) {
  __shared__ float xs[64][64];        // x tile; reused as SPt[n][p] for inter
  __shared__ float ctn[CHUNK][17];    // E[t]*C[t][n-tile]
  __shared__ float dts[CHUNK];
  __shared__ float cums[CHUNK];
  int tid = threadIdx.x;
  int c = blockIdx.x;
  int rh = blockIdx.y;
  int h = rh & 31;
  int r = rh >> 5;
  int bi = r & 1;
  float A = -__expf(A_log[h]);
  dts[tid] = DTt[((size_t)r*NHEADS + h)*SEQLEN + c*CHUNK + tid];
  __syncthreads();
  if (tid == 0) {
    float run = 0.f;
    for (int s2 = 0; s2 < CHUNK; ++s2) { run += dts[s2] * A; cums[s2] = run; }
  }
  __syncthreads();
  int tslot = tid >> 2;   // t = tslot*4 + i
  int pg = tid & 3;       // p = pg*16 + j
  float cum_t[4];
#pragma unroll
  for (int i = 0; i < 4; ++i) cum_t[i] = cums[tslot*4 + i];
  float acc[4][16];
#pragma unroll
  for (int i = 0; i < 4; ++i)
#pragma unroll
    for (int j = 0; j < 16; ++j) acc[i][j] = 0.f;
  size_t cbbase = (((size_t)r*NCH + c) * CHUNK) * CHUNK;
  for (int st = 0; st < 4; ++st) {
    int s0 = st * 64;
    __syncthreads();
    {
      int lrow = tid >> 4;
      int p4 = (tid & 15) << 2;
#pragma unroll
      for (int rep = 0; rep < 4; ++rep) {
        int si = rep*16 + lrow;
        int L = c*CHUNK + s0 + si;
        if (r >= 2) L = flip_l(L);
        *(float4*)&xs[si][p4] =
            *(const float4*)(XT + ((size_t)bi*SEQLEN + L)*CONV_DIM + h*HEADDIM + p4);
      }
    }
    __syncthreads();
    if (tslot*4 + 3 >= s0) {   // wave-uniform skip (t-range below s-tile)
      const float* cbrow = CBs + cbbase + (size_t)s0*CHUNK + tslot*4;
      float4 cbnext = *(const float4*)cbrow;
      for (int si = 0; si < 64; ++si) {
        float4 cb4 = cbnext;
        if (si < 63) cbnext = *(const float4*)(cbrow + (size_t)(si+1)*CHUNK);
        int s = s0 + si;
        float dtv = dts[s];
        float cs = cums[s];
        const float4* xp = (const float4*)&xs[si][pg*16];
        float4 x0 = xp[0], x1 = xp[1], x2 = xp[2], x3 = xp[3];
        float wv[4] = {cb4.x, cb4.y, cb4.z, cb4.w};
#pragma unroll
        for (int i = 0; i < 4; ++i) {
          int t = tslot*4 + i;
          float wgt = 0.f;
          if (s <= t) wgt = wv[i] * __expf(cum_t[i] - cs) * dtv;
          acc[i][0] += wgt*x0.x; acc[i][1] += wgt*x0.y; acc[i][2] += wgt*x0.z; acc[i][3] += wgt*x0.w;
          acc[i][4] += wgt*x1.x; acc[i][5] += wgt*x1.y; acc[i][6] += wgt*x1.z; acc[i][7] += wgt*x1.w;
          acc[i][8] += wgt*x2.x; acc[i][9] += wgt*x2.y; acc[i][10]+= wgt*x2.z; acc[i][11]+= wgt*x2.w;
          acc[i][12]+= wgt*x3.x; acc[i][13]+= wgt*x3.y; acc[i][14]+= wgt*x3.z; acc[i][15]+= wgt*x3.w;
        }
      }
    }
  }
  if (r < 2) {   // inter-chunk term (reverse has zero prev-state by construction)
    __syncthreads();
    {
      int lrow = tid >> 4;
      int n4 = (tid & 15) << 2;
#pragma unroll
      for (int rep = 0; rep < 4; ++rep) {
        int pp = rep*16 + lrow;
        float4 v = *(const float4*)(SPREV +
            ((((size_t)r*NCH + c)*NHEADS + h)*HEADDIM + pp)*D_STATE + n4);
        xs[n4+0][pp] = v.x; xs[n4+1][pp] = v.y; xs[n4+2][pp] = v.z; xs[n4+3][pp] = v.w;
      }
    }
    float et_self = __expf(cums[tid]);
    const float* crow = XT + ((size_t)bi*SEQLEN + c*CHUNK + tid)*CONV_DIM + D_INNER + GN;
    for (int nt = 0; nt < 4; ++nt) {
      __syncthreads();
#pragma unroll
      for (int nl = 0; nl < 16; ++nl) ctn[tid][nl] = crow[nt*16 + nl] * et_self;
      __syncthreads();
#pragma unroll
      for (int nl = 0; nl < 16; ++nl) {
        int n = nt*16 + nl;
        const float4* spp = (const float4*)&xs[n][pg*16];
        float4 s0v = spp[0], s1v = spp[1], s2v = spp[2], s3v = spp[3];
#pragma unroll
        for (int i = 0; i < 4; ++i) {
          float cv = ctn[tslot*4 + i][nl];
          acc[i][0] += cv*s0v.x; acc[i][1] += cv*s0v.y; acc[i][2] += cv*s0v.z; acc[i][3] += cv*s0v.w;
          acc[i][4] += cv*s1v.x; acc[i][5] += cv*s1v.y; acc[i][6] += cv*s1v.z; acc[i][7] += cv*s1v.w;
          acc[i][8] += cv*s2v.x; acc[i][9] += cv*s2v.y; acc[i][10]+= cv*s2v.z; acc[i][11]+= cv*s2v.w;
          acc[i][12]+= cv*s3v.x; acc[i][13]+= cv*s3v.y; acc[i][14]+= cv*s3v.z; acc[i][15]+= cv*s3v.w;
        }
      }
    }
  }
  size_t ybase = ((size_t)r*SEQLEN + c*CHUNK)*D_INNER + h*HEADDIM + pg*16;
#pragma unroll
  for (int i = 0; i < 4; ++i) {
    float* yp = Y + ybase + (size_t)(tslot*4 + i)*D_INNER;
    ((float4*)yp)[0] = make_float4(acc[i][0],  acc[i][1],  acc[i][2],  acc[i][3]);
    ((float4*)yp)[1] = make_float4(acc[i][4],  acc[i][5],  acc[i][6],  acc[i][7]);
    ((float4*)yp)[2] = make_float4(acc[i][8],  acc[i][9],  acc[i][10], acc[i][11]);
    ((float4*)yp)[3] = make_float4(acc[i][12], acc[i][13], acc[i][14], acc[i][15]);
  }
}

// ---------------- shifts + x_res + RMSNorm + gate ----------------
__global__ __launch_bounds__(256) void combine_kernel(const float* __restrict__ Y,
                                                      const float* __restrict__ XT,
                                                      const float* __restrict__ FCD,
                                                      const float* __restrict__ Dp,
                                                      const float* __restrict__ Z,
                                                      const float* __restrict__ norm_w,
                                                      float* __restrict__ YP) {
  __shared__ float red[256];
  int row = blockIdx.x;     // bi*SEQLEN + l
  int bi = row >> 11;
  int l = row & 2047;
  int s = l >> 3, fr = l & 7;
  int tid = threadIdx.x;
  const float* yf = (l >= 1) ? Y + ((size_t)bi*SEQLEN + (l-1))*D_INNER : nullptr;
  const float* yr = (s >= 1) ? Y + ((size_t)(2+bi)*SEQLEN + ((s-1)*8 + (7-fr)))*D_INNER : nullptr;
  const float* xr = XT + ((size_t)bi*SEQLEN + l)*CONV_DIM;
  const float* fc = FCD + (size_t)row*NHEADS;
  float v[8];
  float ss = 0.f;
#pragma unroll
  for (int q = 0; q < 8; ++q) {
    int d = q*256 + tid;
    float val = xr[d] * (fc[d >> 6] + Dp[d >> 6]);
    if (yf) val += yf[d];
    if (yr) val += yr[d];
    v[q] = val;
    ss += val * val;
  }
  red[tid] = ss;
  __syncthreads();
  for (int ofs = 128; ofs > 0; ofs >>= 1) {
    if (tid < ofs) red[tid] += red[tid + ofs];
    __syncthreads();
  }
  float rs = rsqrtf(red[0] / (float)D_INNER + 1e-5f);
  const float* zrow = Z + ((size_t)bi*SEQLEN + l)*D_IN_PROJ;
#pragma unroll
  for (int q = 0; q < 8; ++q) {
    int d = q*256 + tid;
    YP[(size_t)row*D_INNER + d] = v[q] * rs * norm_w[d] * silu_f(zrow[d]);
  }
}

extern "C" void kernel_launch(void* const* d_in, const int* in_sizes, int n_in,
                              void* d_out, int out_size, void* d_ws, size_t ws_size,
                              hipStream_t stream) {
  (void)in_sizes; (void)n_in; (void)out_size; (void)ws_size;
  const float* u          = (const float*)d_in[0];
  const float* in_proj_w  = (const float*)d_in[1];
  const float* conv_sp_w  = (const float*)d_in[2];
  const float* conv_sp_b  = (const float*)d_in[3];
  const float* conv_tp_w  = (const float*)d_in[4];
  const float* conv_tp_b  = (const float*)d_in[5];
  const float* dt_bias    = (const float*)d_in[6];
  const float* A_log      = (const float*)d_in[7];
  const float* Dp         = (const float*)d_in[8];
  const float* fc_D_w     = (const float*)d_in[9];
  const float* norm_w     = (const float*)d_in[10];
  const float* out_proj_w = (const float*)d_in[11];
  float* out = (float*)d_out;
  float* ws = (float*)d_ws;

  // workspace layout (elements); SH region lifetimes: XS -> CBs -> YP
  float* Z     = ws;                       // 2*2048*4416 = 18,087,936
  float* SH    = Z     + 18087936ULL;      // 9,437,184 (>= 8,388,608 needed for CBs/YP)
  float* XT    = SH    + 9437184ULL;       // 2*2048*2304 = 9,437,184
  float* DTt   = XT    + 9437184ULL;       // 4*32*2048 = 262,144
  float* Yb    = DTt   + 262144ULL;        // 4*2048*2048 = 16,777,216
  float* SPREV = Yb    + 16777216ULL;      // 2*8*32*64*64 = 2,097,152
  float* FCD   = SPREV + 2097152ULL;       // 4096*32 = 131,072

  // 1. zxbcdt = u @ in_proj_w^T     (M=4096, N=4416, K=1024)
  gemm_bt_f32<<<dim3(69, 64), 256, 0, stream>>>(u, 1024, in_proj_w, 1024, Z, 4416, 4416, 1024);
  // 2. dt (flip + bias + softplus)
  dt_kernel<<<1024, 256, 0, stream>>>(Z, dt_bias, DTt);
  // 3. spatial conv + silu  (Z -> SH as XS)
  conv_sp_kernel<<<36864, 256, 0, stream>>>(Z, conv_sp_w, conv_sp_b, SH);
  // 4. temporal causal conv + silu (SH -> XT)
  conv_tp_kernel<<<36864, 256, 0, stream>>>(SH, conv_tp_w, conv_tp_b, XT);
  // 5. FCD = x @ fc_D_w^T          (M=4096, N=32, K=2048, lda=2304)
  gemm_bt_f32<<<dim3(1, 64), 256, 0, stream>>>(XT, 2304, fc_D_w, 2048, FCD, 32, 32, 2048);
  // 6. CB[s][t] per (r,c)  (XT -> SH as CBs)
  cb_kernel<<<dim3(16, 8, 4), 256, 0, stream>>>(XT, SH);
  // 7. sequential chunk states (forward only)
  state_kernel<<<dim3(32, 2), 256, 0, stream>>>(XT, DTt, A_log, SPREV);
  // 8. Y = intra + inter
  yscan_kernel<<<dim3(8, 128), 256, 0, stream>>>(XT, DTt, SH, SPREV, A_log, Yb);
  // 9. shifts + x_res + RMSNorm + gate (-> SH as YP)
  combine_kernel<<<4096, 256, 0, stream>>>(Yb, XT, FCD, Dp, Z, norm_w, SH);
  // 10. out = YP @ out_proj_w^T    (M=4096, N=1024, K=2048)
  gemm_bt_f32<<<dim3(16, 64), 256, 0, stream>>>(SH, 2048, out_proj_w, 2048, out, 1024, 1024, 2048);
}

// Round 2
// 855.737 us; speedup vs baseline: 1.7113x; 1.7113x over previous
//
#include <hip/hip_runtime.h>
#include <hip/hip_bf16.h>
#include <math.h>

#define D_STATE   64
#define HEADDIM   64
#define D_INNER   2048
#define NHEADS    32
#define GN        64
#define CONV_DIM  2304
#define D_IN_PROJ 4416
#define ZLD       4352      /* z + xBC columns only (dt handled separately) */
#define K_SP      7
#define K_TP      4
#define CHUNK     256
#define BATCHN    2
#define FRAMES    8
#define SPATIAL   256
#define SEQLEN    2048
#define NCH       8
#define MTOT      4096

typedef __attribute__((ext_vector_type(8))) short short8;
typedef __attribute__((ext_vector_type(4))) float floatx4;

__device__ __forceinline__ float silu_f(float x) { return x / (1.f + __expf(-x)); }
__device__ __forceinline__ int flip_l(int l) { return (l & ~7) | (7 - (l & 7)); }
__device__ __forceinline__ unsigned short f2bf(float f) {
  unsigned int u = __float_as_uint(f);
  unsigned int r = (u + 0x7fffu + ((u >> 16) & 1u)) >> 16;
  return (unsigned short)r;
}
__device__ __forceinline__ void gload_lds16(const unsigned short* g, unsigned short* l) {
  __builtin_amdgcn_global_load_lds((const __attribute__((address_space(1))) void*)g,
                                   (__attribute__((address_space(3))) void*)l, 16, 0, 0);
}

// ---------------- f32 -> bf16 cast ----------------
__global__ __launch_bounds__(256) void cast_bf16_kernel(const float* __restrict__ in,
                                                        unsigned short* __restrict__ out) {
  size_t i = ((size_t)blockIdx.x * 256 + threadIdx.x) * 4;
  float4 v = *(const float4*)(in + i);
  ushort4 o;
  o.x = f2bf(v.x); o.y = f2bf(v.y); o.z = f2bf(v.z); o.w = f2bf(v.w);
  *(ushort4*)(out + i) = o;
}

// ---------------- bf16 MFMA GEMM: C = A * B^T (A: MxK k-fast, B: NxK k-fast) ----------------
// M,N multiples of 128; K multiple of 32. m97 structure: global_load_lds(16B) staging,
// 128x128 tile, 4 waves each computing a 64x64 quadrant via 4x4 grid of 16x16x32 MFMAs.
__global__ __launch_bounds__(256) void gemm_bf16(
    const unsigned short* __restrict__ A, int lda,
    const unsigned short* __restrict__ B, int ldb,
    float* __restrict__ C, int ldc, int K) {
  __shared__ unsigned short As[128 * 32];
  __shared__ unsigned short Bs[128 * 32];
  const int tid = threadIdx.x;
  const int lane = tid & 63;
  const int w = tid >> 6;
  const int m0 = blockIdx.y * 128;
  const int n0 = blockIdx.x * 128;
  const int wm = (w >> 1) * 64;
  const int wn = (w & 1) * 64;
  const int srow = lane >> 2;          // row within 16-row chunk
  const int scol = (lane & 3) * 8;     // k element offset (8 bf16 = 16B)
  floatx4 acc[4][4] = {};
  for (int k0 = 0; k0 < K; k0 += 32) {
#pragma unroll
    for (int it = 0; it < 2; ++it) {
      int ch = it * 4 + w;
      const unsigned short* ga = A + (size_t)(m0 + ch * 16 + srow) * lda + k0 + scol;
      const unsigned short* gb = B + (size_t)(n0 + ch * 16 + srow) * ldb + k0 + scol;
      gload_lds16(ga, &As[ch * 512]);
      gload_lds16(gb, &Bs[ch * 512]);
    }
    __syncthreads();
    const int fr = lane & 15;
    const int kq = (lane >> 4) * 8;
    short8 af[4], bfr[4];
#pragma unroll
    for (int i = 0; i < 4; ++i)
      af[i] = *(const short8*)&As[(wm + i * 16 + fr) * 32 + kq];
#pragma unroll
    for (int j = 0; j < 4; ++j)
      bfr[j] = *(const short8*)&Bs[(wn + j * 16 + fr) * 32 + kq];
#pragma unroll
    for (int i = 0; i < 4; ++i)
#pragma unroll
      for (int j = 0; j < 4; ++j)
        acc[i][j] = __builtin_amdgcn_mfma_f32_16x16x32_bf16(af[i], bfr[j], acc[i][j], 0, 0, 0);
    __syncthreads();
  }
  const int col = lane & 15;
  const int rg = (lane >> 4) * 4;
#pragma unroll
  for (int i = 0; i < 4; ++i)
#pragma unroll
    for (int j = 0; j < 4; ++j)
#pragma unroll
      for (int r = 0; r < 4; ++r)
        C[(size_t)(m0 + wm + i * 16 + rg + r) * ldc + (n0 + wn + j * 16 + col)] = acc[i][j][r];
}

// ---------------- f32 tiled GEMM: C = A * B^T (used for dt cols + fc_D) ----------------
__global__ __launch_bounds__(256) void gemm_bt_f32(
    const float* __restrict__ A, int lda,
    const float* __restrict__ B, int ldb,
    float* __restrict__ C, int ldc,
    int N, int K) {
  __shared__ float As[16][64];
  __shared__ float Bs[16][64];
  const int tid = threadIdx.x;
  const int tx = tid & 15, ty = tid >> 4;
  const int m0 = blockIdx.y * 64;
  const int n0 = blockIdx.x * 64;
  const int lm = tid >> 2;
  const int lk = (tid & 3) << 2;
  const float* Ag = A + (size_t)(m0 + lm) * lda + lk;
  const float* Bg = B + (size_t)(n0 + lm) * ldb + lk;
  const bool bvalid = (n0 + lm) < N;
  float acc[4][4] = {{0.f,0.f,0.f,0.f},{0.f,0.f,0.f,0.f},{0.f,0.f,0.f,0.f},{0.f,0.f,0.f,0.f}};
  for (int k0 = 0; k0 < K; k0 += 16) {
    float4 av = *(const float4*)(Ag + k0);
    float4 bv = bvalid ? *(const float4*)(Bg + k0) : make_float4(0.f,0.f,0.f,0.f);
    __syncthreads();
    As[lk+0][lm] = av.x; As[lk+1][lm] = av.y; As[lk+2][lm] = av.z; As[lk+3][lm] = av.w;
    Bs[lk+0][lm] = bv.x; Bs[lk+1][lm] = bv.y; Bs[lk+2][lm] = bv.z; Bs[lk+3][lm] = bv.w;
    __syncthreads();
#pragma unroll
    for (int kk = 0; kk < 16; ++kk) {
      float4 a4 = *(const float4*)&As[kk][ty << 2];
      float4 b4 = *(const float4*)&Bs[kk][tx << 2];
      float ar[4] = {a4.x, a4.y, a4.z, a4.w};
      float br[4] = {b4.x, b4.y, b4.z, b4.w};
#pragma unroll
      for (int i = 0; i < 4; ++i)
#pragma unroll
        for (int j = 0; j < 4; ++j)
          acc[i][j] += ar[i] * br[j];
    }
  }
  const int n = n0 + (tx << 2);
  if (n < N) {
#pragma unroll
    for (int i = 0; i < 4; ++i) {
      float4 o = make_float4(acc[i][0], acc[i][1], acc[i][2], acc[i][3]);
      *(float4*)(C + (size_t)(m0 + (ty<<2) + i) * ldc + n) = o;
    }
  }
}

// ---------------- dt = softplus(dt_raw + bias), flip for reverse ----------------
__global__ __launch_bounds__(256) void dt_kernel(const float* __restrict__ DTraw,
                                                 const float* __restrict__ dt_bias,
                                                 float* __restrict__ DTt) {
  int idx = blockIdx.x * 256 + threadIdx.x;   // ((r*32+h)<<11) + l
  int l  = idx & 2047;
  int rh = idx >> 11;
  int h  = rh & 31;
  int r  = rh >> 5;
  int bi = r & 1;
  int ls = (r < 2) ? l : flip_l(l);
  int ch = (r < 2) ? h : NHEADS + h;
  float raw = DTraw[((size_t)bi * SEQLEN + ls) * 64 + ch] + dt_bias[h];
  DTt[idx] = (raw > 20.f) ? raw : log1pf(__expf(raw));
}

// ---------------- spatial depthwise conv (same pad) + silu ----------------
__global__ __launch_bounds__(256) void conv_sp_kernel(const float* __restrict__ Z,
                                                      const float* __restrict__ w,
                                                      const float* __restrict__ b,
                                                      float* __restrict__ XS) {
  size_t idx = (size_t)blockIdx.x * 256 + threadIdx.x;
  int c = (int)(idx % CONV_DIM);
  size_t t = idx / CONV_DIM;
  int l = (int)(t & 2047);
  int bi = (int)(t >> 11);
  int s = l >> 3, fr = l & 7;
  float acc = b[c];
  const float* wc = w + c * K_SP;
#pragma unroll
  for (int j = 0; j < K_SP; ++j) {
    int ss = s + j - 3;
    if (0 <= ss && ss < SPATIAL)
      acc += wc[j] * Z[((size_t)bi * SEQLEN + (ss*8 + fr)) * ZLD + D_INNER + c];
  }
  XS[idx] = silu_f(acc);
}

// ---------------- temporal depthwise conv (causal) + silu ----------------
__global__ __launch_bounds__(256) void conv_tp_kernel(const float* __restrict__ XS,
                                                      const float* __restrict__ w,
                                                      const float* __restrict__ b,
                                                      float* __restrict__ XT) {
  size_t idx = (size_t)blockIdx.x * 256 + threadIdx.x;
  int c = (int)(idx % CONV_DIM);
  size_t t = idx / CONV_DIM;
  int l = (int)(t & 2047);
  int bi = (int)(t >> 11);
  int s = l >> 3, fr = l & 7;
  float acc = b[c];
  const float* wc = w + c * K_TP;
#pragma unroll
  for (int j = 0; j < K_TP; ++j) {
    int ff = fr + j - (K_TP - 1);
    if (ff >= 0)
      acc += wc[j] * XS[((size_t)bi * SEQLEN + (s*8 + ff)) * CONV_DIM + c];
  }
  XT[idx] = silu_f(acc);
}

// ---------------- CB[s][t] = sum_n C[t][n] B[s][n], per (r,c) ----------------
__global__ __launch_bounds__(256) void cb_kernel(const float* __restrict__ XT,
                                                 float* __restrict__ CBs) {
  __shared__ float Ct[64][65];
  __shared__ float Bt[64][65];
  int tid = threadIdx.x;
  int t0 = (blockIdx.x & 3) * 64;
  int s0 = (blockIdx.x >> 2) * 64;
  if (s0 > t0) return;   // strictly-upper tiles never read (mask s<=t)
  int c = blockIdx.y;
  int r = blockIdx.z;
  int bi = r & 1;
  int bOff = D_INNER + ((r < 2) ? 0 : 2*GN);
  int cOff = bOff + GN;
  int lrow = tid >> 4;
  int n4 = (tid & 15) << 2;
#pragma unroll
  for (int rep = 0; rep < 4; ++rep) {
    int tl = rep * 16 + lrow;
    int Lc = c * CHUNK + t0 + tl;
    int Ls = c * CHUNK + s0 + tl;
    if (r >= 2) { Lc = flip_l(Lc); Ls = flip_l(Ls); }
    float4 cv = *(const float4*)(XT + ((size_t)bi*SEQLEN + Lc)*CONV_DIM + cOff + n4);
    float4 bv = *(const float4*)(XT + ((size_t)bi*SEQLEN + Ls)*CONV_DIM + bOff + n4);
    Ct[n4+0][tl] = cv.x; Ct[n4+1][tl] = cv.y; Ct[n4+2][tl] = cv.z; Ct[n4+3][tl] = cv.w;
    Bt[n4+0][tl] = bv.x; Bt[n4+1][tl] = bv.y; Bt[n4+2][tl] = bv.z; Bt[n4+3][tl] = bv.w;
  }
  __syncthreads();
  int txx = tid & 15;
  int tyy = tid >> 4;
  float acc[4][4] = {{0.f,0.f,0.f,0.f},{0.f,0.f,0.f,0.f},{0.f,0.f,0.f,0.f},{0.f,0.f,0.f,0.f}};
#pragma unroll
  for (int n = 0; n < D_STATE; ++n) {
    float cr[4], br[4];
#pragma unroll
    for (int j = 0; j < 4; ++j) cr[j] = Ct[n][txx + 16*j];
#pragma unroll
    for (int i = 0; i < 4; ++i) br[i] = Bt[n][tyy + 16*i];
#pragma unroll
    for (int i = 0; i < 4; ++i)
#pragma unroll
      for (int j = 0; j < 4; ++j)
        acc[i][j] += br[i] * cr[j];
  }
  size_t base = (((size_t)r*NCH + c) * CHUNK) * CHUNK;
#pragma unroll
  for (int i = 0; i < 4; ++i)
#pragma unroll
    for (int j = 0; j < 4; ++j)
      CBs[base + (size_t)(s0 + tyy + 16*i)*CHUNK + (t0 + txx + 16*j)] = acc[i][j];
}

// ---------------- sequential chunk states (forward r=0,1 only) ----------------
__global__ __launch_bounds__(256) void state_kernel(const float* __restrict__ XT,
                                                    const float* __restrict__ DTt,
                                                    const float* __restrict__ A_log,
                                                    float* __restrict__ SPREV) {
  __shared__ float xs[64][64];
  __shared__ float bs[64][64];
  __shared__ float dts[CHUNK];
  __shared__ float cums[CHUNK];
  __shared__ float Gs[CHUNK];
  int tid = threadIdx.x;
  int h = blockIdx.x;
  int r = blockIdx.y;    // 0..1
  int bi = r;
  float A = -__expf(A_log[h]);
  int p  = tid & 63;
  int ng = tid >> 6;
  float S[16];
#pragma unroll
  for (int j = 0; j < 16; ++j) S[j] = 0.f;
  for (int c = 0; c < NCH; ++c) {
    size_t pb = ((((size_t)r*NCH + c)*NHEADS + h) * HEADDIM + p) * D_STATE + ng*16;
#pragma unroll
    for (int j = 0; j < 16; ++j) SPREV[pb + j] = S[j];
    __syncthreads();
    dts[tid] = DTt[((size_t)r*NHEADS + h)*SEQLEN + c*CHUNK + tid];
    __syncthreads();
    if (tid == 0) {
      float run = 0.f;
      for (int s2 = 0; s2 < CHUNK; ++s2) { run += dts[s2] * A; cums[s2] = run; }
    }
    __syncthreads();
    float cl = cums[CHUNK-1];
    Gs[tid] = __expf(cl - cums[tid]) * dts[tid];
    float dec = __expf(cl);
#pragma unroll
    for (int j = 0; j < 16; ++j) S[j] *= dec;
    for (int st = 0; st < 4; ++st) {
      int s0 = st * 64;
      __syncthreads();
      int lrow = tid >> 4;
      int p4 = (tid & 15) << 2;
#pragma unroll
      for (int rep = 0; rep < 4; ++rep) {
        int si = rep*16 + lrow;
        const float* row = XT + ((size_t)bi*SEQLEN + (c*CHUNK + s0 + si))*CONV_DIM;
        *(float4*)&xs[si][p4] = *(const float4*)(row + h*HEADDIM + p4);
        *(float4*)&bs[si][p4] = *(const float4*)(row + D_INNER + p4);
      }
      __syncthreads();
      for (int si = 0; si < 64; ++si) {
        float xv = Gs[s0+si] * xs[si][p];
        const float4* bp = (const float4*)&bs[si][ng*16];
#pragma unroll
        for (int q = 0; q < 4; ++q) {
          float4 b4 = bp[q];
          S[q*4+0] += xv * b4.x; S[q*4+1] += xv * b4.y;
          S[q*4+2] += xv * b4.z; S[q*4+3] += xv * b4.w;
        }
      }
    }
  }
}

// ---------------- Y = intra(triangular) + inter (fwd only) ----------------
__global__ __launch_bounds__(256) void yscan_kernel(const float* __restrict__ XT,
                                                    const float* __restrict__ DTt,
                                                    const float* __restrict__ CBs,
                                                    const float* __restrict__ SPREV,
                                                    const float* __restrict__ A_log,
                                                    float* __restrict__ Y) {
  __shared__ float xs[64][64];        // x tile; reused as SPt[n][p] for inter
  __shared__ float ctn[CHUNK][17];    // E[t]*C[t][n-tile]
  __shared__ float dts[CHUNK];
  __shared__ float cums[CHUNK];
  int tid = threadIdx.x;
  int c = blockIdx.x;
  int rh = blockIdx.y;
  int h = rh & 31;
  int r = rh >> 5;
  int bi = r & 1;
  float A = -__expf(A_log[h]);
  dts[tid] = DTt[((size_t)r*NHEADS + h)*SEQLEN + c*CHUNK + tid];
  __syncthreads();
  if (tid == 0) {
    float run = 0.f;
    for (int s2 = 0; s2 < CHUNK; ++s2) { run += dts[s2] * A; cums[s2] = run; }
  }
  __syncthreads();
  int tslot = tid >> 2;   // t = tslot*4 + i
  int pg = tid & 3;       // p = pg*16 + j
  float cum_t[4];
#pragma unroll
  for (int i = 0; i < 4; ++i) cum_t[i] = cums[tslot*4 + i];
  float acc[4][16];
#pragma unroll
  for (int i = 0; i < 4; ++i)
#pragma unroll
    for (int j = 0; j < 16; ++j) acc[i][j] = 0.f;
  size_t cbbase = (((size_t)r*NCH + c) * CHUNK) * CHUNK;
  for (int st = 0; st < 4; ++st) {
    int s0 = st * 64;
    __syncthreads();
    {
      int lrow = tid >> 4;
      int p4 = (tid & 15) << 2;
#pragma unroll
      for (int rep = 0; rep < 4; ++rep) {
        int si = rep*16 + lrow;
        int L = c*CHUNK + s0 + si;
        if (r >= 2) L = flip_l(L);
        *(float4*)&xs[si][p4] =
            *(const float4*)(XT + ((size_t)bi*SEQLEN + L)*CONV_DIM + h*HEADDIM + p4);
      }
    }
    __syncthreads();
    if (tslot*4 + 3 >= s0) {   // wave-uniform skip (t-range below s-tile)
      const float* cbrow = CBs + cbbase + (size_t)s0*CHUNK + tslot*4;
      float4 cbnext = *(const float4*)cbrow;
      for (int si = 0; si < 64; ++si) {
        float4 cb4 = cbnext;
        if (si < 63) cbnext = *(const float4*)(cbrow + (size_t)(si+1)*CHUNK);
        int s = s0 + si;
        float dtv = dts[s];
        float cs = cums[s];
        const float4* xp = (const float4*)&xs[si][pg*16];
        float4 x0 = xp[0], x1 = xp[1], x2 = xp[2], x3 = xp[3];
        float wv[4] = {cb4.x, cb4.y, cb4.z, cb4.w};
#pragma unroll
        for (int i = 0; i < 4; ++i) {
          int t = tslot*4 + i;
          float wgt = 0.f;
          if (s <= t) wgt = wv[i] * __expf(cum_t[i] - cs) * dtv;
          acc[i][0] += wgt*x0.x; acc[i][1] += wgt*x0.y; acc[i][2] += wgt*x0.z; acc[i][3] += wgt*x0.w;
          acc[i][4] += wgt*x1.x; acc[i][5] += wgt*x1.y; acc[i][6] += wgt*x1.z; acc[i][7] += wgt*x1.w;
          acc[i][8] += wgt*x2.x; acc[i][9] += wgt*x2.y; acc[i][10]+= wgt*x2.z; acc[i][11]+= wgt*x2.w;
          acc[i][12]+= wgt*x3.x; acc[i][13]+= wgt*x3.y; acc[i][14]+= wgt*x3.z; acc[i][15]+= wgt*x3.w;
        }
      }
    }
  }
  if (r < 2) {   // inter-chunk term (reverse has zero prev-state by construction)
    __syncthreads();
    {
      int lrow = tid >> 4;
      int n4 = (tid & 15) << 2;
#pragma unroll
      for (int rep = 0; rep < 4; ++rep) {
        int pp = rep*16 + lrow;
        float4 v = *(const float4*)(SPREV +
            ((((size_t)r*NCH + c)*NHEADS + h)*HEADDIM + pp)*D_STATE + n4);
        xs[n4+0][pp] = v.x; xs[n4+1][pp] = v.y; xs[n4+2][pp] = v.z; xs[n4+3][pp] = v.w;
      }
    }
    float et_self = __expf(cums[tid]);
    const float* crow = XT + ((size_t)bi*SEQLEN + c*CHUNK + tid)*CONV_DIM + D_INNER + GN;
    for (int nt = 0; nt < 4; ++nt) {
      __syncthreads();
#pragma unroll
      for (int nl = 0; nl < 16; ++nl) ctn[tid][nl] = crow[nt*16 + nl] * et_self;
      __syncthreads();
#pragma unroll
      for (int nl = 0; nl < 16; ++nl) {
        int n = nt*16 + nl;
        const float4* spp = (const float4*)&xs[n][pg*16];
        float4 s0v = spp[0], s1v = spp[1], s2v = spp[2], s3v = spp[3];
#pragma unroll
        for (int i = 0; i < 4; ++i) {
          float cv = ctn[tslot*4 + i][nl];
          acc[i][0] += cv*s0v.x; acc[i][1] += cv*s0v.y; acc[i][2] += cv*s0v.z; acc[i][3] += cv*s0v.w;
          acc[i][4] += cv*s1v.x; acc[i][5] += cv*s1v.y; acc[i][6] += cv*s1v.z; acc[i][7] += cv*s1v.w;
          acc[i][8] += cv*s2v.x; acc[i][9] += cv*s2v.y; acc[i][10]+= cv*s2v.z; acc[i][11]+= cv*s2v.w;
          acc[i][12]+= cv*s3v.x; acc[i][13]+= cv*s3v.y; acc[i][14]+= cv*s3v.w; acc[i][15]+= cv*s3v.w;
        }
      }
    }
  }
  size_t ybase = ((size_t)r*SEQLEN + c*CHUNK)*D_INNER + h*HEADDIM + pg*16;
#pragma unroll
  for (int i = 0; i < 4; ++i) {
    float* yp = Y + ybase + (size_t)(tslot*4 + i)*D_INNER;
    ((float4*)yp)[0] = make_float4(acc[i][0],  acc[i][1],  acc[i][2],  acc[i][3]);
    ((float4*)yp)[1] = make_float4(acc[i][4],  acc[i][5],  acc[i][6],  acc[i][7]);
    ((float4*)yp)[2] = make_float4(acc[i][8],  acc[i][9],  acc[i][10], acc[i][11]);
    ((float4*)yp)[3] = make_float4(acc[i][12], acc[i][13], acc[i][14], acc[i][15]);
  }
}

// ---------------- shifts + x_res + RMSNorm + gate (-> bf16) ----------------
__global__ __launch_bounds__(256) void combine_kernel(const float* __restrict__ Y,
                                                      const float* __restrict__ XT,
                                                      const float* __restrict__ FCD,
                                                      const float* __restrict__ Dp,
                                                      const float* __restrict__ Z,
                                                      const float* __restrict__ norm_w,
                                                      unsigned short* __restrict__ YPb) {
  __shared__ float red[256];
  int row = blockIdx.x;     // bi*SEQLEN + l
  int bi = row >> 11;
  int l = row & 2047;
  int s = l >> 3, fr = l & 7;
  int tid = threadIdx.x;
  const float* yf = (l >= 1) ? Y + ((size_t)bi*SEQLEN + (l-1))*D_INNER : nullptr;
  const float* yr = (s >= 1) ? Y + ((size_t)(2+bi)*SEQLEN + ((s-1)*8 + (7-fr)))*D_INNER : nullptr;
  const float* xr = XT + ((size_t)bi*SEQLEN + l)*CONV_DIM;
  const float* fc = FCD + (size_t)row*NHEADS;
  float v[8];
  float ss = 0.f;
#pragma unroll
  for (int q = 0; q < 8; ++q) {
    int d = q*256 + tid;
    float val = xr[d] * (fc[d >> 6] + Dp[d >> 6]);
    if (yf) val += yf[d];
    if (yr) val += yr[d];
    v[q] = val;
    ss += val * val;
  }
  red[tid] = ss;
  __syncthreads();
  for (int ofs = 128; ofs > 0; ofs >>= 1) {
    if (tid < ofs) red[tid] += red[tid + ofs];
    __syncthreads();
  }
  float rs = rsqrtf(red[0] / (float)D_INNER + 1e-5f);
  const float* zrow = Z + ((size_t)bi*SEQLEN + l)*ZLD;
#pragma unroll
  for (int q = 0; q < 8; ++q) {
    int d = q*256 + tid;
    YPb[(size_t)row*D_INNER + d] = f2bf(v[q] * rs * norm_w[d] * silu_f(zrow[d]));
  }
}

extern "C" void kernel_launch(void* const* d_in, const int* in_sizes, int n_in,
                              void* d_out, int out_size, void* d_ws, size_t ws_size,
                              hipStream_t stream) {
  (void)in_sizes; (void)n_in; (void)out_size; (void)ws_size;
  const float* u          = (const float*)d_in[0];
  const float* in_proj_w  = (const float*)d_in[1];
  const float* conv_sp_w  = (const float*)d_in[2];
  const float* conv_sp_b  = (const float*)d_in[3];
  const float* conv_tp_w  = (const float*)d_in[4];
  const float* conv_tp_b  = (const float*)d_in[5];
  const float* dt_bias    = (const float*)d_in[6];
  const float* A_log      = (const float*)d_in[7];
  const float* Dp         = (const float*)d_in[8];
  const float* fc_D_w     = (const float*)d_in[9];
  const float* norm_w     = (const float*)d_in[10];
  const float* out_proj_w = (const float*)d_in[11];
  float* out = (float*)d_out;
  float* ws = (float*)d_ws;

  // workspace layout (f32 elements)
  float* Z     = ws;                       // 4096*4352 = 17,825,792
  float* SH    = Z     + 17825792ULL;      // 9,437,184  (XS -> CBs -> YPb)
  float* XT    = SH    + 9437184ULL;       // 9,437,184
  float* DTt   = XT    + 9437184ULL;       // 262,144
  float* Yb    = DTt   + 262144ULL;        // 16,777,216 (also hosts bf16 staging early)
  float* SPREV = Yb    + 16777216ULL;      // 2,097,152
  float* FCD   = SPREV + 2097152ULL;       // 131,072
  float* DTraw = FCD   + 131072ULL;        // 262,144

  // bf16 aliases inside Yb (dead before yscan writes Yb)
  unsigned short* Ub  = (unsigned short*)Yb;                 // 4,194,304 shorts
  unsigned short* Wb  = (unsigned short*)Yb + 4194304ULL;    // 4,456,448 shorts
  // bf16 aliases for the tail (after combine, Yb & early aliases dead)
  unsigned short* Wob = (unsigned short*)Yb;                 // 2,097,152 shorts
  unsigned short* YPb = (unsigned short*)SH;                 // 8,388,608 shorts

  // 1. casts for in_proj
  cast_bf16_kernel<<<4096, 256, 0, stream>>>(u, Ub);                  // 4096x1024
  cast_bf16_kernel<<<4352, 256, 0, stream>>>(in_proj_w, Wb);          // first 4352 rows
  // 2. z+xBC = u @ in_proj_w[0:4352]^T  (bf16 MFMA, M=4096 N=4352 K=1024)
  gemm_bf16<<<dim3(34, 32), 256, 0, stream>>>(Ub, 1024, Wb, 1024, Z, ZLD, 1024);
  // 3. dt_raw = u @ in_proj_w[4352:4416]^T  (f32 — protects exp-amplified path)
  gemm_bt_f32<<<dim3(1, 64), 256, 0, stream>>>(u, 1024, in_proj_w + 4352ULL*1024, 1024,
                                               DTraw, 64, 64, 1024);
  // 4. dt (flip + bias + softplus)
  dt_kernel<<<1024, 256, 0, stream>>>(DTraw, dt_bias, DTt);
  // 5. spatial conv + silu  (Z -> SH as XS)
  conv_sp_kernel<<<36864, 256, 0, stream>>>(Z, conv_sp_w, conv_sp_b, SH);
  // 6. temporal causal conv + silu (SH -> XT)
  conv_tp_kernel<<<36864, 256, 0, stream>>>(SH, conv_tp_w, conv_tp_b, XT);
  // 7. FCD = x @ fc_D_w^T          (M=4096, N=32, K=2048, lda=2304)
  gemm_bt_f32<<<dim3(1, 64), 256, 0, stream>>>(XT, 2304, fc_D_w, 2048, FCD, 32, 32, 2048);
  // 8. CB[s][t] per (r,c)  (XT -> SH as CBs)
  cb_kernel<<<dim3(16, 8, 4), 256, 0, stream>>>(XT, SH);
  // 9. sequential chunk states (forward only)
  state_kernel<<<dim3(32, 2), 256, 0, stream>>>(XT, DTt, A_log, SPREV);
  // 10. Y = intra + inter
  yscan_kernel<<<dim3(8, 128), 256, 0, stream>>>(XT, DTt, SH, SPREV, A_log, Yb);
  // 11. shifts + x_res + RMSNorm + gate (-> YPb bf16 in SH)
  combine_kernel<<<4096, 256, 0, stream>>>(Yb, XT, FCD, Dp, Z, norm_w, YPb);
  // 12. cast out_proj_w (Yb region now dead)
  cast_bf16_kernel<<<2048, 256, 0, stream>>>(out_proj_w, Wob);
  // 13. out = YP @ out_proj_w^T    (bf16 MFMA, M=4096 N=1024 K=2048)
  gemm_bf16<<<dim3(8, 32), 256, 0, stream>>>(YPb, 2048, Wob, 2048, out, 1024, 2048);
}

// Round 3
// 720.656 us; speedup vs baseline: 2.0320x; 1.1874x over previous
//
#include <hip/hip_runtime.h>
#include <hip/hip_bf16.h>
#include <math.h>

#define D_STATE   64
#define HEADDIM   64
#define D_INNER   2048
#define NHEADS    32
#define GN        64
#define CONV_DIM  2304
#define D_IN_PROJ 4416
#define ZLD       4352      /* z + xBC columns only (dt handled separately) */
#define K_SP      7
#define K_TP      4
#define CHUNK     256
#define BATCHN    2
#define FRAMES    8
#define SPATIAL   256
#define SEQLEN    2048
#define NCH       8
#define MTOT      4096

typedef __attribute__((ext_vector_type(8))) short short8;
typedef __attribute__((ext_vector_type(4))) float floatx4;

__device__ __forceinline__ float silu_f(float x) { return x / (1.f + __expf(-x)); }
__device__ __forceinline__ int flip_l(int l) { return (l & ~7) | (7 - (l & 7)); }
__device__ __forceinline__ unsigned short f2bf(float f) {
  unsigned int u = __float_as_uint(f);
  unsigned int r = (u + 0x7fffu + ((u >> 16) & 1u)) >> 16;
  return (unsigned short)r;
}
__device__ __forceinline__ void gload_lds16(const unsigned short* g, unsigned short* l) {
  __builtin_amdgcn_global_load_lds((const __attribute__((address_space(1))) void*)g,
                                   (__attribute__((address_space(3))) void*)l, 16, 0, 0);
}

// ---------------- f32 -> bf16 cast ----------------
__global__ __launch_bounds__(256) void cast_bf16_kernel(const float* __restrict__ in,
                                                        unsigned short* __restrict__ out) {
  size_t i = ((size_t)blockIdx.x * 256 + threadIdx.x) * 4;
  float4 v = *(const float4*)(in + i);
  ushort4 o;
  o.x = f2bf(v.x); o.y = f2bf(v.y); o.z = f2bf(v.z); o.w = f2bf(v.w);
  *(ushort4*)(out + i) = o;
}

// ---------------- bf16 MFMA GEMM: C = A * B^T ----------------
__global__ __launch_bounds__(256) void gemm_bf16(
    const unsigned short* __restrict__ A, int lda,
    const unsigned short* __restrict__ B, int ldb,
    float* __restrict__ C, int ldc, int K) {
  __shared__ unsigned short As[128 * 32];
  __shared__ unsigned short Bs[128 * 32];
  const int tid = threadIdx.x;
  const int lane = tid & 63;
  const int w = tid >> 6;
  const int m0 = blockIdx.y * 128;
  const int n0 = blockIdx.x * 128;
  const int wm = (w >> 1) * 64;
  const int wn = (w & 1) * 64;
  const int srow = lane >> 2;
  const int scol = (lane & 3) * 8;
  floatx4 acc[4][4] = {};
  for (int k0 = 0; k0 < K; k0 += 32) {
#pragma unroll
    for (int it = 0; it < 2; ++it) {
      int ch = it * 4 + w;
      const unsigned short* ga = A + (size_t)(m0 + ch * 16 + srow) * lda + k0 + scol;
      const unsigned short* gb = B + (size_t)(n0 + ch * 16 + srow) * ldb + k0 + scol;
      gload_lds16(ga, &As[ch * 512]);
      gload_lds16(gb, &Bs[ch * 512]);
    }
    __syncthreads();
    const int fr = lane & 15;
    const int kq = (lane >> 4) * 8;
    short8 af[4], bfr[4];
#pragma unroll
    for (int i = 0; i < 4; ++i)
      af[i] = *(const short8*)&As[(wm + i * 16 + fr) * 32 + kq];
#pragma unroll
    for (int j = 0; j < 4; ++j)
      bfr[j] = *(const short8*)&Bs[(wn + j * 16 + fr) * 32 + kq];
#pragma unroll
    for (int i = 0; i < 4; ++i)
#pragma unroll
      for (int j = 0; j < 4; ++j)
        acc[i][j] = __builtin_amdgcn_mfma_f32_16x16x32_bf16(af[i], bfr[j], acc[i][j], 0, 0, 0);
    __syncthreads();
  }
  const int col = lane & 15;
  const int rg = (lane >> 4) * 4;
#pragma unroll
  for (int i = 0; i < 4; ++i)
#pragma unroll
    for (int j = 0; j < 4; ++j)
#pragma unroll
      for (int r = 0; r < 4; ++r)
        C[(size_t)(m0 + wm + i * 16 + rg + r) * ldc + (n0 + wn + j * 16 + col)] = acc[i][j][r];
}

// ---------------- f32 tiled GEMM: C = A * B^T (dt cols + fc_D) ----------------
__global__ __launch_bounds__(256) void gemm_bt_f32(
    const float* __restrict__ A, int lda,
    const float* __restrict__ B, int ldb,
    float* __restrict__ C, int ldc,
    int N, int K) {
  __shared__ float As[16][64];
  __shared__ float Bs[16][64];
  const int tid = threadIdx.x;
  const int tx = tid & 15, ty = tid >> 4;
  const int m0 = blockIdx.y * 64;
  const int n0 = blockIdx.x * 64;
  const int lm = tid >> 2;
  const int lk = (tid & 3) << 2;
  const float* Ag = A + (size_t)(m0 + lm) * lda + lk;
  const float* Bg = B + (size_t)(n0 + lm) * ldb + lk;
  const bool bvalid = (n0 + lm) < N;
  float acc[4][4] = {{0.f,0.f,0.f,0.f},{0.f,0.f,0.f,0.f},{0.f,0.f,0.f,0.f},{0.f,0.f,0.f,0.f}};
  for (int k0 = 0; k0 < K; k0 += 16) {
    float4 av = *(const float4*)(Ag + k0);
    float4 bv = bvalid ? *(const float4*)(Bg + k0) : make_float4(0.f,0.f,0.f,0.f);
    __syncthreads();
    As[lk+0][lm] = av.x; As[lk+1][lm] = av.y; As[lk+2][lm] = av.z; As[lk+3][lm] = av.w;
    Bs[lk+0][lm] = bv.x; Bs[lk+1][lm] = bv.y; Bs[lk+2][lm] = bv.z; Bs[lk+3][lm] = bv.w;
    __syncthreads();
#pragma unroll
    for (int kk = 0; kk < 16; ++kk) {
      float4 a4 = *(const float4*)&As[kk][ty << 2];
      float4 b4 = *(const float4*)&Bs[kk][tx << 2];
      float ar[4] = {a4.x, a4.y, a4.z, a4.w};
      float br[4] = {b4.x, b4.y, b4.z, b4.w};
#pragma unroll
      for (int i = 0; i < 4; ++i)
#pragma unroll
        for (int j = 0; j < 4; ++j)
          acc[i][j] += ar[i] * br[j];
    }
  }
  const int n = n0 + (tx << 2);
  if (n < N) {
#pragma unroll
    for (int i = 0; i < 4; ++i) {
      float4 o = make_float4(acc[i][0], acc[i][1], acc[i][2], acc[i][3]);
      *(float4*)(C + (size_t)(m0 + (ty<<2) + i) * ldc + n) = o;
    }
  }
}

// ---------------- dt = softplus(dt_raw + bias), flip for reverse ----------------
__global__ __launch_bounds__(256) void dt_kernel(const float* __restrict__ DTraw,
                                                 const float* __restrict__ dt_bias,
                                                 float* __restrict__ DTt) {
  int idx = blockIdx.x * 256 + threadIdx.x;
  int l  = idx & 2047;
  int rh = idx >> 11;
  int h  = rh & 31;
  int r  = rh >> 5;
  int bi = r & 1;
  int ls = (r < 2) ? l : flip_l(l);
  int ch = (r < 2) ? h : NHEADS + h;
  float raw = DTraw[((size_t)bi * SEQLEN + ls) * 64 + ch] + dt_bias[h];
  DTt[idx] = (raw > 20.f) ? raw : log1pf(__expf(raw));
}

// ---------------- spatial depthwise conv (same pad) + silu ----------------
__global__ __launch_bounds__(256) void conv_sp_kernel(const float* __restrict__ Z,
                                                      const float* __restrict__ w,
                                                      const float* __restrict__ b,
                                                      float* __restrict__ XS) {
  size_t idx = (size_t)blockIdx.x * 256 + threadIdx.x;
  int c = (int)(idx % CONV_DIM);
  size_t t = idx / CONV_DIM;
  int l = (int)(t & 2047);
  int bi = (int)(t >> 11);
  int s = l >> 3, fr = l & 7;
  float acc = b[c];
  const float* wc = w + c * K_SP;
#pragma unroll
  for (int j = 0; j < K_SP; ++j) {
    int ss = s + j - 3;
    if (0 <= ss && ss < SPATIAL)
      acc += wc[j] * Z[((size_t)bi * SEQLEN + (ss*8 + fr)) * ZLD + D_INNER + c];
  }
  XS[idx] = silu_f(acc);
}

// ---------------- temporal depthwise conv (causal) + silu ----------------
__global__ __launch_bounds__(256) void conv_tp_kernel(const float* __restrict__ XS,
                                                      const float* __restrict__ w,
                                                      const float* __restrict__ b,
                                                      float* __restrict__ XT) {
  size_t idx = (size_t)blockIdx.x * 256 + threadIdx.x;
  int c = (int)(idx % CONV_DIM);
  size_t t = idx / CONV_DIM;
  int l = (int)(t & 2047);
  int bi = (int)(t >> 11);
  int s = l >> 3, fr = l & 7;
  float acc = b[c];
  const float* wc = w + c * K_TP;
#pragma unroll
  for (int j = 0; j < K_TP; ++j) {
    int ff = fr + j - (K_TP - 1);
    if (ff >= 0)
      acc += wc[j] * XS[((size_t)bi * SEQLEN + (s*8 + ff)) * CONV_DIM + c];
  }
  XT[idx] = silu_f(acc);
}

// ---------------- CB[t][s] = sum_n C[t][n] B[s][n], per (r,c)  (t-major!) ----------------
__global__ __launch_bounds__(256) void cb_kernel(const float* __restrict__ XT,
                                                 float* __restrict__ CBs) {
  __shared__ float Ct[64][65];
  __shared__ float Bt[64][65];
  int tid = threadIdx.x;
  int t0 = (blockIdx.x & 3) * 64;
  int s0 = (blockIdx.x >> 2) * 64;
  if (s0 > t0) return;   // strictly-upper tiles never read (mask s<=t)
  int c = blockIdx.y;
  int r = blockIdx.z;
  int bi = r & 1;
  int bOff = D_INNER + ((r < 2) ? 0 : 2*GN);
  int cOff = bOff + GN;
  int lrow = tid >> 4;
  int n4 = (tid & 15) << 2;
#pragma unroll
  for (int rep = 0; rep < 4; ++rep) {
    int tl = rep * 16 + lrow;
    int Lc = c * CHUNK + t0 + tl;
    int Ls = c * CHUNK + s0 + tl;
    if (r >= 2) { Lc = flip_l(Lc); Ls = flip_l(Ls); }
    float4 cv = *(const float4*)(XT + ((size_t)bi*SEQLEN + Lc)*CONV_DIM + cOff + n4);
    float4 bv = *(const float4*)(XT + ((size_t)bi*SEQLEN + Ls)*CONV_DIM + bOff + n4);
    Ct[n4+0][tl] = cv.x; Ct[n4+1][tl] = cv.y; Ct[n4+2][tl] = cv.z; Ct[n4+3][tl] = cv.w;
    Bt[n4+0][tl] = bv.x; Bt[n4+1][tl] = bv.y; Bt[n4+2][tl] = bv.z; Bt[n4+3][tl] = bv.w;
  }
  __syncthreads();
  int txx = tid & 15;
  int tyy = tid >> 4;
  float acc[4][4] = {{0.f,0.f,0.f,0.f},{0.f,0.f,0.f,0.f},{0.f,0.f,0.f,0.f},{0.f,0.f,0.f,0.f}};
#pragma unroll
  for (int n = 0; n < D_STATE; ++n) {
    float cr[4], br[4];
#pragma unroll
    for (int i = 0; i < 4; ++i) cr[i] = Ct[n][tyy + 16*i];   // t rows
#pragma unroll
    for (int j = 0; j < 4; ++j) br[j] = Bt[n][txx + 16*j];   // s cols
#pragma unroll
    for (int i = 0; i < 4; ++i)
#pragma unroll
      for (int j = 0; j < 4; ++j)
        acc[i][j] += cr[i] * br[j];
  }
  size_t base = (((size_t)r*NCH + c) * CHUNK) * CHUNK;
#pragma unroll
  for (int i = 0; i < 4; ++i)
#pragma unroll
    for (int j = 0; j < 4; ++j)
      CBs[base + (size_t)(t0 + tyy + 16*i)*CHUNK + (s0 + txx + 16*j)] = acc[i][j];
}

// ---------------- sequential chunk states (forward r=0,1 only) ----------------
__global__ __launch_bounds__(256) void state_kernel(const float* __restrict__ XT,
                                                    const float* __restrict__ DTt,
                                                    const float* __restrict__ A_log,
                                                    float* __restrict__ SPREV) {
  __shared__ float xs[64][64];
  __shared__ float bs[64][64];
  __shared__ float dts[CHUNK];
  __shared__ float cums[CHUNK];
  __shared__ float Gs[CHUNK];
  int tid = threadIdx.x;
  int h = blockIdx.x;
  int r = blockIdx.y;    // 0..1
  int bi = r;
  float A = -__expf(A_log[h]);
  int p  = tid & 63;
  int ng = tid >> 6;
  float S[16];
#pragma unroll
  for (int j = 0; j < 16; ++j) S[j] = 0.f;
  for (int c = 0; c < NCH; ++c) {
    size_t pb = ((((size_t)r*NCH + c)*NHEADS + h) * HEADDIM + p) * D_STATE + ng*16;
#pragma unroll
    for (int j = 0; j < 16; ++j) SPREV[pb + j] = S[j];
    __syncthreads();
    float dv = DTt[((size_t)r*NHEADS + h)*SEQLEN + c*CHUNK + tid];
    dts[tid] = dv;
    float run = dv * A;
    cums[tid] = run;
    __syncthreads();
#pragma unroll
    for (int ofs = 1; ofs < 256; ofs <<= 1) {
      float add = (tid >= ofs) ? cums[tid - ofs] : 0.f;
      __syncthreads();
      run += add;
      cums[tid] = run;
      __syncthreads();
    }
    float cl = cums[CHUNK-1];
    Gs[tid] = __expf(cl - cums[tid]) * dts[tid];
    float dec = __expf(cl);
#pragma unroll
    for (int j = 0; j < 16; ++j) S[j] *= dec;
    for (int st = 0; st < 4; ++st) {
      int s0 = st * 64;
      __syncthreads();
      int lrow = tid >> 4;
      int p4 = (tid & 15) << 2;
#pragma unroll
      for (int rep = 0; rep < 4; ++rep) {
        int si = rep*16 + lrow;
        const float* row = XT + ((size_t)bi*SEQLEN + (c*CHUNK + s0 + si))*CONV_DIM;
        *(float4*)&xs[si][p4] = *(const float4*)(row + h*HEADDIM + p4);
        *(float4*)&bs[si][p4] = *(const float4*)(row + D_INNER + p4);
      }
      __syncthreads();
      for (int si = 0; si < 64; ++si) {
        float xv = Gs[s0+si] * xs[si][p];
        const float4* bp = (const float4*)&bs[si][ng*16];
#pragma unroll
        for (int q = 0; q < 4; ++q) {
          float4 b4 = bp[q];
          S[q*4+0] += xv * b4.x; S[q*4+1] += xv * b4.y;
          S[q*4+2] += xv * b4.z; S[q*4+3] += xv * b4.w;
        }
      }
    }
  }
}

// ---------------- Y = intra(triangular, MFMA) + inter (MFMA, fwd only) ----------------
__global__ __launch_bounds__(256) void yscan_kernel(const float* __restrict__ XT,
                                                    const float* __restrict__ DTt,
                                                    const float* __restrict__ CBs,
                                                    const float* __restrict__ SPREV,
                                                    const float* __restrict__ A_log,
                                                    float* __restrict__ Y) {
  __shared__ unsigned short Xb[64][40];  // X slab transposed [p][s], padded
  __shared__ float dts[CHUNK];
  __shared__ float cums[CHUNK];
  int tid = threadIdx.x;
  int lane = tid & 63;
  int w = tid >> 6;
  int c = blockIdx.x;
  int rh = blockIdx.y;
  int h = rh & 31;
  int r = rh >> 5;
  int bi = r & 1;
  float A = -__expf(A_log[h]);
  // dt load + parallel inclusive scan of dt*A
  float dv = DTt[((size_t)r*NHEADS + h)*SEQLEN + c*CHUNK + tid];
  dts[tid] = dv;
  float run = dv * A;
  cums[tid] = run;
  __syncthreads();
#pragma unroll
  for (int ofs = 1; ofs < 256; ofs <<= 1) {
    float add = (tid >= ofs) ? cums[tid - ofs] : 0.f;
    __syncthreads();
    run += add;
    cums[tid] = run;
    __syncthreads();
  }
  const int fr = lane & 15;
  const int kq = (lane >> 4) * 8;
  const int wt0 = w * 64;
  float ct[4];
#pragma unroll
  for (int i = 0; i < 4; ++i) ct[i] = cums[wt0 + i*16 + fr];
  floatx4 acc[4][4] = {};
  size_t cbbase = (((size_t)r*NCH + c) * CHUNK) * CHUNK;
  const int maxsl = 2*w + 1;
  for (int sl = 0; sl < 8; ++sl) {
    int s0 = sl * 32;
    __syncthreads();
    {   // stage X slab transposed -> Xb[p][s] (all waves cooperate)
      int srow = tid >> 3;          // 0..31
      int p0 = (tid & 7) * 4;
      int L = c*CHUNK + s0 + srow;
      if (r >= 2) L = flip_l(L);
      const float* xrow = XT + ((size_t)bi*SEQLEN + L)*CONV_DIM + h*HEADDIM;
#pragma unroll
      for (int half = 0; half < 2; ++half) {
        float4 v = *(const float4*)(xrow + p0 + half*32);
        Xb[p0 + half*32 + 0][srow] = f2bf(v.x);
        Xb[p0 + half*32 + 1][srow] = f2bf(v.y);
        Xb[p0 + half*32 + 2][srow] = f2bf(v.z);
        Xb[p0 + half*32 + 3][srow] = f2bf(v.w);
      }
    }
    __syncthreads();
    if (sl <= maxsl) {   // wave-uniform triangular skip
      float cs[8], dtv[8];
#pragma unroll
      for (int j = 0; j < 8; ++j) { cs[j] = cums[s0 + kq + j]; dtv[j] = dts[s0 + kq + j]; }
      short8 bfr[4];
#pragma unroll
      for (int j = 0; j < 4; ++j)
        bfr[j] = *(const short8*)&Xb[j*16 + fr][kq];
#pragma unroll
      for (int i = 0; i < 4; ++i) {
        int t = wt0 + i*16 + fr;
        const float* cbrow = CBs + cbbase + (size_t)t*CHUNK + s0 + kq;
        float4 c0 = *(const float4*)cbrow;
        float4 c1 = *(const float4*)(cbrow + 4);
        float cb[8] = {c0.x,c0.y,c0.z,c0.w,c1.x,c1.y,c1.z,c1.w};
        short8 af;
#pragma unroll
        for (int j = 0; j < 8; ++j) {
          int s = s0 + kq + j;
          float wv = (s <= t) ? cb[j] * __expf(ct[i] - cs[j]) * dtv[j] : 0.f;
          af[j] = (short)f2bf(wv);
        }
#pragma unroll
        for (int j = 0; j < 4; ++j)
          acc[i][j] = __builtin_amdgcn_mfma_f32_16x16x32_bf16(af, bfr[j], acc[i][j], 0, 0, 0);
      }
    }
  }
  if (r < 2) {   // inter-chunk term: (E*C) @ Sprev^T   (reverse prev-state == 0)
    float ect[4];
#pragma unroll
    for (int i = 0; i < 4; ++i) ect[i] = __expf(ct[i]);
    const float* spbase = SPREV + (((size_t)r*NCH + c)*NHEADS + h) * (size_t)(HEADDIM*D_STATE);
#pragma unroll
    for (int ns = 0; ns < 2; ++ns) {
      int n0 = ns * 32;
      short8 bfr[4];
#pragma unroll
      for (int j = 0; j < 4; ++j) {
        const float* sp = spbase + (size_t)(j*16 + fr)*D_STATE + n0 + kq;
        float4 s0v = *(const float4*)sp;
        float4 s1v = *(const float4*)(sp + 4);
        short8 bb;
        bb[0]=(short)f2bf(s0v.x); bb[1]=(short)f2bf(s0v.y); bb[2]=(short)f2bf(s0v.z); bb[3]=(short)f2bf(s0v.w);
        bb[4]=(short)f2bf(s1v.x); bb[5]=(short)f2bf(s1v.y); bb[6]=(short)f2bf(s1v.z); bb[7]=(short)f2bf(s1v.w);
        bfr[j] = bb;
      }
#pragma unroll
      for (int i = 0; i < 4; ++i) {
        int t = wt0 + i*16 + fr;
        const float* crow = XT + ((size_t)bi*SEQLEN + c*CHUNK + t)*CONV_DIM + D_INNER + GN + n0 + kq;
        float4 c0 = *(const float4*)crow;
        float4 c1 = *(const float4*)(crow + 4);
        short8 af;
        af[0]=(short)f2bf(c0.x*ect[i]); af[1]=(short)f2bf(c0.y*ect[i]);
        af[2]=(short)f2bf(c0.z*ect[i]); af[3]=(short)f2bf(c0.w*ect[i]);
        af[4]=(short)f2bf(c1.x*ect[i]); af[5]=(short)f2bf(c1.y*ect[i]);
        af[6]=(short)f2bf(c1.z*ect[i]); af[7]=(short)f2bf(c1.w*ect[i]);
#pragma unroll
        for (int j = 0; j < 4; ++j)
          acc[i][j] = __builtin_amdgcn_mfma_f32_16x16x32_bf16(af, bfr[j], acc[i][j], 0, 0, 0);
      }
    }
  }
  // epilogue: C/D layout col=lane&15, row=(lane>>4)*4+reg
  const int rg = (lane >> 4) * 4;
  size_t ybase = ((size_t)r*SEQLEN + c*CHUNK)*D_INNER + h*HEADDIM;
#pragma unroll
  for (int i = 0; i < 4; ++i)
#pragma unroll
    for (int j = 0; j < 4; ++j)
#pragma unroll
      for (int q = 0; q < 4; ++q)
        Y[ybase + (size_t)(wt0 + i*16 + rg + q)*D_INNER + j*16 + fr] = acc[i][j][q];
}

// ---------------- shifts + x_res + RMSNorm + gate (-> bf16) ----------------
__global__ __launch_bounds__(256) void combine_kernel(const float* __restrict__ Y,
                                                      const float* __restrict__ XT,
                                                      const float* __restrict__ FCD,
                                                      const float* __restrict__ Dp,
                                                      const float* __restrict__ Z,
                                                      const float* __restrict__ norm_w,
                                                      unsigned short* __restrict__ YPb) {
  __shared__ float red[256];
  int row = blockIdx.x;
  int bi = row >> 11;
  int l = row & 2047;
  int s = l >> 3, fr = l & 7;
  int tid = threadIdx.x;
  const float* yf = (l >= 1) ? Y + ((size_t)bi*SEQLEN + (l-1))*D_INNER : nullptr;
  const float* yr = (s >= 1) ? Y + ((size_t)(2+bi)*SEQLEN + ((s-1)*8 + (7-fr)))*D_INNER : nullptr;
  const float* xr = XT + ((size_t)bi*SEQLEN + l)*CONV_DIM;
  const float* fc = FCD + (size_t)row*NHEADS;
  float v[8];
  float ss = 0.f;
#pragma unroll
  for (int q = 0; q < 8; ++q) {
    int d = q*256 + tid;
    float val = xr[d] * (fc[d >> 6] + Dp[d >> 6]);
    if (yf) val += yf[d];
    if (yr) val += yr[d];
    v[q] = val;
    ss += val * val;
  }
  red[tid] = ss;
  __syncthreads();
  for (int ofs = 128; ofs > 0; ofs >>= 1) {
    if (tid < ofs) red[tid] += red[tid + ofs];
    __syncthreads();
  }
  float rs = rsqrtf(red[0] / (float)D_INNER + 1e-5f);
  const float* zrow = Z + ((size_t)bi*SEQLEN + l)*ZLD;
#pragma unroll
  for (int q = 0; q < 8; ++q) {
    int d = q*256 + tid;
    YPb[(size_t)row*D_INNER + d] = f2bf(v[q] * rs * norm_w[d] * silu_f(zrow[d]));
  }
}

extern "C" void kernel_launch(void* const* d_in, const int* in_sizes, int n_in,
                              void* d_out, int out_size, void* d_ws, size_t ws_size,
                              hipStream_t stream) {
  (void)in_sizes; (void)n_in; (void)out_size; (void)ws_size;
  const float* u          = (const float*)d_in[0];
  const float* in_proj_w  = (const float*)d_in[1];
  const float* conv_sp_w  = (const float*)d_in[2];
  const float* conv_sp_b  = (const float*)d_in[3];
  const float* conv_tp_w  = (const float*)d_in[4];
  const float* conv_tp_b  = (const float*)d_in[5];
  const float* dt_bias    = (const float*)d_in[6];
  const float* A_log      = (const float*)d_in[7];
  const float* Dp         = (const float*)d_in[8];
  const float* fc_D_w     = (const float*)d_in[9];
  const float* norm_w     = (const float*)d_in[10];
  const float* out_proj_w = (const float*)d_in[11];
  float* out = (float*)d_out;
  float* ws = (float*)d_ws;

  // workspace layout (f32 elements)
  float* Z     = ws;                       // 4096*4352 = 17,825,792
  float* SH    = Z     + 17825792ULL;      // 9,437,184  (XS -> CBs -> YPb)
  float* XT    = SH    + 9437184ULL;       // 9,437,184
  float* DTt   = XT    + 9437184ULL;       // 262,144
  float* Yb    = DTt   + 262144ULL;        // 16,777,216 (hosts bf16 staging early)
  float* SPREV = Yb    + 16777216ULL;      // 2,097,152
  float* FCD   = SPREV + 2097152ULL;       // 131,072
  float* DTraw = FCD   + 131072ULL;        // 262,144

  unsigned short* Ub  = (unsigned short*)Yb;
  unsigned short* Wb  = (unsigned short*)Yb + 4194304ULL;
  unsigned short* Wob = (unsigned short*)Yb;
  unsigned short* YPb = (unsigned short*)SH;

  cast_bf16_kernel<<<4096, 256, 0, stream>>>(u, Ub);
  cast_bf16_kernel<<<4352, 256, 0, stream>>>(in_proj_w, Wb);
  gemm_bf16<<<dim3(34, 32), 256, 0, stream>>>(Ub, 1024, Wb, 1024, Z, ZLD, 1024);
  gemm_bt_f32<<<dim3(1, 64), 256, 0, stream>>>(u, 1024, in_proj_w + 4352ULL*1024, 1024,
                                               DTraw, 64, 64, 1024);
  dt_kernel<<<1024, 256, 0, stream>>>(DTraw, dt_bias, DTt);
  conv_sp_kernel<<<36864, 256, 0, stream>>>(Z, conv_sp_w, conv_sp_b, SH);
  conv_tp_kernel<<<36864, 256, 0, stream>>>(SH, conv_tp_w, conv_tp_b, XT);
  gemm_bt_f32<<<dim3(1, 64), 256, 0, stream>>>(XT, 2304, fc_D_w, 2048, FCD, 32, 32, 2048);
  cb_kernel<<<dim3(16, 8, 4), 256, 0, stream>>>(XT, SH);
  state_kernel<<<dim3(32, 2), 256, 0, stream>>>(XT, DTt, A_log, SPREV);
  yscan_kernel<<<dim3(8, 128), 256, 0, stream>>>(XT, DTt, SH, SPREV, A_log, Yb);
  combine_kernel<<<4096, 256, 0, stream>>>(Yb, XT, FCD, Dp, Z, norm_w, YPb);
  cast_bf16_kernel<<<2048, 256, 0, stream>>>(out_proj_w, Wob);
  gemm_bf16<<<dim3(8, 32), 256, 0, stream>>>(YPb, 2048, Wob, 2048, out, 1024, 2048);
}

// Round 4
// 610.839 us; speedup vs baseline: 2.3974x; 1.1798x over previous
//
#include <hip/hip_runtime.h>
#include <hip/hip_bf16.h>
#include <math.h>

#define D_STATE   64
#define HEADDIM   64
#define D_INNER   2048
#define NHEADS    32
#define GN        64
#define CONV_DIM  2304
#define D_IN_PROJ 4416
#define ZLD       4352      /* z + xBC columns only (dt handled separately) */
#define K_SP      7
#define K_TP      4
#define CHUNK     256
#define BATCHN    2
#define FRAMES    8
#define SPATIAL   256
#define SEQLEN    2048
#define NCH       8
#define MTOT      4096

typedef __attribute__((ext_vector_type(8))) short short8;
typedef __attribute__((ext_vector_type(4))) float floatx4;

__device__ __forceinline__ float silu_f(float x) { return x / (1.f + __expf(-x)); }
__device__ __forceinline__ int flip_l(int l) { return (l & ~7) | (7 - (l & 7)); }
__device__ __forceinline__ unsigned short f2bf(float f) {
  unsigned int u = __float_as_uint(f);
  unsigned int r = (u + 0x7fffu + ((u >> 16) & 1u)) >> 16;
  return (unsigned short)r;
}
__device__ __forceinline__ void gload_lds16(const unsigned short* g, unsigned short* l) {
  __builtin_amdgcn_global_load_lds((const __attribute__((address_space(1))) void*)g,
                                   (__attribute__((address_space(3))) void*)l, 16, 0, 0);
}

// ---------------- f32 -> bf16 cast ----------------
__global__ __launch_bounds__(256) void cast_bf16_kernel(const float* __restrict__ in,
                                                        unsigned short* __restrict__ out) {
  size_t i = ((size_t)blockIdx.x * 256 + threadIdx.x) * 4;
  float4 v = *(const float4*)(in + i);
  ushort4 o;
  o.x = f2bf(v.x); o.y = f2bf(v.y); o.z = f2bf(v.z); o.w = f2bf(v.w);
  *(ushort4*)(out + i) = o;
}

// ---------------- bf16 MFMA GEMM: C = A * B^T ----------------
__global__ __launch_bounds__(256) void gemm_bf16(
    const unsigned short* __restrict__ A, int lda,
    const unsigned short* __restrict__ B, int ldb,
    float* __restrict__ C, int ldc, int K) {
  __shared__ unsigned short As[128 * 32];
  __shared__ unsigned short Bs[128 * 32];
  const int tid = threadIdx.x;
  const int lane = tid & 63;
  const int w = tid >> 6;
  const int m0 = blockIdx.y * 128;
  const int n0 = blockIdx.x * 128;
  const int wm = (w >> 1) * 64;
  const int wn = (w & 1) * 64;
  const int srow = lane >> 2;
  const int scol = (lane & 3) * 8;
  floatx4 acc[4][4] = {};
  for (int k0 = 0; k0 < K; k0 += 32) {
#pragma unroll
    for (int it = 0; it < 2; ++it) {
      int ch = it * 4 + w;
      const unsigned short* ga = A + (size_t)(m0 + ch * 16 + srow) * lda + k0 + scol;
      const unsigned short* gb = B + (size_t)(n0 + ch * 16 + srow) * ldb + k0 + scol;
      gload_lds16(ga, &As[ch * 512]);
      gload_lds16(gb, &Bs[ch * 512]);
    }
    __syncthreads();
    const int fr = lane & 15;
    const int kq = (lane >> 4) * 8;
    short8 af[4], bfr[4];
#pragma unroll
    for (int i = 0; i < 4; ++i)
      af[i] = *(const short8*)&As[(wm + i * 16 + fr) * 32 + kq];
#pragma unroll
    for (int j = 0; j < 4; ++j)
      bfr[j] = *(const short8*)&Bs[(wn + j * 16 + fr) * 32 + kq];
#pragma unroll
    for (int i = 0; i < 4; ++i)
#pragma unroll
      for (int j = 0; j < 4; ++j)
        acc[i][j] = __builtin_amdgcn_mfma_f32_16x16x32_bf16(af[i], bfr[j], acc[i][j], 0, 0, 0);
    __syncthreads();
  }
  const int col = lane & 15;
  const int rg = (lane >> 4) * 4;
#pragma unroll
  for (int i = 0; i < 4; ++i)
#pragma unroll
    for (int j = 0; j < 4; ++j)
#pragma unroll
      for (int r = 0; r < 4; ++r)
        C[(size_t)(m0 + wm + i * 16 + rg + r) * ldc + (n0 + wn + j * 16 + col)] = acc[i][j][r];
}

// ---------------- f32 tiled GEMM: C = A * B^T (dt cols + fc_D) ----------------
__global__ __launch_bounds__(256) void gemm_bt_f32(
    const float* __restrict__ A, int lda,
    const float* __restrict__ B, int ldb,
    float* __restrict__ C, int ldc,
    int N, int K) {
  __shared__ float As[16][64];
  __shared__ float Bs[16][64];
  const int tid = threadIdx.x;
  const int tx = tid & 15, ty = tid >> 4;
  const int m0 = blockIdx.y * 64;
  const int n0 = blockIdx.x * 64;
  const int lm = tid >> 2;
  const int lk = (tid & 3) << 2;
  const float* Ag = A + (size_t)(m0 + lm) * lda + lk;
  const float* Bg = B + (size_t)(n0 + lm) * ldb + lk;
  const bool bvalid = (n0 + lm) < N;
  float acc[4][4] = {{0.f,0.f,0.f,0.f},{0.f,0.f,0.f,0.f},{0.f,0.f,0.f,0.f},{0.f,0.f,0.f,0.f}};
  for (int k0 = 0; k0 < K; k0 += 16) {
    float4 av = *(const float4*)(Ag + k0);
    float4 bv = bvalid ? *(const float4*)(Bg + k0) : make_float4(0.f,0.f,0.f,0.f);
    __syncthreads();
    As[lk+0][lm] = av.x; As[lk+1][lm] = av.y; As[lk+2][lm] = av.z; As[lk+3][lm] = av.w;
    Bs[lk+0][lm] = bv.x; Bs[lk+1][lm] = bv.y; Bs[lk+2][lm] = bv.z; Bs[lk+3][lm] = bv.w;
    __syncthreads();
#pragma unroll
    for (int kk = 0; kk < 16; ++kk) {
      float4 a4 = *(const float4*)&As[kk][ty << 2];
      float4 b4 = *(const float4*)&Bs[kk][tx << 2];
      float ar[4] = {a4.x, a4.y, a4.z, a4.w};
      float br[4] = {b4.x, b4.y, b4.z, b4.w};
#pragma unroll
      for (int i = 0; i < 4; ++i)
#pragma unroll
        for (int j = 0; j < 4; ++j)
          acc[i][j] += ar[i] * br[j];
    }
  }
  const int n = n0 + (tx << 2);
  if (n < N) {
#pragma unroll
    for (int i = 0; i < 4; ++i) {
      float4 o = make_float4(acc[i][0], acc[i][1], acc[i][2], acc[i][3]);
      *(float4*)(C + (size_t)(m0 + (ty<<2) + i) * ldc + n) = o;
    }
  }
}

// ---------------- dt = softplus(dt_raw + bias), flip for reverse; + chunk-local cumsum ----------------
__global__ __launch_bounds__(256) void dtscan_kernel(const float* __restrict__ DTraw,
                                                     const float* __restrict__ dt_bias,
                                                     const float* __restrict__ A_log,
                                                     float* __restrict__ DTt,
                                                     float* __restrict__ CUMS) {
  __shared__ float sc[256];
  int tid = threadIdx.x;
  int idx = blockIdx.x * 256 + tid;   // block == one (r,h,chunk)
  int l  = idx & 2047;
  int rh = idx >> 11;
  int h  = rh & 31;
  int r  = rh >> 5;
  int bi = r & 1;
  int ls = (r < 2) ? l : flip_l(l);
  int ch = (r < 2) ? h : NHEADS + h;
  float raw = DTraw[((size_t)bi * SEQLEN + ls) * 64 + ch] + dt_bias[h];
  float dtv = (raw > 20.f) ? raw : log1pf(__expf(raw));
  DTt[idx] = dtv;
  float A = -__expf(A_log[h]);
  float run = dtv * A;
  sc[tid] = run;
  __syncthreads();
#pragma unroll
  for (int ofs = 1; ofs < 256; ofs <<= 1) {
    float add = (tid >= ofs) ? sc[tid - ofs] : 0.f;
    __syncthreads();
    run += add;
    sc[tid] = run;
    __syncthreads();
  }
  CUMS[idx] = run;
}

// ---------------- spatial depthwise conv (same pad) + silu ----------------
__global__ __launch_bounds__(256) void conv_sp_kernel(const float* __restrict__ Z,
                                                      const float* __restrict__ w,
                                                      const float* __restrict__ b,
                                                      float* __restrict__ XS) {
  size_t idx = (size_t)blockIdx.x * 256 + threadIdx.x;
  int c = (int)(idx % CONV_DIM);
  size_t t = idx / CONV_DIM;
  int l = (int)(t & 2047);
  int bi = (int)(t >> 11);
  int s = l >> 3, fr = l & 7;
  float acc = b[c];
  const float* wc = w + c * K_SP;
#pragma unroll
  for (int j = 0; j < K_SP; ++j) {
    int ss = s + j - 3;
    if (0 <= ss && ss < SPATIAL)
      acc += wc[j] * Z[((size_t)bi * SEQLEN + (ss*8 + fr)) * ZLD + D_INNER + c];
  }
  XS[idx] = silu_f(acc);
}

// ---------------- temporal depthwise conv (causal) + silu ----------------
__global__ __launch_bounds__(256) void conv_tp_kernel(const float* __restrict__ XS,
                                                      const float* __restrict__ w,
                                                      const float* __restrict__ b,
                                                      float* __restrict__ XT) {
  size_t idx = (size_t)blockIdx.x * 256 + threadIdx.x;
  int c = (int)(idx % CONV_DIM);
  size_t t = idx / CONV_DIM;
  int l = (int)(t & 2047);
  int bi = (int)(t >> 11);
  int s = l >> 3, fr = l & 7;
  float acc = b[c];
  const float* wc = w + c * K_TP;
#pragma unroll
  for (int j = 0; j < K_TP; ++j) {
    int ff = fr + j - (K_TP - 1);
    if (ff >= 0)
      acc += wc[j] * XS[((size_t)bi * SEQLEN + (s*8 + ff)) * CONV_DIM + c];
  }
  XT[idx] = silu_f(acc);
}

// ---------------- CB[t][s] = sum_n C[t][n] B[s][n], per (r,c)  (t-major) ----------------
__global__ __launch_bounds__(256) void cb_kernel(const float* __restrict__ XT,
                                                 float* __restrict__ CBs) {
  __shared__ float Ct[64][65];
  __shared__ float Bt[64][65];
  int tid = threadIdx.x;
  int t0 = (blockIdx.x & 3) * 64;
  int s0 = (blockIdx.x >> 2) * 64;
  if (s0 > t0) return;
  int c = blockIdx.y;
  int r = blockIdx.z;
  int bi = r & 1;
  int bOff = D_INNER + ((r < 2) ? 0 : 2*GN);
  int cOff = bOff + GN;
  int lrow = tid >> 4;
  int n4 = (tid & 15) << 2;
#pragma unroll
  for (int rep = 0; rep < 4; ++rep) {
    int tl = rep * 16 + lrow;
    int Lc = c * CHUNK + t0 + tl;
    int Ls = c * CHUNK + s0 + tl;
    if (r >= 2) { Lc = flip_l(Lc); Ls = flip_l(Ls); }
    float4 cv = *(const float4*)(XT + ((size_t)bi*SEQLEN + Lc)*CONV_DIM + cOff + n4);
    float4 bv = *(const float4*)(XT + ((size_t)bi*SEQLEN + Ls)*CONV_DIM + bOff + n4);
    Ct[n4+0][tl] = cv.x; Ct[n4+1][tl] = cv.y; Ct[n4+2][tl] = cv.z; Ct[n4+3][tl] = cv.w;
    Bt[n4+0][tl] = bv.x; Bt[n4+1][tl] = bv.y; Bt[n4+2][tl] = bv.z; Bt[n4+3][tl] = bv.w;
  }
  __syncthreads();
  int txx = tid & 15;
  int tyy = tid >> 4;
  float acc[4][4] = {{0.f,0.f,0.f,0.f},{0.f,0.f,0.f,0.f},{0.f,0.f,0.f,0.f},{0.f,0.f,0.f,0.f}};
#pragma unroll
  for (int n = 0; n < D_STATE; ++n) {
    float cr[4], br[4];
#pragma unroll
    for (int i = 0; i < 4; ++i) cr[i] = Ct[n][tyy + 16*i];
#pragma unroll
    for (int j = 0; j < 4; ++j) br[j] = Bt[n][txx + 16*j];
#pragma unroll
    for (int i = 0; i < 4; ++i)
#pragma unroll
      for (int j = 0; j < 4; ++j)
        acc[i][j] += cr[i] * br[j];
  }
  size_t base = (((size_t)r*NCH + c) * CHUNK) * CHUNK;
#pragma unroll
  for (int i = 0; i < 4; ++i)
#pragma unroll
    for (int j = 0; j < 4; ++j)
      CBs[base + (size_t)(t0 + tyy + 16*i)*CHUNK + (s0 + txx + 16*j)] = acc[i][j];
}

// ---------------- per-chunk state sums (MFMA, forward r=0,1 only) ----------------
// S_chunk[p][n] = sum_s (G[s]*x[s][p]) * b[s][n];  G[s] = exp(cum_last - cum_s)*dt_s
__global__ __launch_bounds__(256) void chunk_state_kernel(const float* __restrict__ XT,
                                                          const float* __restrict__ DTt,
                                                          const float* __restrict__ CUMS,
                                                          float* __restrict__ SCH) {
  __shared__ unsigned short Xb[64][40];   // [p][s-slab]
  __shared__ unsigned short Bb[64][40];   // [n][s-slab]
  int tid = threadIdx.x;
  int lane = tid & 63;
  int w = tid >> 6;
  int c = blockIdx.x;
  int h = blockIdx.y;
  int r = blockIdx.z;    // 0..1 (forward only)
  int bi = r;
  int rh = r * NHEADS + h;
  float cl = CUMS[(size_t)rh*SEQLEN + c*CHUNK + 255];
  const int fr = lane & 15;
  const int kq = (lane >> 4) * 8;
  floatx4 acc[4] = {};
  for (int sl = 0; sl < 8; ++sl) {
    int s0 = sl * 32;
    __syncthreads();
    {
      int srow = tid >> 3;          // 0..31
      int cg = (tid & 7) * 8;       // 0..56
      int l = c*CHUNK + s0 + srow;
      float g = __expf(cl - CUMS[(size_t)rh*SEQLEN + l]) * DTt[(size_t)rh*SEQLEN + l];
      const float* row = XT + ((size_t)bi*SEQLEN + l)*CONV_DIM;
      float4 x0 = *(const float4*)(row + h*HEADDIM + cg);
      float4 x1 = *(const float4*)(row + h*HEADDIM + cg + 4);
      float4 b0 = *(const float4*)(row + D_INNER + cg);
      float4 b1 = *(const float4*)(row + D_INNER + cg + 4);
      Xb[cg+0][srow] = f2bf(g*x0.x); Xb[cg+1][srow] = f2bf(g*x0.y);
      Xb[cg+2][srow] = f2bf(g*x0.z); Xb[cg+3][srow] = f2bf(g*x0.w);
      Xb[cg+4][srow] = f2bf(g*x1.x); Xb[cg+5][srow] = f2bf(g*x1.y);
      Xb[cg+6][srow] = f2bf(g*x1.z); Xb[cg+7][srow] = f2bf(g*x1.w);
      Bb[cg+0][srow] = f2bf(b0.x);   Bb[cg+1][srow] = f2bf(b0.y);
      Bb[cg+2][srow] = f2bf(b0.z);   Bb[cg+3][srow] = f2bf(b0.w);
      Bb[cg+4][srow] = f2bf(b1.x);   Bb[cg+5][srow] = f2bf(b1.y);
      Bb[cg+6][srow] = f2bf(b1.z);   Bb[cg+7][srow] = f2bf(b1.w);
    }
    __syncthreads();
    short8 af = *(const short8*)&Xb[w*16 + fr][kq];
#pragma unroll
    for (int j = 0; j < 4; ++j) {
      short8 bf8 = *(const short8*)&Bb[j*16 + fr][kq];
      acc[j] = __builtin_amdgcn_mfma_f32_16x16x32_bf16(af, bf8, acc[j], 0, 0, 0);
    }
  }
  const int col = lane & 15;
  const int rg = (lane >> 4) * 4;
  size_t base = (((size_t)r*NCH + c)*NHEADS + h) * (size_t)(HEADDIM*D_STATE);
#pragma unroll
  for (int j = 0; j < 4; ++j)
#pragma unroll
    for (int q = 0; q < 4; ++q)
      SCH[base + (size_t)(w*16 + rg + q)*D_STATE + j*16 + col] = acc[j][q];
}

// ---------------- prefix-combine chunk states -> SPREV ----------------
__global__ __launch_bounds__(256) void state_combine_kernel(const float* __restrict__ SCH,
                                                            const float* __restrict__ CUMS,
                                                            float* __restrict__ SPREV) {
  int bid = blockIdx.x;          // r*128 + h*4 + pq
  int pq = bid & 3;
  int h = (bid >> 2) & 31;
  int r = bid >> 7;
  int tid = threadIdx.x;
  int p = pq*16 + (tid >> 4);
  int n = (tid & 15) * 4;
  float4 S = make_float4(0.f, 0.f, 0.f, 0.f);
  for (int c = 0; c < NCH; ++c) {
    size_t off = ((((size_t)r*NCH + c)*NHEADS + h)*HEADDIM + p)*D_STATE + n;
    *(float4*)(SPREV + off) = S;
    float dec = __expf(CUMS[((size_t)r*NHEADS + h)*SEQLEN + c*CHUNK + 255]);
    float4 v = *(const float4*)(SCH + off);
    S.x = dec*S.x + v.x; S.y = dec*S.y + v.y;
    S.z = dec*S.z + v.z; S.w = dec*S.w + v.w;
  }
}

// ---------------- Y = intra(triangular, MFMA) + inter (MFMA, fwd only) ----------------
__global__ __launch_bounds__(256) void yscan_kernel(const float* __restrict__ XT,
                                                    const float* __restrict__ DTt,
                                                    const float* __restrict__ CUMS,
                                                    const float* __restrict__ CBs,
                                                    const float* __restrict__ SPREV,
                                                    float* __restrict__ Y) {
  __shared__ unsigned short Xb[64][40];  // X slab transposed [p][s]
  __shared__ float dts[CHUNK];
  __shared__ float cums[CHUNK];
  int tid = threadIdx.x;
  int lane = tid & 63;
  int w = tid >> 6;
  int c = blockIdx.x;
  int rh = blockIdx.y;
  int h = rh & 31;
  int r = rh >> 5;
  int bi = r & 1;
  dts[tid]  = DTt[(size_t)rh*SEQLEN + c*CHUNK + tid];
  cums[tid] = CUMS[(size_t)rh*SEQLEN + c*CHUNK + tid];
  __syncthreads();
  const int fr = lane & 15;
  const int kq = (lane >> 4) * 8;
  const int wt0 = w * 64;
  float ct[4];
#pragma unroll
  for (int i = 0; i < 4; ++i) ct[i] = cums[wt0 + i*16 + fr];
  floatx4 acc[4][4] = {};
  size_t cbbase = (((size_t)r*NCH + c) * CHUNK) * CHUNK;
  const int maxsl = 2*w + 1;
  for (int sl = 0; sl < 8; ++sl) {
    int s0 = sl * 32;
    __syncthreads();
    {
      int srow = tid >> 3;
      int p0 = (tid & 7) * 4;
      int L = c*CHUNK + s0 + srow;
      if (r >= 2) L = flip_l(L);
      const float* xrow = XT + ((size_t)bi*SEQLEN + L)*CONV_DIM + h*HEADDIM;
#pragma unroll
      for (int half = 0; half < 2; ++half) {
        float4 v = *(const float4*)(xrow + p0 + half*32);
        Xb[p0 + half*32 + 0][srow] = f2bf(v.x);
        Xb[p0 + half*32 + 1][srow] = f2bf(v.y);
        Xb[p0 + half*32 + 2][srow] = f2bf(v.z);
        Xb[p0 + half*32 + 3][srow] = f2bf(v.w);
      }
    }
    __syncthreads();
    if (sl <= maxsl) {
      float cs[8], dtv[8];
#pragma unroll
      for (int j = 0; j < 8; ++j) { cs[j] = cums[s0 + kq + j]; dtv[j] = dts[s0 + kq + j]; }
      short8 bfr[4];
#pragma unroll
      for (int j = 0; j < 4; ++j)
        bfr[j] = *(const short8*)&Xb[j*16 + fr][kq];
#pragma unroll
      for (int i = 0; i < 4; ++i) {
        int t = wt0 + i*16 + fr;
        const float* cbrow = CBs + cbbase + (size_t)t*CHUNK + s0 + kq;
        float4 c0 = *(const float4*)cbrow;
        float4 c1 = *(const float4*)(cbrow + 4);
        float cb[8] = {c0.x,c0.y,c0.z,c0.w,c1.x,c1.y,c1.z,c1.w};
        short8 af;
#pragma unroll
        for (int j = 0; j < 8; ++j) {
          int s = s0 + kq + j;
          float wv = (s <= t) ? cb[j] * __expf(ct[i] - cs[j]) * dtv[j] : 0.f;
          af[j] = (short)f2bf(wv);
        }
#pragma unroll
        for (int j = 0; j < 4; ++j)
          acc[i][j] = __builtin_amdgcn_mfma_f32_16x16x32_bf16(af, bfr[j], acc[i][j], 0, 0, 0);
      }
    }
  }
  if (r < 2) {   // inter-chunk term: (E*C) @ Sprev^T
    float ect[4];
#pragma unroll
    for (int i = 0; i < 4; ++i) ect[i] = __expf(ct[i]);
    const float* spbase = SPREV + (((size_t)r*NCH + c)*NHEADS + h) * (size_t)(HEADDIM*D_STATE);
#pragma unroll
    for (int ns = 0; ns < 2; ++ns) {
      int n0 = ns * 32;
      short8 bfr[4];
#pragma unroll
      for (int j = 0; j < 4; ++j) {
        const float* sp = spbase + (size_t)(j*16 + fr)*D_STATE + n0 + kq;
        float4 s0v = *(const float4*)sp;
        float4 s1v = *(const float4*)(sp + 4);
        short8 bb;
        bb[0]=(short)f2bf(s0v.x); bb[1]=(short)f2bf(s0v.y); bb[2]=(short)f2bf(s0v.z); bb[3]=(short)f2bf(s0v.w);
        bb[4]=(short)f2bf(s1v.x); bb[5]=(short)f2bf(s1v.y); bb[6]=(short)f2bf(s1v.z); bb[7]=(short)f2bf(s1v.w);
        bfr[j] = bb;
      }
#pragma unroll
      for (int i = 0; i < 4; ++i) {
        int t = wt0 + i*16 + fr;
        const float* crow = XT + ((size_t)bi*SEQLEN + c*CHUNK + t)*CONV_DIM + D_INNER + GN + n0 + kq;
        float4 c0 = *(const float4*)crow;
        float4 c1 = *(const float4*)(crow + 4);
        short8 af;
        af[0]=(short)f2bf(c0.x*ect[i]); af[1]=(short)f2bf(c0.y*ect[i]);
        af[2]=(short)f2bf(c0.z*ect[i]); af[3]=(short)f2bf(c0.w*ect[i]);
        af[4]=(short)f2bf(c1.x*ect[i]); af[5]=(short)f2bf(c1.y*ect[i]);
        af[6]=(short)f2bf(c1.z*ect[i]); af[7]=(short)f2bf(c1.w*ect[i]);
#pragma unroll
        for (int j = 0; j < 4; ++j)
          acc[i][j] = __builtin_amdgcn_mfma_f32_16x16x32_bf16(af, bfr[j], acc[i][j], 0, 0, 0);
      }
    }
  }
  const int rg = (lane >> 4) * 4;
  size_t ybase = ((size_t)r*SEQLEN + c*CHUNK)*D_INNER + h*HEADDIM;
#pragma unroll
  for (int i = 0; i < 4; ++i)
#pragma unroll
    for (int j = 0; j < 4; ++j)
#pragma unroll
      for (int q = 0; q < 4; ++q)
        Y[ybase + (size_t)(wt0 + i*16 + rg + q)*D_INNER + j*16 + fr] = acc[i][j][q];
}

// ---------------- shifts + x_res + RMSNorm + gate (-> bf16) ----------------
__global__ __launch_bounds__(256) void combine_kernel(const float* __restrict__ Y,
                                                      const float* __restrict__ XT,
                                                      const float* __restrict__ FCD,
                                                      const float* __restrict__ Dp,
                                                      const float* __restrict__ Z,
                                                      const float* __restrict__ norm_w,
                                                      unsigned short* __restrict__ YPb) {
  __shared__ float red[256];
  int row = blockIdx.x;
  int bi = row >> 11;
  int l = row & 2047;
  int s = l >> 3, fr = l & 7;
  int tid = threadIdx.x;
  const float* yf = (l >= 1) ? Y + ((size_t)bi*SEQLEN + (l-1))*D_INNER : nullptr;
  const float* yr = (s >= 1) ? Y + ((size_t)(2+bi)*SEQLEN + ((s-1)*8 + (7-fr)))*D_INNER : nullptr;
  const float* xr = XT + ((size_t)bi*SEQLEN + l)*CONV_DIM;
  const float* fc = FCD + (size_t)row*NHEADS;
  float v[8];
  float ss = 0.f;
#pragma unroll
  for (int q = 0; q < 8; ++q) {
    int d = q*256 + tid;
    float val = xr[d] * (fc[d >> 6] + Dp[d >> 6]);
    if (yf) val += yf[d];
    if (yr) val += yr[d];
    v[q] = val;
    ss += val * val;
  }
  red[tid] = ss;
  __syncthreads();
  for (int ofs = 128; ofs > 0; ofs >>= 1) {
    if (tid < ofs) red[tid] += red[tid + ofs];
    __syncthreads();
  }
  float rs = rsqrtf(red[0] / (float)D_INNER + 1e-5f);
  const float* zrow = Z + ((size_t)bi*SEQLEN + l)*ZLD;
#pragma unroll
  for (int q = 0; q < 8; ++q) {
    int d = q*256 + tid;
    YPb[(size_t)row*D_INNER + d] = f2bf(v[q] * rs * norm_w[d] * silu_f(zrow[d]));
  }
}

extern "C" void kernel_launch(void* const* d_in, const int* in_sizes, int n_in,
                              void* d_out, int out_size, void* d_ws, size_t ws_size,
                              hipStream_t stream) {
  (void)in_sizes; (void)n_in; (void)out_size; (void)ws_size;
  const float* u          = (const float*)d_in[0];
  const float* in_proj_w  = (const float*)d_in[1];
  const float* conv_sp_w  = (const float*)d_in[2];
  const float* conv_sp_b  = (const float*)d_in[3];
  const float* conv_tp_w  = (const float*)d_in[4];
  const float* conv_tp_b  = (const float*)d_in[5];
  const float* dt_bias    = (const float*)d_in[6];
  const float* A_log      = (const float*)d_in[7];
  const float* Dp         = (const float*)d_in[8];
  const float* fc_D_w     = (const float*)d_in[9];
  const float* norm_w     = (const float*)d_in[10];
  const float* out_proj_w = (const float*)d_in[11];
  float* out = (float*)d_out;
  float* ws = (float*)d_ws;

  // workspace layout (f32 elements)
  float* Z     = ws;                       // 17,825,792
  float* SH    = Z     + 17825792ULL;      // 9,437,184  (XS -> CBs -> YPb)
  float* XT    = SH    + 9437184ULL;       // 9,437,184
  float* DTt   = XT    + 9437184ULL;       // 262,144
  float* Yb    = DTt   + 262144ULL;        // 16,777,216 (hosts bf16 staging + SCH early)
  float* SPREV = Yb    + 16777216ULL;      // 2,097,152
  float* FCD   = SPREV + 2097152ULL;       // 131,072
  float* DTraw = FCD   + 131072ULL;        // 262,144
  float* CUMS  = DTraw + 262144ULL;        // 262,144

  unsigned short* Ub  = (unsigned short*)Yb;
  unsigned short* Wb  = (unsigned short*)Yb + 4194304ULL;
  float* SCH = Yb + 8388608ULL;            // 2,097,152 (dead before yscan writes Yb)
  unsigned short* Wob = (unsigned short*)Yb;
  unsigned short* YPb = (unsigned short*)SH;

  cast_bf16_kernel<<<4096, 256, 0, stream>>>(u, Ub);
  cast_bf16_kernel<<<4352, 256, 0, stream>>>(in_proj_w, Wb);
  gemm_bf16<<<dim3(34, 32), 256, 0, stream>>>(Ub, 1024, Wb, 1024, Z, ZLD, 1024);
  gemm_bt_f32<<<dim3(1, 64), 256, 0, stream>>>(u, 1024, in_proj_w + 4352ULL*1024, 1024,
                                               DTraw, 64, 64, 1024);
  dtscan_kernel<<<1024, 256, 0, stream>>>(DTraw, dt_bias, A_log, DTt, CUMS);
  conv_sp_kernel<<<36864, 256, 0, stream>>>(Z, conv_sp_w, conv_sp_b, SH);
  conv_tp_kernel<<<36864, 256, 0, stream>>>(SH, conv_tp_w, conv_tp_b, XT);
  gemm_bt_f32<<<dim3(1, 64), 256, 0, stream>>>(XT, 2304, fc_D_w, 2048, FCD, 32, 32, 2048);
  cb_kernel<<<dim3(16, 8, 4), 256, 0, stream>>>(XT, SH);
  chunk_state_kernel<<<dim3(NCH, NHEADS, 2), 256, 0, stream>>>(XT, DTt, CUMS, SCH);
  state_combine_kernel<<<256, 256, 0, stream>>>(SCH, CUMS, SPREV);
  yscan_kernel<<<dim3(8, 128), 256, 0, stream>>>(XT, DTt, CUMS, SH, SPREV, Yb);
  combine_kernel<<<4096, 256, 0, stream>>>(Yb, XT, FCD, Dp, Z, norm_w, YPb);
  cast_bf16_kernel<<<2048, 256, 0, stream>>>(out_proj_w, Wob);
  gemm_bf16<<<dim3(8, 32), 256, 0, stream>>>(YPb, 2048, Wob, 2048, out, 1024, 2048);
}

// Round 5
// 513.238 us; speedup vs baseline: 2.8533x; 1.1902x over previous
//
#include <hip/hip_runtime.h>
#include <hip/hip_bf16.h>
#include <math.h>

#define D_STATE   64
#define HEADDIM   64
#define D_INNER   2048
#define NHEADS    32
#define GN        64
#define CONV_DIM  2304
#define D_IN_PROJ 4416
#define ZLD       4352      /* z + xBC columns only (dt handled separately) */
#define K_SP      7
#define K_TP      4
#define CHUNK     256
#define BATCHN    2
#define FRAMES    8
#define SPATIAL   256
#define SEQLEN    2048
#define NCH       8
#define MTOT      4096

typedef __attribute__((ext_vector_type(8))) short short8;
typedef __attribute__((ext_vector_type(4))) float floatx4;

__device__ __forceinline__ float silu_f(float x) { return x / (1.f + __expf(-x)); }
__device__ __forceinline__ int flip_l(int l) { return (l & ~7) | (7 - (l & 7)); }
__device__ __forceinline__ unsigned short f2bf(float f) {
  unsigned int u = __float_as_uint(f);
  unsigned int r = (u + 0x7fffu + ((u >> 16) & 1u)) >> 16;
  return (unsigned short)r;
}
__device__ __forceinline__ void gload_lds16(const unsigned short* g, unsigned short* l) {
  __builtin_amdgcn_global_load_lds((const __attribute__((address_space(1))) void*)g,
                                   (__attribute__((address_space(3))) void*)l, 16, 0, 0);
}

// ---------------- f32 -> bf16 cast ----------------
__global__ __launch_bounds__(256) void cast_bf16_kernel(const float* __restrict__ in,
                                                        unsigned short* __restrict__ out) {
  size_t i = ((size_t)blockIdx.x * 256 + threadIdx.x) * 4;
  float4 v = *(const float4*)(in + i);
  ushort4 o;
  o.x = f2bf(v.x); o.y = f2bf(v.y); o.z = f2bf(v.z); o.w = f2bf(v.w);
  *(ushort4*)(out + i) = o;
}

// ---------------- bf16 MFMA GEMM: C = A * B^T ----------------
__global__ __launch_bounds__(256) void gemm_bf16(
    const unsigned short* __restrict__ A, int lda,
    const unsigned short* __restrict__ B, int ldb,
    float* __restrict__ C, int ldc, int K) {
  __shared__ unsigned short As[128 * 32];
  __shared__ unsigned short Bs[128 * 32];
  const int tid = threadIdx.x;
  const int lane = tid & 63;
  const int w = tid >> 6;
  const int m0 = blockIdx.y * 128;
  const int n0 = blockIdx.x * 128;
  const int wm = (w >> 1) * 64;
  const int wn = (w & 1) * 64;
  const int srow = lane >> 2;
  const int scol = (lane & 3) * 8;
  floatx4 acc[4][4] = {};
  for (int k0 = 0; k0 < K; k0 += 32) {
#pragma unroll
    for (int it = 0; it < 2; ++it) {
      int ch = it * 4 + w;
      const unsigned short* ga = A + (size_t)(m0 + ch * 16 + srow) * lda + k0 + scol;
      const unsigned short* gb = B + (size_t)(n0 + ch * 16 + srow) * ldb + k0 + scol;
      gload_lds16(ga, &As[ch * 512]);
      gload_lds16(gb, &Bs[ch * 512]);
    }
    __syncthreads();
    const int fr = lane & 15;
    const int kq = (lane >> 4) * 8;
    short8 af[4], bfr[4];
#pragma unroll
    for (int i = 0; i < 4; ++i)
      af[i] = *(const short8*)&As[(wm + i * 16 + fr) * 32 + kq];
#pragma unroll
    for (int j = 0; j < 4; ++j)
      bfr[j] = *(const short8*)&Bs[(wn + j * 16 + fr) * 32 + kq];
#pragma unroll
    for (int i = 0; i < 4; ++i)
#pragma unroll
      for (int j = 0; j < 4; ++j)
        acc[i][j] = __builtin_amdgcn_mfma_f32_16x16x32_bf16(af[i], bfr[j], acc[i][j], 0, 0, 0);
    __syncthreads();
  }
  const int col = lane & 15;
  const int rg = (lane >> 4) * 4;
#pragma unroll
  for (int i = 0; i < 4; ++i)
#pragma unroll
    for (int j = 0; j < 4; ++j)
#pragma unroll
      for (int r = 0; r < 4; ++r)
        C[(size_t)(m0 + wm + i * 16 + rg + r) * ldc + (n0 + wn + j * 16 + col)] = acc[i][j][r];
}

// ---------------- skinny f32 GEMM: C[M x N(<=64)] = A * B^T, M-tile=16 ----------------
// grid = M/16 blocks; B (N x K) staged transposed to LDS as Bs[k][n].
__global__ __launch_bounds__(256) void gemm_skinny_f32(
    const float* __restrict__ A, int lda,
    const float* __restrict__ B, int ldb,
    float* __restrict__ C, int ldc, int N, int K) {
  __shared__ float Bs[64][68];   // [k][n], stride 68 keeps float4 alignment
  __shared__ float As[16][68];   // [m][k]
  const int tid = threadIdx.x;
  const int m0 = blockIdx.x * 16;
  const int tm = tid >> 4;
  const int tn4 = (tid & 15) * 4;
  float acc[4] = {0.f, 0.f, 0.f, 0.f};
  for (int k0 = 0; k0 < K; k0 += 64) {
    __syncthreads();
    {   // stage B chunk transposed: thread reads row bn, 16 k's; scalar-transpose into Bs
      int bn = tid >> 2;
      int bk = (tid & 3) * 16;
      if (bn < N) {
#pragma unroll
        for (int q = 0; q < 4; ++q) {
          float4 v = *(const float4*)(B + (size_t)bn * ldb + k0 + bk + q * 4);
          Bs[bk + q*4 + 0][bn] = v.x;
          Bs[bk + q*4 + 1][bn] = v.y;
          Bs[bk + q*4 + 2][bn] = v.z;
          Bs[bk + q*4 + 3][bn] = v.w;
        }
      } else {
#pragma unroll
        for (int q = 0; q < 4; ++q) {
          Bs[bk + q*4 + 0][bn] = 0.f;
          Bs[bk + q*4 + 1][bn] = 0.f;
          Bs[bk + q*4 + 2][bn] = 0.f;
          Bs[bk + q*4 + 3][bn] = 0.f;
        }
      }
      // stage A chunk: 16 rows x 64 k
      int am = tid >> 4;
      int ak = (tid & 15) * 4;
      *(float4*)&As[am][ak] = *(const float4*)(A + (size_t)(m0 + am) * lda + k0 + ak);
    }
    __syncthreads();
#pragma unroll 8
    for (int k = 0; k < 64; ++k) {
      float a = As[tm][k];
      float4 b4 = *(const float4*)&Bs[k][tn4];
      acc[0] += a * b4.x; acc[1] += a * b4.y;
      acc[2] += a * b4.z; acc[3] += a * b4.w;
    }
  }
  if (tn4 < N)
    *(float4*)(C + (size_t)(m0 + tm) * ldc + tn4) = make_float4(acc[0], acc[1], acc[2], acc[3]);
}

// ---------------- dt = softplus(dt_raw + bias), flip for reverse; + chunk-local cumsum ----------------
__global__ __launch_bounds__(256) void dtscan_kernel(const float* __restrict__ DTraw,
                                                     const float* __restrict__ dt_bias,
                                                     const float* __restrict__ A_log,
                                                     float* __restrict__ DTt,
                                                     float* __restrict__ CUMS) {
  __shared__ float sc[256];
  int tid = threadIdx.x;
  int idx = blockIdx.x * 256 + tid;   // block == one (r,h,chunk)
  int l  = idx & 2047;
  int rh = idx >> 11;
  int h  = rh & 31;
  int r  = rh >> 5;
  int bi = r & 1;
  int ls = (r < 2) ? l : flip_l(l);
  int ch = (r < 2) ? h : NHEADS + h;
  float raw = DTraw[((size_t)bi * SEQLEN + ls) * 64 + ch] + dt_bias[h];
  float dtv = (raw > 20.f) ? raw : log1pf(__expf(raw));
  DTt[idx] = dtv;
  float A = -__expf(A_log[h]);
  float run = dtv * A;
  sc[tid] = run;
  __syncthreads();
#pragma unroll
  for (int ofs = 1; ofs < 256; ofs <<= 1) {
    float add = (tid >= ofs) ? sc[tid - ofs] : 0.f;
    __syncthreads();
    run += add;
    sc[tid] = run;
    __syncthreads();
  }
  CUMS[idx] = run;
}

// ---------------- fused spatial+temporal depthwise conv + silu ----------------
// block = (32-channel tile, spatial s, batch); all 8 frames of s in LDS.
__global__ __launch_bounds__(256) void conv_fused_kernel(const float* __restrict__ Z,
                                                         const float* __restrict__ wsp,
                                                         const float* __restrict__ bsp,
                                                         const float* __restrict__ wtp,
                                                         const float* __restrict__ btp,
                                                         float* __restrict__ XT) {
  __shared__ float xsl[8][33];
  int cl = threadIdx.x & 31;
  int fr = threadIdx.x >> 5;
  int c = blockIdx.x * 32 + cl;
  int s = blockIdx.y;
  int bi = blockIdx.z;
  float acc = bsp[c];
  const float* wc = wsp + c * K_SP;
#pragma unroll
  for (int j = 0; j < K_SP; ++j) {
    int ss = s + j - 3;
    if (0 <= ss && ss < SPATIAL)
      acc += wc[j] * Z[((size_t)bi * SEQLEN + (ss*8 + fr)) * ZLD + D_INNER + c];
  }
  xsl[fr][cl] = silu_f(acc);
  __syncthreads();
  float acct = btp[c];
  const float* wt = wtp + c * K_TP;
#pragma unroll
  for (int j = 0; j < K_TP; ++j) {
    int ff = fr + j - (K_TP - 1);
    if (ff >= 0)
      acct += wt[j] * xsl[ff][cl];
  }
  XT[((size_t)bi * SEQLEN + (s*8 + fr)) * CONV_DIM + c] = silu_f(acct);
}

// ---------------- CB[t][s] = sum_n C[t][n] B[s][n], per (r,c)  (t-major) ----------------
__global__ __launch_bounds__(256) void cb_kernel(const float* __restrict__ XT,
                                                 float* __restrict__ CBs) {
  __shared__ float Ct[64][65];
  __shared__ float Bt[64][65];
  int tid = threadIdx.x;
  int t0 = (blockIdx.x & 3) * 64;
  int s0 = (blockIdx.x >> 2) * 64;
  if (s0 > t0) return;
  int c = blockIdx.y;
  int r = blockIdx.z;
  int bi = r & 1;
  int bOff = D_INNER + ((r < 2) ? 0 : 2*GN);
  int cOff = bOff + GN;
  int lrow = tid >> 4;
  int n4 = (tid & 15) << 2;
#pragma unroll
  for (int rep = 0; rep < 4; ++rep) {
    int tl = rep * 16 + lrow;
    int Lc = c * CHUNK + t0 + tl;
    int Ls = c * CHUNK + s0 + tl;
    if (r >= 2) { Lc = flip_l(Lc); Ls = flip_l(Ls); }
    float4 cv = *(const float4*)(XT + ((size_t)bi*SEQLEN + Lc)*CONV_DIM + cOff + n4);
    float4 bv = *(const float4*)(XT + ((size_t)bi*SEQLEN + Ls)*CONV_DIM + bOff + n4);
    Ct[n4+0][tl] = cv.x; Ct[n4+1][tl] = cv.y; Ct[n4+2][tl] = cv.z; Ct[n4+3][tl] = cv.w;
    Bt[n4+0][tl] = bv.x; Bt[n4+1][tl] = bv.y; Bt[n4+2][tl] = bv.z; Bt[n4+3][tl] = bv.w;
  }
  __syncthreads();
  int txx = tid & 15;
  int tyy = tid >> 4;
  float acc[4][4] = {{0.f,0.f,0.f,0.f},{0.f,0.f,0.f,0.f},{0.f,0.f,0.f,0.f},{0.f,0.f,0.f,0.f}};
#pragma unroll
  for (int n = 0; n < D_STATE; ++n) {
    float cr[4], br[4];
#pragma unroll
    for (int i = 0; i < 4; ++i) cr[i] = Ct[n][tyy + 16*i];
#pragma unroll
    for (int j = 0; j < 4; ++j) br[j] = Bt[n][txx + 16*j];
#pragma unroll
    for (int i = 0; i < 4; ++i)
#pragma unroll
      for (int j = 0; j < 4; ++j)
        acc[i][j] += cr[i] * br[j];
  }
  size_t base = (((size_t)r*NCH + c) * CHUNK) * CHUNK;
#pragma unroll
  for (int i = 0; i < 4; ++i)
#pragma unroll
    for (int j = 0; j < 4; ++j)
      CBs[base + (size_t)(t0 + tyy + 16*i)*CHUNK + (s0 + txx + 16*j)] = acc[i][j];
}

// ---------------- per-chunk state sums (MFMA, forward r=0,1 only) ----------------
__global__ __launch_bounds__(256) void chunk_state_kernel(const float* __restrict__ XT,
                                                          const float* __restrict__ DTt,
                                                          const float* __restrict__ CUMS,
                                                          float* __restrict__ SCH) {
  __shared__ unsigned short Xb[64][40];   // [p][s-slab]
  __shared__ unsigned short Bb[64][40];   // [n][s-slab]
  int tid = threadIdx.x;
  int lane = tid & 63;
  int w = tid >> 6;
  int c = blockIdx.x;
  int h = blockIdx.y;
  int r = blockIdx.z;    // 0..1 (forward only)
  int bi = r;
  int rh = r * NHEADS + h;
  float cl = CUMS[(size_t)rh*SEQLEN + c*CHUNK + 255];
  const int fr = lane & 15;
  const int kq = (lane >> 4) * 8;
  floatx4 acc[4] = {};
  for (int sl = 0; sl < 8; ++sl) {
    int s0 = sl * 32;
    __syncthreads();
    {
      int srow = tid >> 3;          // 0..31
      int cg = (tid & 7) * 8;       // 0..56
      int l = c*CHUNK + s0 + srow;
      float g = __expf(cl - CUMS[(size_t)rh*SEQLEN + l]) * DTt[(size_t)rh*SEQLEN + l];
      const float* row = XT + ((size_t)bi*SEQLEN + l)*CONV_DIM;
      float4 x0 = *(const float4*)(row + h*HEADDIM + cg);
      float4 x1 = *(const float4*)(row + h*HEADDIM + cg + 4);
      float4 b0 = *(const float4*)(row + D_INNER + cg);
      float4 b1 = *(const float4*)(row + D_INNER + cg + 4);
      Xb[cg+0][srow] = f2bf(g*x0.x); Xb[cg+1][srow] = f2bf(g*x0.y);
      Xb[cg+2][srow] = f2bf(g*x0.z); Xb[cg+3][srow] = f2bf(g*x0.w);
      Xb[cg+4][srow] = f2bf(g*x1.x); Xb[cg+5][srow] = f2bf(g*x1.y);
      Xb[cg+6][srow] = f2bf(g*x1.z); Xb[cg+7][srow] = f2bf(g*x1.w);
      Bb[cg+0][srow] = f2bf(b0.x);   Bb[cg+1][srow] = f2bf(b0.y);
      Bb[cg+2][srow] = f2bf(b0.z);   Bb[cg+3][srow] = f2bf(b0.w);
      Bb[cg+4][srow] = f2bf(b1.x);   Bb[cg+5][srow] = f2bf(b1.y);
      Bb[cg+6][srow] = f2bf(b1.z);   Bb[cg+7][srow] = f2bf(b1.w);
    }
    __syncthreads();
    short8 af = *(const short8*)&Xb[w*16 + fr][kq];
#pragma unroll
    for (int j = 0; j < 4; ++j) {
      short8 bf8 = *(const short8*)&Bb[j*16 + fr][kq];
      acc[j] = __builtin_amdgcn_mfma_f32_16x16x32_bf16(af, bf8, acc[j], 0, 0, 0);
    }
  }
  const int col = lane & 15;
  const int rg = (lane >> 4) * 4;
  size_t base = (((size_t)r*NCH + c)*NHEADS + h) * (size_t)(HEADDIM*D_STATE);
#pragma unroll
  for (int j = 0; j < 4; ++j)
#pragma unroll
    for (int q = 0; q < 4; ++q)
      SCH[base + (size_t)(w*16 + rg + q)*D_STATE + j*16 + col] = acc[j][q];
}

// ---------------- prefix-combine chunk states -> SPREV ----------------
__global__ __launch_bounds__(256) void state_combine_kernel(const float* __restrict__ SCH,
                                                            const float* __restrict__ CUMS,
                                                            float* __restrict__ SPREV) {
  int bid = blockIdx.x;          // r*128 + h*4 + pq
  int pq = bid & 3;
  int h = (bid >> 2) & 31;
  int r = bid >> 7;
  int tid = threadIdx.x;
  int p = pq*16 + (tid >> 4);
  int n = (tid & 15) * 4;
  float4 S = make_float4(0.f, 0.f, 0.f, 0.f);
  for (int c = 0; c < NCH; ++c) {
    size_t off = ((((size_t)r*NCH + c)*NHEADS + h)*HEADDIM + p)*D_STATE + n;
    *(float4*)(SPREV + off) = S;
    float dec = __expf(CUMS[((size_t)r*NHEADS + h)*SEQLEN + c*CHUNK + 255]);
    float4 v = *(const float4*)(SCH + off);
    S.x = dec*S.x + v.x; S.y = dec*S.y + v.y;
    S.z = dec*S.z + v.z; S.w = dec*S.w + v.w;
  }
}

// ---------------- Y = intra(triangular, MFMA) + inter (MFMA, fwd only) ----------------
__global__ __launch_bounds__(256) void yscan_kernel(const float* __restrict__ XT,
                                                    const float* __restrict__ DTt,
                                                    const float* __restrict__ CUMS,
                                                    const float* __restrict__ CBs,
                                                    const float* __restrict__ SPREV,
                                                    float* __restrict__ Y) {
  __shared__ unsigned short Xb[64][40];  // X slab transposed [p][s]
  __shared__ float dts[CHUNK];
  __shared__ float cums[CHUNK];
  int tid = threadIdx.x;
  int lane = tid & 63;
  int w = tid >> 6;
  int c = blockIdx.x;
  int rh = blockIdx.y;
  int h = rh & 31;
  int r = rh >> 5;
  int bi = r & 1;
  dts[tid]  = DTt[(size_t)rh*SEQLEN + c*CHUNK + tid];
  cums[tid] = CUMS[(size_t)rh*SEQLEN + c*CHUNK + tid];
  __syncthreads();
  const int fr = lane & 15;
  const int kq = (lane >> 4) * 8;
  const int wt0 = w * 64;
  float ct[4];
#pragma unroll
  for (int i = 0; i < 4; ++i) ct[i] = cums[wt0 + i*16 + fr];
  floatx4 acc[4][4] = {};
  size_t cbbase = (((size_t)r*NCH + c) * CHUNK) * CHUNK;
  const int maxsl = 2*w + 1;
  for (int sl = 0; sl < 8; ++sl) {
    int s0 = sl * 32;
    __syncthreads();
    {
      int srow = tid >> 3;
      int p0 = (tid & 7) * 4;
      int L = c*CHUNK + s0 + srow;
      if (r >= 2) L = flip_l(L);
      const float* xrow = XT + ((size_t)bi*SEQLEN + L)*CONV_DIM + h*HEADDIM;
#pragma unroll
      for (int half = 0; half < 2; ++half) {
        float4 v = *(const float4*)(xrow + p0 + half*32);
        Xb[p0 + half*32 + 0][srow] = f2bf(v.x);
        Xb[p0 + half*32 + 1][srow] = f2bf(v.y);
        Xb[p0 + half*32 + 2][srow] = f2bf(v.z);
        Xb[p0 + half*32 + 3][srow] = f2bf(v.w);
      }
    }
    __syncthreads();
    if (sl <= maxsl) {
      float cs[8], dtv[8];
#pragma unroll
      for (int j = 0; j < 8; ++j) { cs[j] = cums[s0 + kq + j]; dtv[j] = dts[s0 + kq + j]; }
      short8 bfr[4];
#pragma unroll
      for (int j = 0; j < 4; ++j)
        bfr[j] = *(const short8*)&Xb[j*16 + fr][kq];
#pragma unroll
      for (int i = 0; i < 4; ++i) {
        int t = wt0 + i*16 + fr;
        const float* cbrow = CBs + cbbase + (size_t)t*CHUNK + s0 + kq;
        float4 c0 = *(const float4*)cbrow;
        float4 c1 = *(const float4*)(cbrow + 4);
        float cb[8] = {c0.x,c0.y,c0.z,c0.w,c1.x,c1.y,c1.z,c1.w};
        short8 af;
#pragma unroll
        for (int j = 0; j < 8; ++j) {
          int s = s0 + kq + j;
          float wv = (s <= t) ? cb[j] * __expf(ct[i] - cs[j]) * dtv[j] : 0.f;
          af[j] = (short)f2bf(wv);
        }
#pragma unroll
        for (int j = 0; j < 4; ++j)
          acc[i][j] = __builtin_amdgcn_mfma_f32_16x16x32_bf16(af, bfr[j], acc[i][j], 0, 0, 0);
      }
    }
  }
  if (r < 2) {   // inter-chunk term: (E*C) @ Sprev^T
    float ect[4];
#pragma unroll
    for (int i = 0; i < 4; ++i) ect[i] = __expf(ct[i]);
    const float* spbase = SPREV + (((size_t)r*NCH + c)*NHEADS + h) * (size_t)(HEADDIM*D_STATE);
#pragma unroll
    for (int ns = 0; ns < 2; ++ns) {
      int n0 = ns * 32;
      short8 bfr[4];
#pragma unroll
      for (int j = 0; j < 4; ++j) {
        const float* sp = spbase + (size_t)(j*16 + fr)*D_STATE + n0 + kq;
        float4 s0v = *(const float4*)sp;
        float4 s1v = *(const float4*)(sp + 4);
        short8 bb;
        bb[0]=(short)f2bf(s0v.x); bb[1]=(short)f2bf(s0v.y); bb[2]=(short)f2bf(s0v.z); bb[3]=(short)f2bf(s0v.w);
        bb[4]=(short)f2bf(s1v.x); bb[5]=(short)f2bf(s1v.y); bb[6]=(short)f2bf(s1v.z); bb[7]=(short)f2bf(s1v.w);
        bfr[j] = bb;
      }
#pragma unroll
      for (int i = 0; i < 4; ++i) {
        int t = wt0 + i*16 + fr;
        const float* crow = XT + ((size_t)bi*SEQLEN + c*CHUNK + t)*CONV_DIM + D_INNER + GN + n0 + kq;
        float4 c0 = *(const float4*)crow;
        float4 c1 = *(const float4*)(crow + 4);
        short8 af;
        af[0]=(short)f2bf(c0.x*ect[i]); af[1]=(short)f2bf(c0.y*ect[i]);
        af[2]=(short)f2bf(c0.z*ect[i]); af[3]=(short)f2bf(c0.w*ect[i]);
        af[4]=(short)f2bf(c1.x*ect[i]); af[5]=(short)f2bf(c1.y*ect[i]);
        af[6]=(short)f2bf(c1.z*ect[i]); af[7]=(short)f2bf(c1.w*ect[i]);
#pragma unroll
        for (int j = 0; j < 4; ++j)
          acc[i][j] = __builtin_amdgcn_mfma_f32_16x16x32_bf16(af, bfr[j], acc[i][j], 0, 0, 0);
      }
    }
  }
  const int rg = (lane >> 4) * 4;
  size_t ybase = ((size_t)r*SEQLEN + c*CHUNK)*D_INNER + h*HEADDIM;
#pragma unroll
  for (int i = 0; i < 4; ++i)
#pragma unroll
    for (int j = 0; j < 4; ++j)
#pragma unroll
      for (int q = 0; q < 4; ++q)
        Y[ybase + (size_t)(wt0 + i*16 + rg + q)*D_INNER + j*16 + fr] = acc[i][j][q];
}

// ---------------- shifts + x_res + RMSNorm + gate (-> bf16) ----------------
__global__ __launch_bounds__(256) void combine_kernel(const float* __restrict__ Y,
                                                      const float* __restrict__ XT,
                                                      const float* __restrict__ FCD,
                                                      const float* __restrict__ Dp,
                                                      const float* __restrict__ Z,
                                                      const float* __restrict__ norm_w,
                                                      unsigned short* __restrict__ YPb) {
  __shared__ float red[256];
  int row = blockIdx.x;
  int bi = row >> 11;
  int l = row & 2047;
  int s = l >> 3, fr = l & 7;
  int tid = threadIdx.x;
  const float* yf = (l >= 1) ? Y + ((size_t)bi*SEQLEN + (l-1))*D_INNER : nullptr;
  const float* yr = (s >= 1) ? Y + ((size_t)(2+bi)*SEQLEN + ((s-1)*8 + (7-fr)))*D_INNER : nullptr;
  const float* xr = XT + ((size_t)bi*SEQLEN + l)*CONV_DIM;
  const float* fc = FCD + (size_t)row*NHEADS;
  float v[8];
  float ss = 0.f;
#pragma unroll
  for (int q = 0; q < 8; ++q) {
    int d = q*256 + tid;
    float val = xr[d] * (fc[d >> 6] + Dp[d >> 6]);
    if (yf) val += yf[d];
    if (yr) val += yr[d];
    v[q] = val;
    ss += val * val;
  }
  red[tid] = ss;
  __syncthreads();
  for (int ofs = 128; ofs > 0; ofs >>= 1) {
    if (tid < ofs) red[tid] += red[tid + ofs];
    __syncthreads();
  }
  float rs = rsqrtf(red[0] / (float)D_INNER + 1e-5f);
  const float* zrow = Z + ((size_t)bi*SEQLEN + l)*ZLD;
#pragma unroll
  for (int q = 0; q < 8; ++q) {
    int d = q*256 + tid;
    YPb[(size_t)row*D_INNER + d] = f2bf(v[q] * rs * norm_w[d] * silu_f(zrow[d]));
  }
}

extern "C" void kernel_launch(void* const* d_in, const int* in_sizes, int n_in,
                              void* d_out, int out_size, void* d_ws, size_t ws_size,
                              hipStream_t stream) {
  (void)in_sizes; (void)n_in; (void)out_size; (void)ws_size;
  const float* u          = (const float*)d_in[0];
  const float* in_proj_w  = (const float*)d_in[1];
  const float* conv_sp_w  = (const float*)d_in[2];
  const float* conv_sp_b  = (const float*)d_in[3];
  const float* conv_tp_w  = (const float*)d_in[4];
  const float* conv_tp_b  = (const float*)d_in[5];
  const float* dt_bias    = (const float*)d_in[6];
  const float* A_log      = (const float*)d_in[7];
  const float* Dp         = (const float*)d_in[8];
  const float* fc_D_w     = (const float*)d_in[9];
  const float* norm_w     = (const float*)d_in[10];
  const float* out_proj_w = (const float*)d_in[11];
  float* out = (float*)d_out;
  float* ws = (float*)d_ws;

  // workspace layout (f32 elements)
  float* Z     = ws;                       // 17,825,792
  float* SH    = Z     + 17825792ULL;      // 9,437,184  (CBs -> YPb)
  float* XT    = SH    + 9437184ULL;       // 9,437,184
  float* DTt   = XT    + 9437184ULL;       // 262,144
  float* Yb    = DTt   + 262144ULL;        // 16,777,216 (hosts bf16 staging + SCH early)
  float* SPREV = Yb    + 16777216ULL;      // 2,097,152
  float* FCD   = SPREV + 2097152ULL;       // 131,072
  float* DTraw = FCD   + 131072ULL;        // 262,144
  float* CUMS  = DTraw + 262144ULL;        // 262,144

  unsigned short* Ub  = (unsigned short*)Yb;
  unsigned short* Wb  = (unsigned short*)Yb + 4194304ULL;
  float* SCH = Yb + 8388608ULL;            // 2,097,152 (dead before yscan writes Yb)
  unsigned short* Wob = (unsigned short*)Yb;
  unsigned short* YPb = (unsigned short*)SH;

  cast_bf16_kernel<<<4096, 256, 0, stream>>>(u, Ub);
  cast_bf16_kernel<<<4352, 256, 0, stream>>>(in_proj_w, Wb);
  gemm_bf16<<<dim3(34, 32), 256, 0, stream>>>(Ub, 1024, Wb, 1024, Z, ZLD, 1024);
  gemm_skinny_f32<<<256, 256, 0, stream>>>(u, 1024, in_proj_w + 4352ULL*1024, 1024,
                                           DTraw, 64, 64, 1024);
  dtscan_kernel<<<1024, 256, 0, stream>>>(DTraw, dt_bias, A_log, DTt, CUMS);
  conv_fused_kernel<<<dim3(72, 256, 2), 256, 0, stream>>>(Z, conv_sp_w, conv_sp_b,
                                                          conv_tp_w, conv_tp_b, XT);
  gemm_skinny_f32<<<256, 256, 0, stream>>>(XT, 2304, fc_D_w, 2048, FCD, 32, 32, 2048);
  cb_kernel<<<dim3(16, 8, 4), 256, 0, stream>>>(XT, SH);
  chunk_state_kernel<<<dim3(NCH, NHEADS, 2), 256, 0, stream>>>(XT, DTt, CUMS, SCH);
  state_combine_kernel<<<256, 256, 0, stream>>>(SCH, CUMS, SPREV);
  yscan_kernel<<<dim3(8, 128), 256, 0, stream>>>(XT, DTt, CUMS, SH, SPREV, Yb);
  combine_kernel<<<4096, 256, 0, stream>>>(Yb, XT, FCD, Dp, Z, norm_w, YPb);
  cast_bf16_kernel<<<2048, 256, 0, stream>>>(out_proj_w, Wob);
  gemm_bf16<<<dim3(8, 32), 256, 0, stream>>>(YPb, 2048, Wob, 2048, out, 1024, 2048);
}

// Round 6
// 465.202 us; speedup vs baseline: 3.1479x; 1.1033x over previous
//
#include <hip/hip_runtime.h>
#include <hip/hip_bf16.h>
#include <math.h>

#define D_STATE   64
#define HEADDIM   64
#define D_INNER   2048
#define NHEADS    32
#define GN        64
#define CONV_DIM  2304
#define D_IN_PROJ 4416
#define ZLD       4352      /* z + xBC columns only (dt handled separately) */
#define K_SP      7
#define K_TP      4
#define CHUNK     256
#define BATCHN    2
#define FRAMES    8
#define SPATIAL   256
#define SEQLEN    2048
#define NCH       8
#define MTOT      4096

typedef __attribute__((ext_vector_type(8))) short short8;
typedef __attribute__((ext_vector_type(4))) float floatx4;

__device__ __forceinline__ float silu_f(float x) { return x / (1.f + __expf(-x)); }
__device__ __forceinline__ int flip_l(int l) { return (l & ~7) | (7 - (l & 7)); }
__device__ __forceinline__ unsigned short f2bf(float f) {
  unsigned int u = __float_as_uint(f);
  unsigned int r = (u + 0x7fffu + ((u >> 16) & 1u)) >> 16;
  return (unsigned short)r;
}
__device__ __forceinline__ void gload_lds16(const unsigned short* g, unsigned short* l) {
  __builtin_amdgcn_global_load_lds((const __attribute__((address_space(1))) void*)g,
                                   (__attribute__((address_space(3))) void*)l, 16, 0, 0);
}

// ---------------- f32 -> bf16 cast ----------------
__global__ __launch_bounds__(256) void cast_bf16_kernel(const float* __restrict__ in,
                                                        unsigned short* __restrict__ out) {
  size_t i = ((size_t)blockIdx.x * 256 + threadIdx.x) * 4;
  float4 v = *(const float4*)(in + i);
  ushort4 o;
  o.x = f2bf(v.x); o.y = f2bf(v.y); o.z = f2bf(v.z); o.w = f2bf(v.w);
  *(ushort4*)(out + i) = o;
}

// ---------------- bf16 MFMA GEMM: C = A * B^T ----------------
__global__ __launch_bounds__(256) void gemm_bf16(
    const unsigned short* __restrict__ A, int lda,
    const unsigned short* __restrict__ B, int ldb,
    float* __restrict__ C, int ldc, int K) {
  __shared__ unsigned short As[128 * 32];
  __shared__ unsigned short Bs[128 * 32];
  const int tid = threadIdx.x;
  const int lane = tid & 63;
  const int w = tid >> 6;
  const int m0 = blockIdx.y * 128;
  const int n0 = blockIdx.x * 128;
  const int wm = (w >> 1) * 64;
  const int wn = (w & 1) * 64;
  const int srow = lane >> 2;
  const int scol = (lane & 3) * 8;
  floatx4 acc[4][4] = {};
  for (int k0 = 0; k0 < K; k0 += 32) {
#pragma unroll
    for (int it = 0; it < 2; ++it) {
      int ch = it * 4 + w;
      const unsigned short* ga = A + (size_t)(m0 + ch * 16 + srow) * lda + k0 + scol;
      const unsigned short* gb = B + (size_t)(n0 + ch * 16 + srow) * ldb + k0 + scol;
      gload_lds16(ga, &As[ch * 512]);
      gload_lds16(gb, &Bs[ch * 512]);
    }
    __syncthreads();
    const int fr = lane & 15;
    const int kq = (lane >> 4) * 8;
    short8 af[4], bfr[4];
#pragma unroll
    for (int i = 0; i < 4; ++i)
      af[i] = *(const short8*)&As[(wm + i * 16 + fr) * 32 + kq];
#pragma unroll
    for (int j = 0; j < 4; ++j)
      bfr[j] = *(const short8*)&Bs[(wn + j * 16 + fr) * 32 + kq];
#pragma unroll
    for (int i = 0; i < 4; ++i)
#pragma unroll
      for (int j = 0; j < 4; ++j)
        acc[i][j] = __builtin_amdgcn_mfma_f32_16x16x32_bf16(af[i], bfr[j], acc[i][j], 0, 0, 0);
    __syncthreads();
  }
  const int col = lane & 15;
  const int rg = (lane >> 4) * 4;
#pragma unroll
  for (int i = 0; i < 4; ++i)
#pragma unroll
    for (int j = 0; j < 4; ++j)
#pragma unroll
      for (int r = 0; r < 4; ++r)
        C[(size_t)(m0 + wm + i * 16 + rg + r) * ldc + (n0 + wn + j * 16 + col)] = acc[i][j][r];
}

// ---------------- skinny f32 GEMM: C[M x N(<=64)] = A * B^T, M-tile=16 ----------------
__global__ __launch_bounds__(256) void gemm_skinny_f32(
    const float* __restrict__ A, int lda,
    const float* __restrict__ B, int ldb,
    float* __restrict__ C, int ldc, int N, int K) {
  __shared__ float Bs[64][68];
  __shared__ float As[16][68];
  const int tid = threadIdx.x;
  const int m0 = blockIdx.x * 16;
  const int tm = tid >> 4;
  const int tn4 = (tid & 15) * 4;
  float acc[4] = {0.f, 0.f, 0.f, 0.f};
  for (int k0 = 0; k0 < K; k0 += 64) {
    __syncthreads();
    {
      int bn = tid >> 2;
      int bk = (tid & 3) * 16;
      if (bn < N) {
#pragma unroll
        for (int q = 0; q < 4; ++q) {
          float4 v = *(const float4*)(B + (size_t)bn * ldb + k0 + bk + q * 4);
          Bs[bk + q*4 + 0][bn] = v.x;
          Bs[bk + q*4 + 1][bn] = v.y;
          Bs[bk + q*4 + 2][bn] = v.z;
          Bs[bk + q*4 + 3][bn] = v.w;
        }
      } else {
#pragma unroll
        for (int q = 0; q < 4; ++q) {
          Bs[bk + q*4 + 0][bn] = 0.f;
          Bs[bk + q*4 + 1][bn] = 0.f;
          Bs[bk + q*4 + 2][bn] = 0.f;
          Bs[bk + q*4 + 3][bn] = 0.f;
        }
      }
      int am = tid >> 4;
      int ak = (tid & 15) * 4;
      *(float4*)&As[am][ak] = *(const float4*)(A + (size_t)(m0 + am) * lda + k0 + ak);
    }
    __syncthreads();
#pragma unroll 8
    for (int k = 0; k < 64; ++k) {
      float a = As[tm][k];
      float4 b4 = *(const float4*)&Bs[k][tn4];
      acc[0] += a * b4.x; acc[1] += a * b4.y;
      acc[2] += a * b4.z; acc[3] += a * b4.w;
    }
  }
  if (tn4 < N)
    *(float4*)(C + (size_t)(m0 + tm) * ldc + tn4) = make_float4(acc[0], acc[1], acc[2], acc[3]);
}

// ---------------- dt = softplus(dt_raw + bias), flip for reverse; + chunk-local cumsum ----------------
__global__ __launch_bounds__(256) void dtscan_kernel(const float* __restrict__ DTraw,
                                                     const float* __restrict__ dt_bias,
                                                     const float* __restrict__ A_log,
                                                     float* __restrict__ DTt,
                                                     float* __restrict__ CUMS) {
  __shared__ float sc[256];
  int tid = threadIdx.x;
  int idx = blockIdx.x * 256 + tid;
  int l  = idx & 2047;
  int rh = idx >> 11;
  int h  = rh & 31;
  int r  = rh >> 5;
  int bi = r & 1;
  int ls = (r < 2) ? l : flip_l(l);
  int ch = (r < 2) ? h : NHEADS + h;
  float raw = DTraw[((size_t)bi * SEQLEN + ls) * 64 + ch] + dt_bias[h];
  float dtv = (raw > 20.f) ? raw : log1pf(__expf(raw));
  DTt[idx] = dtv;
  float A = -__expf(A_log[h]);
  float run = dtv * A;
  sc[tid] = run;
  __syncthreads();
#pragma unroll
  for (int ofs = 1; ofs < 256; ofs <<= 1) {
    float add = (tid >= ofs) ? sc[tid - ofs] : 0.f;
    __syncthreads();
    run += add;
    sc[tid] = run;
    __syncthreads();
  }
  CUMS[idx] = run;
}

// ---------------- fused convs v2: register sliding-window, float4 channels ----------------
// block = (128-ch tile, 8-spatial tile, batch); thread = (fr, c4 group).
__global__ __launch_bounds__(256) void conv_fused2_kernel(const float* __restrict__ Z,
                                                          const float* __restrict__ wsp,
                                                          const float* __restrict__ bsp,
                                                          const float* __restrict__ wtp,
                                                          const float* __restrict__ btp,
                                                          float* __restrict__ XT) {
  __shared__ float4 xsl[8][8][32];   // [fr][so][c4g]  (32 KB)
  const int tid = threadIdx.x;
  const int g  = tid & 31;        // c4 group
  const int fr = tid >> 5;        // frame
  const int c  = blockIdx.x * 128 + g * 4;
  const int s0 = blockIdx.y * 8;
  const int bi = blockIdx.z;
  // per-channel weights -> registers
  float wsp_r[4][K_SP];
#pragma unroll
  for (int ch = 0; ch < 4; ++ch)
#pragma unroll
    for (int j = 0; j < K_SP; ++j) wsp_r[ch][j] = wsp[(c + ch) * K_SP + j];
  float4 bsp4 = *(const float4*)(bsp + c);
  // halo load: ss in [s0-3, s0+10]
  float4 z[14];
#pragma unroll
  for (int i = 0; i < 14; ++i) {
    int ss = s0 - 3 + i;
    if (0 <= ss && ss < SPATIAL)
      z[i] = *(const float4*)(Z + ((size_t)bi * SEQLEN + (ss*8 + fr)) * ZLD + D_INNER + c);
    else
      z[i] = make_float4(0.f, 0.f, 0.f, 0.f);
  }
#pragma unroll
  for (int so = 0; so < 8; ++so) {
    float4 a = bsp4;
#pragma unroll
    for (int j = 0; j < K_SP; ++j) {
      a.x += wsp_r[0][j] * z[so + j].x;
      a.y += wsp_r[1][j] * z[so + j].y;
      a.z += wsp_r[2][j] * z[so + j].z;
      a.w += wsp_r[3][j] * z[so + j].w;
    }
    a.x = silu_f(a.x); a.y = silu_f(a.y); a.z = silu_f(a.z); a.w = silu_f(a.w);
    xsl[fr][so][g] = a;
  }
  __syncthreads();
  float wtp_r[4][K_TP];
#pragma unroll
  for (int ch = 0; ch < 4; ++ch)
#pragma unroll
    for (int j = 0; j < K_TP; ++j) wtp_r[ch][j] = wtp[(c + ch) * K_TP + j];
  float4 btp4 = *(const float4*)(btp + c);
#pragma unroll
  for (int so = 0; so < 8; ++so) {
    float4 t = btp4;
#pragma unroll
    for (int j = 0; j < K_TP; ++j) {
      int ff = fr + j - (K_TP - 1);
      if (ff >= 0) {
        float4 xv = xsl[ff][so][g];
        t.x += wtp_r[0][j] * xv.x;
        t.y += wtp_r[1][j] * xv.y;
        t.z += wtp_r[2][j] * xv.z;
        t.w += wtp_r[3][j] * xv.w;
      }
    }
    t.x = silu_f(t.x); t.y = silu_f(t.y); t.z = silu_f(t.z); t.w = silu_f(t.w);
    *(float4*)(XT + ((size_t)bi * SEQLEN + ((s0 + so)*8 + fr)) * CONV_DIM + c) = t;
  }
}

// ---------------- CB[t][s] = sum_n C[t][n] B[s][n], per (r,c)  (t-major) ----------------
__global__ __launch_bounds__(256) void cb_kernel(const float* __restrict__ XT,
                                                 float* __restrict__ CBs) {
  __shared__ float Ct[64][65];
  __shared__ float Bt[64][65];
  int tid = threadIdx.x;
  int t0 = (blockIdx.x & 3) * 64;
  int s0 = (blockIdx.x >> 2) * 64;
  if (s0 > t0) return;
  int c = blockIdx.y;
  int r = blockIdx.z;
  int bi = r & 1;
  int bOff = D_INNER + ((r < 2) ? 0 : 2*GN);
  int cOff = bOff + GN;
  int lrow = tid >> 4;
  int n4 = (tid & 15) << 2;
#pragma unroll
  for (int rep = 0; rep < 4; ++rep) {
    int tl = rep * 16 + lrow;
    int Lc = c * CHUNK + t0 + tl;
    int Ls = c * CHUNK + s0 + tl;
    if (r >= 2) { Lc = flip_l(Lc); Ls = flip_l(Ls); }
    float4 cv = *(const float4*)(XT + ((size_t)bi*SEQLEN + Lc)*CONV_DIM + cOff + n4);
    float4 bv = *(const float4*)(XT + ((size_t)bi*SEQLEN + Ls)*CONV_DIM + bOff + n4);
    Ct[n4+0][tl] = cv.x; Ct[n4+1][tl] = cv.y; Ct[n4+2][tl] = cv.z; Ct[n4+3][tl] = cv.w;
    Bt[n4+0][tl] = bv.x; Bt[n4+1][tl] = bv.y; Bt[n4+2][tl] = bv.z; Bt[n4+3][tl] = bv.w;
  }
  __syncthreads();
  int txx = tid & 15;
  int tyy = tid >> 4;
  float acc[4][4] = {{0.f,0.f,0.f,0.f},{0.f,0.f,0.f,0.f},{0.f,0.f,0.f,0.f},{0.f,0.f,0.f,0.f}};
#pragma unroll
  for (int n = 0; n < D_STATE; ++n) {
    float cr[4], br[4];
#pragma unroll
    for (int i = 0; i < 4; ++i) cr[i] = Ct[n][tyy + 16*i];
#pragma unroll
    for (int j = 0; j < 4; ++j) br[j] = Bt[n][txx + 16*j];
#pragma unroll
    for (int i = 0; i < 4; ++i)
#pragma unroll
      for (int j = 0; j < 4; ++j)
        acc[i][j] += cr[i] * br[j];
  }
  size_t base = (((size_t)r*NCH + c) * CHUNK) * CHUNK;
#pragma unroll
  for (int i = 0; i < 4; ++i)
#pragma unroll
    for (int j = 0; j < 4; ++j)
      CBs[base + (size_t)(t0 + tyy + 16*i)*CHUNK + (s0 + txx + 16*j)] = acc[i][j];
}

// ---------------- per-chunk state sums (MFMA, forward r=0,1 only) ----------------
__global__ __launch_bounds__(256) void chunk_state_kernel(const float* __restrict__ XT,
                                                          const float* __restrict__ DTt,
                                                          const float* __restrict__ CUMS,
                                                          float* __restrict__ SCH) {
  __shared__ unsigned short Xb[64][40];
  __shared__ unsigned short Bb[64][40];
  int tid = threadIdx.x;
  int lane = tid & 63;
  int w = tid >> 6;
  int c = blockIdx.x;
  int h = blockIdx.y;
  int r = blockIdx.z;
  int bi = r;
  int rh = r * NHEADS + h;
  float cl = CUMS[(size_t)rh*SEQLEN + c*CHUNK + 255];
  const int fr = lane & 15;
  const int kq = (lane >> 4) * 8;
  floatx4 acc[4] = {};
  for (int sl = 0; sl < 8; ++sl) {
    int s0 = sl * 32;
    __syncthreads();
    {
      int srow = tid >> 3;
      int cg = (tid & 7) * 8;
      int l = c*CHUNK + s0 + srow;
      float g = __expf(cl - CUMS[(size_t)rh*SEQLEN + l]) * DTt[(size_t)rh*SEQLEN + l];
      const float* row = XT + ((size_t)bi*SEQLEN + l)*CONV_DIM;
      float4 x0 = *(const float4*)(row + h*HEADDIM + cg);
      float4 x1 = *(const float4*)(row + h*HEADDIM + cg + 4);
      float4 b0 = *(const float4*)(row + D_INNER + cg);
      float4 b1 = *(const float4*)(row + D_INNER + cg + 4);
      Xb[cg+0][srow] = f2bf(g*x0.x); Xb[cg+1][srow] = f2bf(g*x0.y);
      Xb[cg+2][srow] = f2bf(g*x0.z); Xb[cg+3][srow] = f2bf(g*x0.w);
      Xb[cg+4][srow] = f2bf(g*x1.x); Xb[cg+5][srow] = f2bf(g*x1.y);
      Xb[cg+6][srow] = f2bf(g*x1.z); Xb[cg+7][srow] = f2bf(g*x1.w);
      Bb[cg+0][srow] = f2bf(b0.x);   Bb[cg+1][srow] = f2bf(b0.y);
      Bb[cg+2][srow] = f2bf(b0.z);   Bb[cg+3][srow] = f2bf(b0.w);
      Bb[cg+4][srow] = f2bf(b1.x);   Bb[cg+5][srow] = f2bf(b1.y);
      Bb[cg+6][srow] = f2bf(b1.z);   Bb[cg+7][srow] = f2bf(b1.w);
    }
    __syncthreads();
    short8 af = *(const short8*)&Xb[w*16 + fr][kq];
#pragma unroll
    for (int j = 0; j < 4; ++j) {
      short8 bf8 = *(const short8*)&Bb[j*16 + fr][kq];
      acc[j] = __builtin_amdgcn_mfma_f32_16x16x32_bf16(af, bf8, acc[j], 0, 0, 0);
    }
  }
  const int col = lane & 15;
  const int rg = (lane >> 4) * 4;
  size_t base = (((size_t)r*NCH + c)*NHEADS + h) * (size_t)(HEADDIM*D_STATE);
#pragma unroll
  for (int j = 0; j < 4; ++j)
#pragma unroll
    for (int q = 0; q < 4; ++q)
      SCH[base + (size_t)(w*16 + rg + q)*D_STATE + j*16 + col] = acc[j][q];
}

// ---------------- prefix-combine chunk states -> SPREV ----------------
__global__ __launch_bounds__(256) void state_combine_kernel(const float* __restrict__ SCH,
                                                            const float* __restrict__ CUMS,
                                                            float* __restrict__ SPREV) {
  int bid = blockIdx.x;
  int pq = bid & 3;
  int h = (bid >> 2) & 31;
  int r = bid >> 7;
  int tid = threadIdx.x;
  int p = pq*16 + (tid >> 4);
  int n = (tid & 15) * 4;
  float4 S = make_float4(0.f, 0.f, 0.f, 0.f);
  for (int c = 0; c < NCH; ++c) {
    size_t off = ((((size_t)r*NCH + c)*NHEADS + h)*HEADDIM + p)*D_STATE + n;
    *(float4*)(SPREV + off) = S;
    float dec = __expf(CUMS[((size_t)r*NHEADS + h)*SEQLEN + c*CHUNK + 255]);
    float4 v = *(const float4*)(SCH + off);
    S.x = dec*S.x + v.x; S.y = dec*S.y + v.y;
    S.z = dec*S.z + v.z; S.w = dec*S.w + v.w;
  }
}

// ---------------- Y = intra(triangular, MFMA) + inter (MFMA, fwd only) ----------------
__global__ __launch_bounds__(256) void yscan_kernel(const float* __restrict__ XT,
                                                    const float* __restrict__ DTt,
                                                    const float* __restrict__ CUMS,
                                                    const float* __restrict__ CBs,
                                                    const float* __restrict__ SPREV,
                                                    float* __restrict__ Y) {
  __shared__ unsigned short Xb[64][40];
  __shared__ float dts[CHUNK];
  __shared__ float cums[CHUNK];
  int tid = threadIdx.x;
  int lane = tid & 63;
  int w = tid >> 6;
  int c = blockIdx.x;
  int rh = blockIdx.y;
  int h = rh & 31;
  int r = rh >> 5;
  int bi = r & 1;
  dts[tid]  = DTt[(size_t)rh*SEQLEN + c*CHUNK + tid];
  cums[tid] = CUMS[(size_t)rh*SEQLEN + c*CHUNK + tid];
  __syncthreads();
  const int fr = lane & 15;
  const int kq = (lane >> 4) * 8;
  const int wt0 = w * 64;
  float ct[4];
#pragma unroll
  for (int i = 0; i < 4; ++i) ct[i] = cums[wt0 + i*16 + fr];
  floatx4 acc[4][4] = {};
  size_t cbbase = (((size_t)r*NCH + c) * CHUNK) * CHUNK;
  const int maxsl = 2*w + 1;
  for (int sl = 0; sl < 8; ++sl) {
    int s0 = sl * 32;
    __syncthreads();
    {
      int srow = tid >> 3;
      int p0 = (tid & 7) * 4;
      int L = c*CHUNK + s0 + srow;
      if (r >= 2) L = flip_l(L);
      const float* xrow = XT + ((size_t)bi*SEQLEN + L)*CONV_DIM + h*HEADDIM;
#pragma unroll
      for (int half = 0; half < 2; ++half) {
        float4 v = *(const float4*)(xrow + p0 + half*32);
        Xb[p0 + half*32 + 0][srow] = f2bf(v.x);
        Xb[p0 + half*32 + 1][srow] = f2bf(v.y);
        Xb[p0 + half*32 + 2][srow] = f2bf(v.z);
        Xb[p0 + half*32 + 3][srow] = f2bf(v.w);
      }
    }
    __syncthreads();
    if (sl <= maxsl) {
      float cs[8], dtv[8];
#pragma unroll
      for (int j = 0; j < 8; ++j) { cs[j] = cums[s0 + kq + j]; dtv[j] = dts[s0 + kq + j]; }
      short8 bfr[4];
#pragma unroll
      for (int j = 0; j < 4; ++j)
        bfr[j] = *(const short8*)&Xb[j*16 + fr][kq];
#pragma unroll
      for (int i = 0; i < 4; ++i) {
        int t = wt0 + i*16 + fr;
        const float* cbrow = CBs + cbbase + (size_t)t*CHUNK + s0 + kq;
        float4 c0 = *(const float4*)cbrow;
        float4 c1 = *(const float4*)(cbrow + 4);
        float cb[8] = {c0.x,c0.y,c0.z,c0.w,c1.x,c1.y,c1.z,c1.w};
        short8 af;
#pragma unroll
        for (int j = 0; j < 8; ++j) {
          int s = s0 + kq + j;
          float wv = (s <= t) ? cb[j] * __expf(ct[i] - cs[j]) * dtv[j] : 0.f;
          af[j] = (short)f2bf(wv);
        }
#pragma unroll
        for (int j = 0; j < 4; ++j)
          acc[i][j] = __builtin_amdgcn_mfma_f32_16x16x32_bf16(af, bfr[j], acc[i][j], 0, 0, 0);
      }
    }
  }
  if (r < 2) {
    float ect[4];
#pragma unroll
    for (int i = 0; i < 4; ++i) ect[i] = __expf(ct[i]);
    const float* spbase = SPREV + (((size_t)r*NCH + c)*NHEADS + h) * (size_t)(HEADDIM*D_STATE);
#pragma unroll
    for (int ns = 0; ns < 2; ++ns) {
      int n0 = ns * 32;
      short8 bfr[4];
#pragma unroll
      for (int j = 0; j < 4; ++j) {
        const float* sp = spbase + (size_t)(j*16 + fr)*D_STATE + n0 + kq;
        float4 s0v = *(const float4*)sp;
        float4 s1v = *(const float4*)(sp + 4);
        short8 bb;
        bb[0]=(short)f2bf(s0v.x); bb[1]=(short)f2bf(s0v.y); bb[2]=(short)f2bf(s0v.z); bb[3]=(short)f2bf(s0v.w);
        bb[4]=(short)f2bf(s1v.x); bb[5]=(short)f2bf(s1v.y); bb[6]=(short)f2bf(s1v.z); bb[7]=(short)f2bf(s1v.w);
        bfr[j] = bb;
      }
#pragma unroll
      for (int i = 0; i < 4; ++i) {
        int t = wt0 + i*16 + fr;
        const float* crow = XT + ((size_t)bi*SEQLEN + c*CHUNK + t)*CONV_DIM + D_INNER + GN + n0 + kq;
        float4 c0 = *(const float4*)crow;
        float4 c1 = *(const float4*)(crow + 4);
        short8 af;
        af[0]=(short)f2bf(c0.x*ect[i]); af[1]=(short)f2bf(c0.y*ect[i]);
        af[2]=(short)f2bf(c0.z*ect[i]); af[3]=(short)f2bf(c0.w*ect[i]);
        af[4]=(short)f2bf(c1.x*ect[i]); af[5]=(short)f2bf(c1.y*ect[i]);
        af[6]=(short)f2bf(c1.z*ect[i]); af[7]=(short)f2bf(c1.w*ect[i]);
#pragma unroll
        for (int j = 0; j < 4; ++j)
          acc[i][j] = __builtin_amdgcn_mfma_f32_16x16x32_bf16(af, bfr[j], acc[i][j], 0, 0, 0);
      }
    }
  }
  const int rg = (lane >> 4) * 4;
  size_t ybase = ((size_t)r*SEQLEN + c*CHUNK)*D_INNER + h*HEADDIM;
#pragma unroll
  for (int i = 0; i < 4; ++i)
#pragma unroll
    for (int j = 0; j < 4; ++j)
#pragma unroll
      for (int q = 0; q < 4; ++q)
        Y[ybase + (size_t)(wt0 + i*16 + rg + q)*D_INNER + j*16 + fr] = acc[i][j][q];
}

// ---------------- shifts + x_res + RMSNorm + gate (-> bf16) ----------------
__global__ __launch_bounds__(256) void combine_kernel(const float* __restrict__ Y,
                                                      const float* __restrict__ XT,
                                                      const float* __restrict__ FCD,
                                                      const float* __restrict__ Dp,
                                                      const float* __restrict__ Z,
                                                      const float* __restrict__ norm_w,
                                                      unsigned short* __restrict__ YPb) {
  __shared__ float red[256];
  int row = blockIdx.x;
  int bi = row >> 11;
  int l = row & 2047;
  int s = l >> 3, fr = l & 7;
  int tid = threadIdx.x;
  const float* yf = (l >= 1) ? Y + ((size_t)bi*SEQLEN + (l-1))*D_INNER : nullptr;
  const float* yr = (s >= 1) ? Y + ((size_t)(2+bi)*SEQLEN + ((s-1)*8 + (7-fr)))*D_INNER : nullptr;
  const float* xr = XT + ((size_t)bi*SEQLEN + l)*CONV_DIM;
  const float* fc = FCD + (size_t)row*NHEADS;
  float v[8];
  float ss = 0.f;
#pragma unroll
  for (int q = 0; q < 8; ++q) {
    int d = q*256 + tid;
    float val = xr[d] * (fc[d >> 6] + Dp[d >> 6]);
    if (yf) val += yf[d];
    if (yr) val += yr[d];
    v[q] = val;
    ss += val * val;
  }
  red[tid] = ss;
  __syncthreads();
  for (int ofs = 128; ofs > 0; ofs >>= 1) {
    if (tid < ofs) red[tid] += red[tid + ofs];
    __syncthreads();
  }
  float rs = rsqrtf(red[0] / (float)D_INNER + 1e-5f);
  const float* zrow = Z + ((size_t)bi*SEQLEN + l)*ZLD;
#pragma unroll
  for (int q = 0; q < 8; ++q) {
    int d = q*256 + tid;
    YPb[(size_t)row*D_INNER + d] = f2bf(v[q] * rs * norm_w[d] * silu_f(zrow[d]));
  }
}

extern "C" void kernel_launch(void* const* d_in, const int* in_sizes, int n_in,
                              void* d_out, int out_size, void* d_ws, size_t ws_size,
                              hipStream_t stream) {
  (void)in_sizes; (void)n_in; (void)out_size; (void)ws_size;
  const float* u          = (const float*)d_in[0];
  const float* in_proj_w  = (const float*)d_in[1];
  const float* conv_sp_w  = (const float*)d_in[2];
  const float* conv_sp_b  = (const float*)d_in[3];
  const float* conv_tp_w  = (const float*)d_in[4];
  const float* conv_tp_b  = (const float*)d_in[5];
  const float* dt_bias    = (const float*)d_in[6];
  const float* A_log      = (const float*)d_in[7];
  const float* Dp         = (const float*)d_in[8];
  const float* fc_D_w     = (const float*)d_in[9];
  const float* norm_w     = (const float*)d_in[10];
  const float* out_proj_w = (const float*)d_in[11];
  float* out = (float*)d_out;
  float* ws = (float*)d_ws;

  // workspace layout (f32 elements)
  float* Z     = ws;                       // 17,825,792
  float* SH    = Z     + 17825792ULL;      // 9,437,184  (CBs -> YPb)
  float* XT    = SH    + 9437184ULL;       // 9,437,184
  float* DTt   = XT    + 9437184ULL;       // 262,144
  float* Yb    = DTt   + 262144ULL;        // 16,777,216 (hosts bf16 staging + SCH early)
  float* SPREV = Yb    + 16777216ULL;      // 2,097,152
  float* FCD   = SPREV + 2097152ULL;       // 131,072
  float* DTraw = FCD   + 131072ULL;        // 262,144
  float* CUMS  = DTraw + 262144ULL;        // 262,144

  unsigned short* Ub  = (unsigned short*)Yb;
  unsigned short* Wb  = (unsigned short*)Yb + 4194304ULL;
  float* SCH = Yb + 8388608ULL;            // 2,097,152 (dead before yscan writes Yb)
  unsigned short* Wob = (unsigned short*)Yb;
  unsigned short* YPb = (unsigned short*)SH;

  cast_bf16_kernel<<<4096, 256, 0, stream>>>(u, Ub);
  cast_bf16_kernel<<<4352, 256, 0, stream>>>(in_proj_w, Wb);
  gemm_bf16<<<dim3(34, 32), 256, 0, stream>>>(Ub, 1024, Wb, 1024, Z, ZLD, 1024);
  gemm_skinny_f32<<<256, 256, 0, stream>>>(u, 1024, in_proj_w + 4352ULL*1024, 1024,
                                           DTraw, 64, 64, 1024);
  dtscan_kernel<<<1024, 256, 0, stream>>>(DTraw, dt_bias, A_log, DTt, CUMS);
  conv_fused2_kernel<<<dim3(18, 32, 2), 256, 0, stream>>>(Z, conv_sp_w, conv_sp_b,
                                                          conv_tp_w, conv_tp_b, XT);
  gemm_skinny_f32<<<256, 256, 0, stream>>>(XT, 2304, fc_D_w, 2048, FCD, 32, 32, 2048);
  cb_kernel<<<dim3(16, 8, 4), 256, 0, stream>>>(XT, SH);
  chunk_state_kernel<<<dim3(NCH, NHEADS, 2), 256, 0, stream>>>(XT, DTt, CUMS, SCH);
  state_combine_kernel<<<256, 256, 0, stream>>>(SCH, CUMS, SPREV);
  yscan_kernel<<<dim3(8, 128), 256, 0, stream>>>(XT, DTt, CUMS, SH, SPREV, Yb);
  combine_kernel<<<4096, 256, 0, stream>>>(Yb, XT, FCD, Dp, Z, norm_w, YPb);
  cast_bf16_kernel<<<2048, 256, 0, stream>>>(out_proj_w, Wob);
  gemm_bf16<<<dim3(8, 32), 256, 0, stream>>>(YPb, 2048, Wob, 2048, out, 1024, 2048);
}

// Round 7
// 438.204 us; speedup vs baseline: 3.3418x; 1.0616x over previous
//
#include <hip/hip_runtime.h>
#include <hip/hip_bf16.h>
#include <math.h>

#define D_STATE   64
#define HEADDIM   64
#define D_INNER   2048
#define NHEADS    32
#define GN        64
#define CONV_DIM  2304
#define D_IN_PROJ 4416
#define ZLD       4352      /* z + xBC columns only (dt handled separately) */
#define K_SP      7
#define K_TP      4
#define CHUNK     256
#define BATCHN    2
#define FRAMES    8
#define SPATIAL   256
#define SEQLEN    2048
#define NCH       8
#define MTOT      4096

typedef __attribute__((ext_vector_type(8))) short short8;
typedef __attribute__((ext_vector_type(8))) unsigned short ushort8v;
typedef __attribute__((ext_vector_type(4))) float floatx4;

__device__ __forceinline__ float silu_f(float x) { return x / (1.f + __expf(-x)); }
__device__ __forceinline__ int flip_l(int l) { return (l & ~7) | (7 - (l & 7)); }
__device__ __forceinline__ unsigned short f2bf(float f) {
  unsigned int u = __float_as_uint(f);
  unsigned int r = (u + 0x7fffu + ((u >> 16) & 1u)) >> 16;
  return (unsigned short)r;
}
__device__ __forceinline__ float bf2f(unsigned short s) {
  return __uint_as_float(((unsigned int)s) << 16);
}
__device__ __forceinline__ void gload_lds16(const unsigned short* g, unsigned short* l) {
  __builtin_amdgcn_global_load_lds((const __attribute__((address_space(1))) void*)g,
                                   (__attribute__((address_space(3))) void*)l, 16, 0, 0);
}

// ---------------- f32 -> bf16 cast ----------------
__global__ __launch_bounds__(256) void cast_bf16_kernel(const float* __restrict__ in,
                                                        unsigned short* __restrict__ out) {
  size_t i = ((size_t)blockIdx.x * 256 + threadIdx.x) * 4;
  float4 v = *(const float4*)(in + i);
  ushort4 o;
  o.x = f2bf(v.x); o.y = f2bf(v.y); o.z = f2bf(v.z); o.w = f2bf(v.w);
  *(ushort4*)(out + i) = o;
}

// ---------------- bf16 MFMA GEMM (f32 out): C = A * B^T ----------------
__global__ __launch_bounds__(256) void gemm_bf16(
    const unsigned short* __restrict__ A, int lda,
    const unsigned short* __restrict__ B, int ldb,
    float* __restrict__ C, int ldc, int K) {
  __shared__ unsigned short As[128 * 32];
  __shared__ unsigned short Bs[128 * 32];
  const int tid = threadIdx.x;
  const int lane = tid & 63;
  const int w = tid >> 6;
  const int m0 = blockIdx.y * 128;
  const int n0 = blockIdx.x * 128;
  const int wm = (w >> 1) * 64;
  const int wn = (w & 1) * 64;
  const int srow = lane >> 2;
  const int scol = (lane & 3) * 8;
  floatx4 acc[4][4] = {};
  for (int k0 = 0; k0 < K; k0 += 32) {
#pragma unroll
    for (int it = 0; it < 2; ++it) {
      int ch = it * 4 + w;
      gload_lds16(A + (size_t)(m0 + ch * 16 + srow) * lda + k0 + scol, &As[ch * 512]);
      gload_lds16(B + (size_t)(n0 + ch * 16 + srow) * ldb + k0 + scol, &Bs[ch * 512]);
    }
    __syncthreads();
    const int fr = lane & 15;
    const int kq = (lane >> 4) * 8;
    short8 af[4], bfr[4];
#pragma unroll
    for (int i = 0; i < 4; ++i)
      af[i] = *(const short8*)&As[(wm + i * 16 + fr) * 32 + kq];
#pragma unroll
    for (int j = 0; j < 4; ++j)
      bfr[j] = *(const short8*)&Bs[(wn + j * 16 + fr) * 32 + kq];
#pragma unroll
    for (int i = 0; i < 4; ++i)
#pragma unroll
      for (int j = 0; j < 4; ++j)
        acc[i][j] = __builtin_amdgcn_mfma_f32_16x16x32_bf16(af[i], bfr[j], acc[i][j], 0, 0, 0);
    __syncthreads();
  }
  const int col = lane & 15;
  const int rg = (lane >> 4) * 4;
#pragma unroll
  for (int i = 0; i < 4; ++i)
#pragma unroll
    for (int j = 0; j < 4; ++j)
#pragma unroll
      for (int r = 0; r < 4; ++r)
        C[(size_t)(m0 + wm + i * 16 + rg + r) * ldc + (n0 + wn + j * 16 + col)] = acc[i][j][r];
}

// ---------------- bf16 MFMA GEMM (bf16 out, vectorized epilogue) ----------------
__global__ __launch_bounds__(256) void gemm_bf16_bf16out(
    const unsigned short* __restrict__ A, int lda,
    const unsigned short* __restrict__ B, int ldb,
    unsigned short* __restrict__ C, int ldc, int K) {
  __shared__ unsigned short As[128 * 32];
  __shared__ unsigned short Bs[128 * 32];
  const int tid = threadIdx.x;
  const int lane = tid & 63;
  const int w = tid >> 6;
  const int m0 = blockIdx.y * 128;
  const int n0 = blockIdx.x * 128;
  const int wm = (w >> 1) * 64;
  const int wn = (w & 1) * 64;
  const int srow = lane >> 2;
  const int scol = (lane & 3) * 8;
  floatx4 acc[4][4] = {};
  for (int k0 = 0; k0 < K; k0 += 32) {
#pragma unroll
    for (int it = 0; it < 2; ++it) {
      int ch = it * 4 + w;
      gload_lds16(A + (size_t)(m0 + ch * 16 + srow) * lda + k0 + scol, &As[ch * 512]);
      gload_lds16(B + (size_t)(n0 + ch * 16 + srow) * ldb + k0 + scol, &Bs[ch * 512]);
    }
    __syncthreads();
    const int fr = lane & 15;
    const int kq = (lane >> 4) * 8;
    short8 af[4], bfr[4];
#pragma unroll
    for (int i = 0; i < 4; ++i)
      af[i] = *(const short8*)&As[(wm + i * 16 + fr) * 32 + kq];
#pragma unroll
    for (int j = 0; j < 4; ++j)
      bfr[j] = *(const short8*)&Bs[(wn + j * 16 + fr) * 32 + kq];
#pragma unroll
    for (int i = 0; i < 4; ++i)
#pragma unroll
      for (int j = 0; j < 4; ++j)
        acc[i][j] = __builtin_amdgcn_mfma_f32_16x16x32_bf16(af[i], bfr[j], acc[i][j], 0, 0, 0);
    __syncthreads();
  }
  // epilogue: per-wave LDS transpose (reuse As: 4 waves x 1024 shorts), ushort8 stores
  const int fr = lane & 15;
  const int rg = (lane >> 4) * 4;
  unsigned short* Ew = &As[w * 1024];
  const int rr = lane >> 3;        // 0..7
  const int c8 = (lane & 7) * 8;
#pragma unroll
  for (int i = 0; i < 4; ++i) {
#pragma unroll
    for (int q = 0; q < 4; ++q)
#pragma unroll
      for (int j = 0; j < 4; ++j)
        Ew[(rg + q) * 64 + j * 16 + fr] = f2bf(acc[i][j][q]);
    // wave-local in-order DS: reads below wait on the writes above
    ushort8v v0 = *(const ushort8v*)&Ew[rr * 64 + c8];
    ushort8v v1 = *(const ushort8v*)&Ew[(rr + 8) * 64 + c8];
    *(ushort8v*)(C + (size_t)(m0 + wm + i * 16 + rr) * ldc + n0 + wn + c8) = v0;
    *(ushort8v*)(C + (size_t)(m0 + wm + i * 16 + rr + 8) * ldc + n0 + wn + c8) = v1;
  }
}

// ---------------- skinny f32 GEMM: C[M x N(<=64)] = A * B^T, M-tile=16 ----------------
__global__ __launch_bounds__(256) void gemm_skinny_f32(
    const float* __restrict__ A, int lda,
    const float* __restrict__ B, int ldb,
    float* __restrict__ C, int ldc, int N, int K) {
  __shared__ float Bs[64][68];
  __shared__ float As[16][68];
  const int tid = threadIdx.x;
  const int m0 = blockIdx.x * 16;
  const int tm = tid >> 4;
  const int tn4 = (tid & 15) * 4;
  float acc[4] = {0.f, 0.f, 0.f, 0.f};
  for (int k0 = 0; k0 < K; k0 += 64) {
    __syncthreads();
    {
      int bn = tid >> 2;
      int bk = (tid & 3) * 16;
      if (bn < N) {
#pragma unroll
        for (int q = 0; q < 4; ++q) {
          float4 v = *(const float4*)(B + (size_t)bn * ldb + k0 + bk + q * 4);
          Bs[bk + q*4 + 0][bn] = v.x;
          Bs[bk + q*4 + 1][bn] = v.y;
          Bs[bk + q*4 + 2][bn] = v.z;
          Bs[bk + q*4 + 3][bn] = v.w;
        }
      } else {
#pragma unroll
        for (int q = 0; q < 4; ++q) {
          Bs[bk + q*4 + 0][bn] = 0.f;
          Bs[bk + q*4 + 1][bn] = 0.f;
          Bs[bk + q*4 + 2][bn] = 0.f;
          Bs[bk + q*4 + 3][bn] = 0.f;
        }
      }
      int am = tid >> 4;
      int ak = (tid & 15) * 4;
      *(float4*)&As[am][ak] = *(const float4*)(A + (size_t)(m0 + am) * lda + k0 + ak);
    }
    __syncthreads();
#pragma unroll 8
    for (int k = 0; k < 64; ++k) {
      float a = As[tm][k];
      float4 b4 = *(const float4*)&Bs[k][tn4];
      acc[0] += a * b4.x; acc[1] += a * b4.y;
      acc[2] += a * b4.z; acc[3] += a * b4.w;
    }
  }
  if (tn4 < N)
    *(float4*)(C + (size_t)(m0 + tm) * ldc + tn4) = make_float4(acc[0], acc[1], acc[2], acc[3]);
}

// ---------------- skinny GEMM, bf16 A: C[M x N(<=64)] = A * B^T ----------------
__global__ __launch_bounds__(256) void gemm_skinny_a16(
    const unsigned short* __restrict__ A, int lda,
    const float* __restrict__ B, int ldb,
    float* __restrict__ C, int ldc, int N, int K) {
  __shared__ float Bs[64][68];
  __shared__ float As[16][68];
  const int tid = threadIdx.x;
  const int m0 = blockIdx.x * 16;
  const int tm = tid >> 4;
  const int tn4 = (tid & 15) * 4;
  float acc[4] = {0.f, 0.f, 0.f, 0.f};
  for (int k0 = 0; k0 < K; k0 += 64) {
    __syncthreads();
    {
      int bn = tid >> 2;
      int bk = (tid & 3) * 16;
      if (bn < N) {
#pragma unroll
        for (int q = 0; q < 4; ++q) {
          float4 v = *(const float4*)(B + (size_t)bn * ldb + k0 + bk + q * 4);
          Bs[bk + q*4 + 0][bn] = v.x;
          Bs[bk + q*4 + 1][bn] = v.y;
          Bs[bk + q*4 + 2][bn] = v.z;
          Bs[bk + q*4 + 3][bn] = v.w;
        }
      } else {
#pragma unroll
        for (int q = 0; q < 4; ++q) {
          Bs[bk + q*4 + 0][bn] = 0.f;
          Bs[bk + q*4 + 1][bn] = 0.f;
          Bs[bk + q*4 + 2][bn] = 0.f;
          Bs[bk + q*4 + 3][bn] = 0.f;
        }
      }
      int am = tid >> 4;
      int ak = (tid & 15) * 4;
      ushort4 v = *(const ushort4*)(A + (size_t)(m0 + am) * lda + k0 + ak);
      As[am][ak+0] = bf2f(v.x); As[am][ak+1] = bf2f(v.y);
      As[am][ak+2] = bf2f(v.z); As[am][ak+3] = bf2f(v.w);
    }
    __syncthreads();
#pragma unroll 8
    for (int k = 0; k < 64; ++k) {
      float a = As[tm][k];
      float4 b4 = *(const float4*)&Bs[k][tn4];
      acc[0] += a * b4.x; acc[1] += a * b4.y;
      acc[2] += a * b4.z; acc[3] += a * b4.w;
    }
  }
  if (tn4 < N)
    *(float4*)(C + (size_t)(m0 + tm) * ldc + tn4) = make_float4(acc[0], acc[1], acc[2], acc[3]);
}

// ---------------- dt = softplus(dt_raw + bias), flip for reverse; + chunk-local cumsum ----------------
__global__ __launch_bounds__(256) void dtscan_kernel(const float* __restrict__ DTraw,
                                                     const float* __restrict__ dt_bias,
                                                     const float* __restrict__ A_log,
                                                     float* __restrict__ DTt,
                                                     float* __restrict__ CUMS) {
  __shared__ float sc[256];
  int tid = threadIdx.x;
  int idx = blockIdx.x * 256 + tid;
  int l  = idx & 2047;
  int rh = idx >> 11;
  int h  = rh & 31;
  int r  = rh >> 5;
  int bi = r & 1;
  int ls = (r < 2) ? l : flip_l(l);
  int ch = (r < 2) ? h : NHEADS + h;
  float raw = DTraw[((size_t)bi * SEQLEN + ls) * 64 + ch] + dt_bias[h];
  float dtv = (raw > 20.f) ? raw : log1pf(__expf(raw));
  DTt[idx] = dtv;
  float A = -__expf(A_log[h]);
  float run = dtv * A;
  sc[tid] = run;
  __syncthreads();
#pragma unroll
  for (int ofs = 1; ofs < 256; ofs <<= 1) {
    float add = (tid >= ofs) ? sc[tid - ofs] : 0.f;
    __syncthreads();
    run += add;
    sc[tid] = run;
    __syncthreads();
  }
  CUMS[idx] = run;
}

// ---------------- fused convs: bf16 in/out, register sliding-window ----------------
__global__ __launch_bounds__(256) void conv_fused2_kernel(const unsigned short* __restrict__ Zb,
                                                          const float* __restrict__ wsp,
                                                          const float* __restrict__ bsp,
                                                          const float* __restrict__ wtp,
                                                          const float* __restrict__ btp,
                                                          unsigned short* __restrict__ XTb) {
  __shared__ float4 xsl[8][8][32];
  const int tid = threadIdx.x;
  const int g  = tid & 31;
  const int fr = tid >> 5;
  const int c  = blockIdx.x * 128 + g * 4;
  const int s0 = blockIdx.y * 8;
  const int bi = blockIdx.z;
  float wsp_r[4][K_SP];
#pragma unroll
  for (int ch = 0; ch < 4; ++ch)
#pragma unroll
    for (int j = 0; j < K_SP; ++j) wsp_r[ch][j] = wsp[(c + ch) * K_SP + j];
  float4 bsp4 = *(const float4*)(bsp + c);
  float4 z[14];
#pragma unroll
  for (int i = 0; i < 14; ++i) {
    int ss = s0 - 3 + i;
    if (0 <= ss && ss < SPATIAL) {
      ushort4 v = *(const ushort4*)(Zb + ((size_t)bi * SEQLEN + (ss*8 + fr)) * ZLD + D_INNER + c);
      z[i] = make_float4(bf2f(v.x), bf2f(v.y), bf2f(v.z), bf2f(v.w));
    } else {
      z[i] = make_float4(0.f, 0.f, 0.f, 0.f);
    }
  }
#pragma unroll
  for (int so = 0; so < 8; ++so) {
    float4 a = bsp4;
#pragma unroll
    for (int j = 0; j < K_SP; ++j) {
      a.x += wsp_r[0][j] * z[so + j].x;
      a.y += wsp_r[1][j] * z[so + j].y;
      a.z += wsp_r[2][j] * z[so + j].z;
      a.w += wsp_r[3][j] * z[so + j].w;
    }
    a.x = silu_f(a.x); a.y = silu_f(a.y); a.z = silu_f(a.z); a.w = silu_f(a.w);
    xsl[fr][so][g] = a;
  }
  __syncthreads();
  float wtp_r[4][K_TP];
#pragma unroll
  for (int ch = 0; ch < 4; ++ch)
#pragma unroll
    for (int j = 0; j < K_TP; ++j) wtp_r[ch][j] = wtp[(c + ch) * K_TP + j];
  float4 btp4 = *(const float4*)(btp + c);
#pragma unroll
  for (int so = 0; so < 8; ++so) {
    float4 t = btp4;
#pragma unroll
    for (int j = 0; j < K_TP; ++j) {
      int ff = fr + j - (K_TP - 1);
      if (ff >= 0) {
        float4 xv = xsl[ff][so][g];
        t.x += wtp_r[0][j] * xv.x;
        t.y += wtp_r[1][j] * xv.y;
        t.z += wtp_r[2][j] * xv.z;
        t.w += wtp_r[3][j] * xv.w;
      }
    }
    ushort4 o;
    o.x = f2bf(silu_f(t.x)); o.y = f2bf(silu_f(t.y));
    o.z = f2bf(silu_f(t.z)); o.w = f2bf(silu_f(t.w));
    *(ushort4*)(XTb + ((size_t)bi * SEQLEN + ((s0 + so)*8 + fr)) * CONV_DIM + c) = o;
  }
}

// ---------------- CB[t][s] = sum_n C[t][n] B[s][n], per (r,c)  (t-major) ----------------
__global__ __launch_bounds__(256) void cb_kernel(const unsigned short* __restrict__ XTb,
                                                 float* __restrict__ CBs) {
  __shared__ float Ct[64][65];
  __shared__ float Bt[64][65];
  int tid = threadIdx.x;
  int t0 = (blockIdx.x & 3) * 64;
  int s0 = (blockIdx.x >> 2) * 64;
  if (s0 > t0) return;
  int c = blockIdx.y;
  int r = blockIdx.z;
  int bi = r & 1;
  int bOff = D_INNER + ((r < 2) ? 0 : 2*GN);
  int cOff = bOff + GN;
  int lrow = tid >> 4;
  int n4 = (tid & 15) << 2;
#pragma unroll
  for (int rep = 0; rep < 4; ++rep) {
    int tl = rep * 16 + lrow;
    int Lc = c * CHUNK + t0 + tl;
    int Ls = c * CHUNK + s0 + tl;
    if (r >= 2) { Lc = flip_l(Lc); Ls = flip_l(Ls); }
    ushort4 cv = *(const ushort4*)(XTb + ((size_t)bi*SEQLEN + Lc)*CONV_DIM + cOff + n4);
    ushort4 bv = *(const ushort4*)(XTb + ((size_t)bi*SEQLEN + Ls)*CONV_DIM + bOff + n4);
    Ct[n4+0][tl] = bf2f(cv.x); Ct[n4+1][tl] = bf2f(cv.y);
    Ct[n4+2][tl] = bf2f(cv.z); Ct[n4+3][tl] = bf2f(cv.w);
    Bt[n4+0][tl] = bf2f(bv.x); Bt[n4+1][tl] = bf2f(bv.y);
    Bt[n4+2][tl] = bf2f(bv.z); Bt[n4+3][tl] = bf2f(bv.w);
  }
  __syncthreads();
  int txx = tid & 15;
  int tyy = tid >> 4;
  float acc[4][4] = {{0.f,0.f,0.f,0.f},{0.f,0.f,0.f,0.f},{0.f,0.f,0.f,0.f},{0.f,0.f,0.f,0.f}};
#pragma unroll
  for (int n = 0; n < D_STATE; ++n) {
    float cr[4], br[4];
#pragma unroll
    for (int i = 0; i < 4; ++i) cr[i] = Ct[n][tyy + 16*i];
#pragma unroll
    for (int j = 0; j < 4; ++j) br[j] = Bt[n][txx + 16*j];
#pragma unroll
    for (int i = 0; i < 4; ++i)
#pragma unroll
      for (int j = 0; j < 4; ++j)
        acc[i][j] += cr[i] * br[j];
  }
  size_t base = (((size_t)r*NCH + c) * CHUNK) * CHUNK;
#pragma unroll
  for (int i = 0; i < 4; ++i)
#pragma unroll
    for (int j = 0; j < 4; ++j)
      CBs[base + (size_t)(t0 + tyy + 16*i)*CHUNK + (s0 + txx + 16*j)] = acc[i][j];
}

// ---------------- per-chunk state sums (MFMA, forward r=0,1 only) ----------------
__global__ __launch_bounds__(256) void chunk_state_kernel(const unsigned short* __restrict__ XTb,
                                                          const float* __restrict__ DTt,
                                                          const float* __restrict__ CUMS,
                                                          float* __restrict__ SCH) {
  __shared__ unsigned short Xb[64][40];
  __shared__ unsigned short Bb[64][40];
  int tid = threadIdx.x;
  int lane = tid & 63;
  int w = tid >> 6;
  int c = blockIdx.x;
  int h = blockIdx.y;
  int r = blockIdx.z;
  int bi = r;
  int rh = r * NHEADS + h;
  float cl = CUMS[(size_t)rh*SEQLEN + c*CHUNK + 255];
  const int fr = lane & 15;
  const int kq = (lane >> 4) * 8;
  floatx4 acc[4] = {};
  for (int sl = 0; sl < 8; ++sl) {
    int s0 = sl * 32;
    __syncthreads();
    {
      int srow = tid >> 3;
      int cg = (tid & 7) * 8;
      int l = c*CHUNK + s0 + srow;
      float g = __expf(cl - CUMS[(size_t)rh*SEQLEN + l]) * DTt[(size_t)rh*SEQLEN + l];
      const unsigned short* row = XTb + ((size_t)bi*SEQLEN + l)*CONV_DIM;
      ushort4 x0 = *(const ushort4*)(row + h*HEADDIM + cg);
      ushort4 x1 = *(const ushort4*)(row + h*HEADDIM + cg + 4);
      ushort4 b0 = *(const ushort4*)(row + D_INNER + cg);
      ushort4 b1 = *(const ushort4*)(row + D_INNER + cg + 4);
      Xb[cg+0][srow] = f2bf(g*bf2f(x0.x)); Xb[cg+1][srow] = f2bf(g*bf2f(x0.y));
      Xb[cg+2][srow] = f2bf(g*bf2f(x0.z)); Xb[cg+3][srow] = f2bf(g*bf2f(x0.w));
      Xb[cg+4][srow] = f2bf(g*bf2f(x1.x)); Xb[cg+5][srow] = f2bf(g*bf2f(x1.y));
      Xb[cg+6][srow] = f2bf(g*bf2f(x1.z)); Xb[cg+7][srow] = f2bf(g*bf2f(x1.w));
      Bb[cg+0][srow] = b0.x; Bb[cg+1][srow] = b0.y;
      Bb[cg+2][srow] = b0.z; Bb[cg+3][srow] = b0.w;
      Bb[cg+4][srow] = b1.x; Bb[cg+5][srow] = b1.y;
      Bb[cg+6][srow] = b1.z; Bb[cg+7][srow] = b1.w;
    }
    __syncthreads();
    short8 af = *(const short8*)&Xb[w*16 + fr][kq];
#pragma unroll
    for (int j = 0; j < 4; ++j) {
      short8 bf8 = *(const short8*)&Bb[j*16 + fr][kq];
      acc[j] = __builtin_amdgcn_mfma_f32_16x16x32_bf16(af, bf8, acc[j], 0, 0, 0);
    }
  }
  const int col = lane & 15;
  const int rg = (lane >> 4) * 4;
  size_t base = (((size_t)r*NCH + c)*NHEADS + h) * (size_t)(HEADDIM*D_STATE);
#pragma unroll
  for (int j = 0; j < 4; ++j)
#pragma unroll
    for (int q = 0; q < 4; ++q)
      SCH[base + (size_t)(w*16 + rg + q)*D_STATE + j*16 + col] = acc[j][q];
}

// ---------------- prefix-combine chunk states -> SPREV ----------------
__global__ __launch_bounds__(256) void state_combine_kernel(const float* __restrict__ SCH,
                                                            const float* __restrict__ CUMS,
                                                            float* __restrict__ SPREV) {
  int bid = blockIdx.x;
  int pq = bid & 3;
  int h = (bid >> 2) & 31;
  int r = bid >> 7;
  int tid = threadIdx.x;
  int p = pq*16 + (tid >> 4);
  int n = (tid & 15) * 4;
  float4 S = make_float4(0.f, 0.f, 0.f, 0.f);
  for (int c = 0; c < NCH; ++c) {
    size_t off = ((((size_t)r*NCH + c)*NHEADS + h)*HEADDIM + p)*D_STATE + n;
    *(float4*)(SPREV + off) = S;
    float dec = __expf(CUMS[((size_t)r*NHEADS + h)*SEQLEN + c*CHUNK + 255]);
    float4 v = *(const float4*)(SCH + off);
    S.x = dec*S.x + v.x; S.y = dec*S.y + v.y;
    S.z = dec*S.z + v.z; S.w = dec*S.w + v.w;
  }
}

// ---------------- Y = intra(triangular, MFMA) + inter (MFMA, fwd only) ----------------
__global__ __launch_bounds__(256) void yscan_kernel(const unsigned short* __restrict__ XTb,
                                                    const float* __restrict__ DTt,
                                                    const float* __restrict__ CUMS,
                                                    const float* __restrict__ CBs,
                                                    const float* __restrict__ SPREV,
                                                    float* __restrict__ Y) {
  __shared__ unsigned short Xb[64][40];
  __shared__ float dts[CHUNK];
  __shared__ float cums[CHUNK];
  int tid = threadIdx.x;
  int lane = tid & 63;
  int w = tid >> 6;
  int c = blockIdx.x;
  int rh = blockIdx.y;
  int h = rh & 31;
  int r = rh >> 5;
  int bi = r & 1;
  dts[tid]  = DTt[(size_t)rh*SEQLEN + c*CHUNK + tid];
  cums[tid] = CUMS[(size_t)rh*SEQLEN + c*CHUNK + tid];
  __syncthreads();
  const int fr = lane & 15;
  const int kq = (lane >> 4) * 8;
  const int wt0 = w * 64;
  float ct[4];
#pragma unroll
  for (int i = 0; i < 4; ++i) ct[i] = cums[wt0 + i*16 + fr];
  floatx4 acc[4][4] = {};
  size_t cbbase = (((size_t)r*NCH + c) * CHUNK) * CHUNK;
  const int maxsl = 2*w + 1;
  for (int sl = 0; sl < 8; ++sl) {
    int s0 = sl * 32;
    __syncthreads();
    {
      int srow = tid >> 3;
      int p0 = (tid & 7) * 4;
      int L = c*CHUNK + s0 + srow;
      if (r >= 2) L = flip_l(L);
      const unsigned short* xrow = XTb + ((size_t)bi*SEQLEN + L)*CONV_DIM + h*HEADDIM;
#pragma unroll
      for (int half = 0; half < 2; ++half) {
        ushort4 v = *(const ushort4*)(xrow + p0 + half*32);
        Xb[p0 + half*32 + 0][srow] = v.x;
        Xb[p0 + half*32 + 1][srow] = v.y;
        Xb[p0 + half*32 + 2][srow] = v.z;
        Xb[p0 + half*32 + 3][srow] = v.w;
      }
    }
    __syncthreads();
    if (sl <= maxsl) {
      float cs[8], dtv[8];
#pragma unroll
      for (int j = 0; j < 8; ++j) { cs[j] = cums[s0 + kq + j]; dtv[j] = dts[s0 + kq + j]; }
      short8 bfr[4];
#pragma unroll
      for (int j = 0; j < 4; ++j)
        bfr[j] = *(const short8*)&Xb[j*16 + fr][kq];
#pragma unroll
      for (int i = 0; i < 4; ++i) {
        int t = wt0 + i*16 + fr;
        const float* cbrow = CBs + cbbase + (size_t)t*CHUNK + s0 + kq;
        float4 c0 = *(const float4*)cbrow;
        float4 c1 = *(const float4*)(cbrow + 4);
        float cb[8] = {c0.x,c0.y,c0.z,c0.w,c1.x,c1.y,c1.z,c1.w};
        short8 af;
#pragma unroll
        for (int j = 0; j < 8; ++j) {
          int s = s0 + kq + j;
          float wv = (s <= t) ? cb[j] * __expf(ct[i] - cs[j]) * dtv[j] : 0.f;
          af[j] = (short)f2bf(wv);
        }
#pragma unroll
        for (int j = 0; j < 4; ++j)
          acc[i][j] = __builtin_amdgcn_mfma_f32_16x16x32_bf16(af, bfr[j], acc[i][j], 0, 0, 0);
      }
    }
  }
  if (r < 2) {
    float ect[4];
#pragma unroll
    for (int i = 0; i < 4; ++i) ect[i] = __expf(ct[i]);
    const float* spbase = SPREV + (((size_t)r*NCH + c)*NHEADS + h) * (size_t)(HEADDIM*D_STATE);
#pragma unroll
    for (int ns = 0; ns < 2; ++ns) {
      int n0 = ns * 32;
      short8 bfr[4];
#pragma unroll
      for (int j = 0; j < 4; ++j) {
        const float* sp = spbase + (size_t)(j*16 + fr)*D_STATE + n0 + kq;
        float4 s0v = *(const float4*)sp;
        float4 s1v = *(const float4*)(sp + 4);
        short8 bb;
        bb[0]=(short)f2bf(s0v.x); bb[1]=(short)f2bf(s0v.y); bb[2]=(short)f2bf(s0v.z); bb[3]=(short)f2bf(s0v.w);
        bb[4]=(short)f2bf(s1v.x); bb[5]=(short)f2bf(s1v.y); bb[6]=(short)f2bf(s1v.z); bb[7]=(short)f2bf(s1v.w);
        bfr[j] = bb;
      }
#pragma unroll
      for (int i = 0; i < 4; ++i) {
        int t = wt0 + i*16 + fr;
        const unsigned short* crow = XTb + ((size_t)bi*SEQLEN + c*CHUNK + t)*CONV_DIM + D_INNER + GN + n0 + kq;
        ushort4 c0 = *(const ushort4*)crow;
        ushort4 c1 = *(const ushort4*)(crow + 4);
        short8 af;
        af[0]=(short)f2bf(bf2f(c0.x)*ect[i]); af[1]=(short)f2bf(bf2f(c0.y)*ect[i]);
        af[2]=(short)f2bf(bf2f(c0.z)*ect[i]); af[3]=(short)f2bf(bf2f(c0.w)*ect[i]);
        af[4]=(short)f2bf(bf2f(c1.x)*ect[i]); af[5]=(short)f2bf(bf2f(c1.y)*ect[i]);
        af[6]=(short)f2bf(bf2f(c1.z)*ect[i]); af[7]=(short)f2bf(bf2f(c1.w)*ect[i]);
#pragma unroll
        for (int j = 0; j < 4; ++j)
          acc[i][j] = __builtin_amdgcn_mfma_f32_16x16x32_bf16(af, bfr[j], acc[i][j], 0, 0, 0);
      }
    }
  }
  const int rg = (lane >> 4) * 4;
  size_t ybase = ((size_t)r*SEQLEN + c*CHUNK)*D_INNER + h*HEADDIM;
#pragma unroll
  for (int i = 0; i < 4; ++i)
#pragma unroll
    for (int j = 0; j < 4; ++j)
#pragma unroll
      for (int q = 0; q < 4; ++q)
        Y[ybase + (size_t)(wt0 + i*16 + rg + q)*D_INNER + j*16 + fr] = acc[i][j][q];
}

// ---------------- shifts + x_res + RMSNorm + gate (vectorized, -> bf16) ----------------
__global__ __launch_bounds__(256) void combine_kernel(const float* __restrict__ Y,
                                                      const unsigned short* __restrict__ XTb,
                                                      const float* __restrict__ FCD,
                                                      const float* __restrict__ Dp,
                                                      const unsigned short* __restrict__ Zb,
                                                      const float* __restrict__ norm_w,
                                                      unsigned short* __restrict__ YPb) {
  __shared__ float red[256];
  int row = blockIdx.x;
  int bi = row >> 11;
  int l = row & 2047;
  int s = l >> 3, fr = l & 7;
  int tid = threadIdx.x;
  int d0 = tid * 8;
  const float* yf = (l >= 1) ? Y + ((size_t)bi*SEQLEN + (l-1))*D_INNER + d0 : nullptr;
  const float* yr = (s >= 1) ? Y + ((size_t)(2+bi)*SEQLEN + ((s-1)*8 + (7-fr)))*D_INNER + d0 : nullptr;
  const unsigned short* xr = XTb + ((size_t)row)*CONV_DIM + d0;
  float fcv = FCD[(size_t)row*NHEADS + (d0 >> 6)] + Dp[d0 >> 6];
  ushort8v xv8 = *(const ushort8v*)xr;
  float v[8];
#pragma unroll
  for (int q = 0; q < 8; ++q) v[q] = bf2f(xv8[q]) * fcv;
  if (yf) {
    float4 a = *(const float4*)yf, b = *(const float4*)(yf + 4);
    v[0]+=a.x; v[1]+=a.y; v[2]+=a.z; v[3]+=a.w;
    v[4]+=b.x; v[5]+=b.y; v[6]+=b.z; v[7]+=b.w;
  }
  if (yr) {
    float4 a = *(const float4*)yr, b = *(const float4*)(yr + 4);
    v[0]+=a.x; v[1]+=a.y; v[2]+=a.z; v[3]+=a.w;
    v[4]+=b.x; v[5]+=b.y; v[6]+=b.z; v[7]+=b.w;
  }
  float ss = 0.f;
#pragma unroll
  for (int q = 0; q < 8; ++q) ss += v[q] * v[q];
  red[tid] = ss;
  __syncthreads();
  for (int ofs = 128; ofs > 0; ofs >>= 1) {
    if (tid < ofs) red[tid] += red[tid + ofs];
    __syncthreads();
  }
  float rs = rsqrtf(red[0] / (float)D_INNER + 1e-5f);
  ushort8v zv8 = *(const ushort8v*)(Zb + ((size_t)row)*ZLD + d0);
  float4 nw0 = *(const float4*)(norm_w + d0);
  float4 nw1 = *(const float4*)(norm_w + d0 + 4);
  float nw[8] = {nw0.x,nw0.y,nw0.z,nw0.w,nw1.x,nw1.y,nw1.z,nw1.w};
  ushort8v o;
#pragma unroll
  for (int q = 0; q < 8; ++q)
    o[q] = f2bf(v[q] * rs * nw[q] * silu_f(bf2f(zv8[q])));
  *(ushort8v*)(YPb + (size_t)row*D_INNER + d0) = o;
}

extern "C" void kernel_launch(void* const* d_in, const int* in_sizes, int n_in,
                              void* d_out, int out_size, void* d_ws, size_t ws_size,
                              hipStream_t stream) {
  (void)in_sizes; (void)n_in; (void)out_size; (void)ws_size;
  const float* u          = (const float*)d_in[0];
  const float* in_proj_w  = (const float*)d_in[1];
  const float* conv_sp_w  = (const float*)d_in[2];
  const float* conv_sp_b  = (const float*)d_in[3];
  const float* conv_tp_w  = (const float*)d_in[4];
  const float* conv_tp_b  = (const float*)d_in[5];
  const float* dt_bias    = (const float*)d_in[6];
  const float* A_log      = (const float*)d_in[7];
  const float* Dp         = (const float*)d_in[8];
  const float* fc_D_w     = (const float*)d_in[9];
  const float* norm_w     = (const float*)d_in[10];
  const float* out_proj_w = (const float*)d_in[11];
  float* out = (float*)d_out;
  float* ws = (float*)d_ws;

  // workspace layout (f32-element offsets; Z/XT regions hold bf16 now)
  float* Z     = ws;                       // 17,825,792 slots (bf16 uses half)
  float* SH    = Z     + 17825792ULL;      // 9,437,184  (CBs -> YPb)
  float* XT    = SH    + 9437184ULL;       // 9,437,184  (bf16 uses half)
  float* DTt   = XT    + 9437184ULL;       // 262,144
  float* Yb    = DTt   + 262144ULL;        // 16,777,216 (hosts bf16 staging + SCH early)
  float* SPREV = Yb    + 16777216ULL;      // 2,097,152
  float* FCD   = SPREV + 2097152ULL;       // 131,072
  float* DTraw = FCD   + 131072ULL;        // 262,144
  float* CUMS  = DTraw + 262144ULL;        // 262,144

  unsigned short* Zb  = (unsigned short*)Z;
  unsigned short* XTb = (unsigned short*)XT;
  unsigned short* Ub  = (unsigned short*)Yb;
  unsigned short* Wb  = (unsigned short*)Yb + 4194304ULL;
  float* SCH = Yb + 8388608ULL;            // 2,097,152 (dead before yscan writes Yb)
  unsigned short* Wob = (unsigned short*)Yb;
  unsigned short* YPb = (unsigned short*)SH;

  cast_bf16_kernel<<<4096, 256, 0, stream>>>(u, Ub);
  cast_bf16_kernel<<<4352, 256, 0, stream>>>(in_proj_w, Wb);
  gemm_bf16_bf16out<<<dim3(34, 32), 256, 0, stream>>>(Ub, 1024, Wb, 1024, Zb, ZLD, 1024);
  gemm_skinny_f32<<<256, 256, 0, stream>>>(u, 1024, in_proj_w + 4352ULL*1024, 1024,
                                           DTraw, 64, 64, 1024);
  dtscan_kernel<<<1024, 256, 0, stream>>>(DTraw, dt_bias, A_log, DTt, CUMS);
  conv_fused2_kernel<<<dim3(18, 32, 2), 256, 0, stream>>>(Zb, conv_sp_w, conv_sp_b,
                                                          conv_tp_w, conv_tp_b, XTb);
  gemm_skinny_a16<<<256, 256, 0, stream>>>(XTb, 2304, fc_D_w, 2048, FCD, 32, 32, 2048);
  cb_kernel<<<dim3(16, 8, 4), 256, 0, stream>>>(XTb, SH);
  chunk_state_kernel<<<dim3(NCH, NHEADS, 2), 256, 0, stream>>>(XTb, DTt, CUMS, SCH);
  state_combine_kernel<<<256, 256, 0, stream>>>(SCH, CUMS, SPREV);
  yscan_kernel<<<dim3(8, 128), 256, 0, stream>>>(XTb, DTt, CUMS, SH, SPREV, Yb);
  combine_kernel<<<4096, 256, 0, stream>>>(Yb, XTb, FCD, Dp, Zb, norm_w, YPb);
  cast_bf16_kernel<<<2048, 256, 0, stream>>>(out_proj_w, Wob);
  gemm_bf16<<<dim3(8, 32), 256, 0, stream>>>(YPb, 2048, Wob, 2048, out, 1024, 2048);
}